// Round 6
// baseline (611.815 us; speedup 1.0000x reference)
//
#include <hip/hip_runtime.h>

#define N_NODES 50000
#define N_EDGES 800000
#define E_TOT   850000           // edges + self loops
#define IN_DIM  128
#define HID     64
#define HEADS   4
#define C1      256              // HEADS*HID
#define OUT_DIM 64
#define NEG_SLOPE 0.2f

#define ACT_STRIDE  (C1 + 4)                 // 260: pad breaks power-of-2 strides

// ---------------------------------------------------------------------------
// CSR build (by destination): count -> exclusive scan -> fill
// ---------------------------------------------------------------------------
__global__ void count_kernel(const int* __restrict__ dst_a, int* __restrict__ deg)
{
    int j = blockIdx.x * blockDim.x + threadIdx.x;
    if (j >= E_TOT) return;
    int d = (j < N_EDGES) ? dst_a[j] : (j - N_EDGES);   // self loop
    atomicAdd(&deg[d], 1);
}

__global__ __launch_bounds__(1024) void scan_kernel(const int* __restrict__ deg,
                                                    int* __restrict__ rowptr)
{
    __shared__ int psum[1024];
    const int t = threadIdx.x;
    const int CH = (N_NODES + 1023) / 1024;            // 49
    const int base = t * CH;
    int s = 0;
    for (int i = 0; i < CH; i++) {
        int idx = base + i;
        if (idx < N_NODES) s += deg[idx];
    }
    psum[t] = s;
    __syncthreads();
    for (int off = 1; off < 1024; off <<= 1) {         // Hillis-Steele inclusive
        int v = (t >= off) ? psum[t - off] : 0;
        __syncthreads();
        psum[t] += v;
        __syncthreads();
    }
    int run = (t > 0) ? psum[t - 1] : 0;
    for (int i = 0; i < CH; i++) {
        int idx = base + i;
        if (idx < N_NODES) { rowptr[idx] = run; run += deg[idx]; }
    }
    if (t == 0) rowptr[N_NODES] = E_TOT;
}

__global__ void fill_kernel(const int* __restrict__ src_a, const int* __restrict__ dst_a,
                            const int* __restrict__ rowptr, int* __restrict__ cursor,
                            int* __restrict__ srcSorted)
{
    int j = blockIdx.x * blockDim.x + threadIdx.x;
    if (j >= E_TOT) return;
    int s, d;
    if (j < N_EDGES) { s = src_a[j]; d = dst_a[j]; }
    else             { s = j - N_EDGES; d = s; }
    int pos = atomicAdd(&cursor[d], 1);
    srcSorted[rowptr[d] + pos] = s;
}

// ---------------------------------------------------------------------------
// prep: p_src[k][h] = sum_c W1[k][h*64+c] * a_src1[h][c]  (and p_dst).
// ---------------------------------------------------------------------------
__global__ __launch_bounds__(512) void prep_kernel(
    const float* __restrict__ W1, const float* __restrict__ a_src1,
    const float* __restrict__ a_dst1,
    float* __restrict__ p_src, float* __restrict__ p_dst)
{
    const int t = threadIdx.x;                 // 512 = 128 k * 4 h
    const int k = t >> 2, h = t & 3;
    const float* wrow = W1 + k * C1 + h * HID;
    const float* as = a_src1 + h * HID;
    const float* ad = a_dst1 + h * HID;
    float s = 0.f, d = 0.f;
    for (int c = 0; c < HID; c++) {
        float w = wrow[c];
        s = fmaf(w, as[c], s);
        d = fmaf(w, ad[c], d);
    }
    p_src[k * HEADS + h] = s;
    p_dst[k * HEADS + h] = d;
}

// ---------------------------------------------------------------------------
// proj1: as1/ad1[n][4] = x[n] @ p_src / p_dst. One wave per node.
// ---------------------------------------------------------------------------
__global__ __launch_bounds__(256) void proj1_kernel(
    const float* __restrict__ x, const float* __restrict__ p_src,
    const float* __restrict__ p_dst, float* __restrict__ as1, float* __restrict__ ad1)
{
    __shared__ float ps[IN_DIM * HEADS];       // 2 KB
    __shared__ float pd[IN_DIM * HEADS];       // 2 KB
    const int t = threadIdx.x;
    for (int i = t; i < IN_DIM * HEADS; i += 256) { ps[i] = p_src[i]; pd[i] = p_dst[i]; }
    __syncthreads();
    const int node = blockIdx.x * 4 + (t >> 6);
    const int lane = t & 63;
    float2 xv = *(const float2*)(x + (size_t)node * IN_DIM + lane * 2);
    float4 p0 = *(const float4*)(ps + (lane * 2) * HEADS);
    float4 p1 = *(const float4*)(ps + (lane * 2 + 1) * HEADS);
    float4 q0 = *(const float4*)(pd + (lane * 2) * HEADS);
    float4 q1 = *(const float4*)(pd + (lane * 2 + 1) * HEADS);
    float s0 = xv.x * p0.x + xv.y * p1.x;
    float s1 = xv.x * p0.y + xv.y * p1.y;
    float s2 = xv.x * p0.z + xv.y * p1.z;
    float s3 = xv.x * p0.w + xv.y * p1.w;
    float d0 = xv.x * q0.x + xv.y * q1.x;
    float d1 = xv.x * q0.y + xv.y * q1.y;
    float d2 = xv.x * q0.z + xv.y * q1.z;
    float d3 = xv.x * q0.w + xv.y * q1.w;
    #pragma unroll
    for (int off = 32; off; off >>= 1) {
        s0 += __shfl_down(s0, off, 64); s1 += __shfl_down(s1, off, 64);
        s2 += __shfl_down(s2, off, 64); s3 += __shfl_down(s3, off, 64);
        d0 += __shfl_down(d0, off, 64); d1 += __shfl_down(d1, off, 64);
        d2 += __shfl_down(d2, off, 64); d3 += __shfl_down(d3, off, 64);
    }
    if (lane == 0) {
        float4 sv = {s0, s1, s2, s3};
        float4 dv = {d0, d1, d2, d3};
        *(float4*)(as1 + node * 4) = sv;
        *(float4*)(ad1 + node * 4) = dv;
    }
}

// ---------------------------------------------------------------------------
// agg1x: xagg[n][h][k] = softmax-weighted sum of x[src] rows. One wave per
// dst node, lane = 2 k-channels, 4 head-accumulators. High-occupancy,
// latency-tolerant (separate from the VALU-dense MLP on purpose).
// ---------------------------------------------------------------------------
__global__ __launch_bounds__(256) void agg1x_kernel(
    const int* __restrict__ rowptr, const int* __restrict__ srcS,
    const float* __restrict__ x, const float* __restrict__ as1,
    const float* __restrict__ ad1, float* __restrict__ xagg)
{
    int gid  = blockIdx.x * blockDim.x + threadIdx.x;
    int n    = gid >> 6;
    int lane = threadIdx.x & 63;
    if (n >= N_NODES) return;
    float4 adv = *(const float4*)(ad1 + n * 4);
    const int e0 = rowptr[n], e1 = rowptr[n + 1];

    float2 acc0 = {0,0}, acc1 = {0,0}, acc2 = {0,0}, acc3 = {0,0};
    float den0 = 0, den1 = 0, den2 = 0, den3 = 0;
    int e = e0;
    for (; e + 2 <= e1; e += 2) {              // 2 row-loads in flight
        int s0 = srcS[e], s1 = srcS[e + 1];
        float4 A0 = *(const float4*)(as1 + s0 * 4);
        float4 A1 = *(const float4*)(as1 + s1 * 4);
        float2 xv0 = *(const float2*)(x + (size_t)s0 * IN_DIM + lane * 2);
        float2 xv1 = *(const float2*)(x + (size_t)s1 * IN_DIM + lane * 2);
        float a0 = A0.x + adv.x, a1 = A0.y + adv.y, a2 = A0.z + adv.z, a3 = A0.w + adv.w;
        a0 = a0 > 0.f ? a0 : NEG_SLOPE * a0;  a1 = a1 > 0.f ? a1 : NEG_SLOPE * a1;
        a2 = a2 > 0.f ? a2 : NEG_SLOPE * a2;  a3 = a3 > 0.f ? a3 : NEG_SLOPE * a3;
        float w0 = __expf(a0), w1 = __expf(a1), w2 = __expf(a2), w3 = __expf(a3);
        float b0 = A1.x + adv.x, b1v = A1.y + adv.y, b2v = A1.z + adv.z, b3 = A1.w + adv.w;
        b0 = b0 > 0.f ? b0 : NEG_SLOPE * b0;    b1v = b1v > 0.f ? b1v : NEG_SLOPE * b1v;
        b2v = b2v > 0.f ? b2v : NEG_SLOPE * b2v; b3 = b3 > 0.f ? b3 : NEG_SLOPE * b3;
        float u0 = __expf(b0), u1 = __expf(b1v), u2 = __expf(b2v), u3 = __expf(b3);
        acc0.x = fmaf(w0, xv0.x, acc0.x); acc0.y = fmaf(w0, xv0.y, acc0.y);
        acc1.x = fmaf(w1, xv0.x, acc1.x); acc1.y = fmaf(w1, xv0.y, acc1.y);
        acc2.x = fmaf(w2, xv0.x, acc2.x); acc2.y = fmaf(w2, xv0.y, acc2.y);
        acc3.x = fmaf(w3, xv0.x, acc3.x); acc3.y = fmaf(w3, xv0.y, acc3.y);
        acc0.x = fmaf(u0, xv1.x, acc0.x); acc0.y = fmaf(u0, xv1.y, acc0.y);
        acc1.x = fmaf(u1, xv1.x, acc1.x); acc1.y = fmaf(u1, xv1.y, acc1.y);
        acc2.x = fmaf(u2, xv1.x, acc2.x); acc2.y = fmaf(u2, xv1.y, acc2.y);
        acc3.x = fmaf(u3, xv1.x, acc3.x); acc3.y = fmaf(u3, xv1.y, acc3.y);
        den0 += w0 + u0; den1 += w1 + u1; den2 += w2 + u2; den3 += w3 + u3;
    }
    for (; e < e1; e++) {
        int s = srcS[e];
        float4 A0 = *(const float4*)(as1 + s * 4);
        float2 xv = *(const float2*)(x + (size_t)s * IN_DIM + lane * 2);
        float a0 = A0.x + adv.x, a1 = A0.y + adv.y, a2 = A0.z + adv.z, a3 = A0.w + adv.w;
        a0 = a0 > 0.f ? a0 : NEG_SLOPE * a0;  a1 = a1 > 0.f ? a1 : NEG_SLOPE * a1;
        a2 = a2 > 0.f ? a2 : NEG_SLOPE * a2;  a3 = a3 > 0.f ? a3 : NEG_SLOPE * a3;
        float w0 = __expf(a0), w1 = __expf(a1), w2 = __expf(a2), w3 = __expf(a3);
        acc0.x = fmaf(w0, xv.x, acc0.x); acc0.y = fmaf(w0, xv.y, acc0.y);
        acc1.x = fmaf(w1, xv.x, acc1.x); acc1.y = fmaf(w1, xv.y, acc1.y);
        acc2.x = fmaf(w2, xv.x, acc2.x); acc2.y = fmaf(w2, xv.y, acc2.y);
        acc3.x = fmaf(w3, xv.x, acc3.x); acc3.y = fmaf(w3, xv.y, acc3.y);
        den0 += w0; den1 += w1; den2 += w2; den3 += w3;
    }
    float i0 = 1.f / (den0 + 1e-16f), i1 = 1.f / (den1 + 1e-16f);
    float i2 = 1.f / (den2 + 1e-16f), i3 = 1.f / (den3 + 1e-16f);
    float* o = xagg + (size_t)n * (HEADS * IN_DIM) + lane * 2;
    float2 r0 = {acc0.x * i0, acc0.y * i0};
    float2 r1 = {acc1.x * i1, acc1.y * i1};
    float2 r2 = {acc2.x * i2, acc2.y * i2};
    float2 r3 = {acc3.x * i3, acc3.y * i3};
    *(float2*)(o + 0 * IN_DIM) = r0;
    *(float2*)(o + 1 * IN_DIM) = r1;
    *(float2*)(o + 2 * IN_DIM) = r2;
    *(float2*)(o + 3 * IN_DIM) = r3;
}

// ---------------------------------------------------------------------------
// mlp2: 16 nodes per block.
//  Phase B: act = ELU(xagg @ W1 + b1). wave = head -> W1 read ONCE per block;
//           xagg read directly from global (16-lane-uniform, dedup-coalesced).
//  Phase C: h2 = act @ W2 col-split (W2 from L2, act from LDS broadcast),
//           fused as2/ad2 projections.
//  LDS = act only (16.6 KB) -> ~2x the occupancy of the fused round-5 kernel.
// ---------------------------------------------------------------------------
__global__ __launch_bounds__(256) void mlp2_kernel(
    const float* __restrict__ xagg,
    const float* __restrict__ W1, const float* __restrict__ b1,
    const float* __restrict__ W2,
    const float* __restrict__ a_src2, const float* __restrict__ a_dst2,
    float* __restrict__ h2, float* __restrict__ as2, float* __restrict__ ad2)
{
    __shared__ float act[16 * ACT_STRIDE];     // 16,640 B
    const int t = threadIdx.x;
    const int nodeBase = blockIdx.x * 16;
    const int wv = t >> 6;

    {   // ---- Phase B: act = ELU(xagg @ W1 + b1). wave = head. ----
        const int q  = t & 15;                 // col-quad within head
        const int g  = (t >> 4) & 3;           // node group (4 nodes)
        const int h  = wv;                     // head = wave
        const int c0 = h * HID + q * 4;        // column in [0,256)
        float acc[4][4];
        #pragma unroll
        for (int i = 0; i < 4; i++)
            #pragma unroll
            for (int m = 0; m < 4; m++) acc[i][m] = 0.f;
        const float* xb = xagg + (size_t)(nodeBase + g * 4) * (HEADS * IN_DIM) + h * IN_DIM;
        for (int k = 0; k < IN_DIM; k += 4) {
            float4 w0 = *(const float4*)(W1 + (size_t)(k + 0) * C1 + c0);
            float4 w1 = *(const float4*)(W1 + (size_t)(k + 1) * C1 + c0);
            float4 w2 = *(const float4*)(W1 + (size_t)(k + 2) * C1 + c0);
            float4 w3 = *(const float4*)(W1 + (size_t)(k + 3) * C1 + c0);
            #pragma unroll
            for (int i = 0; i < 4; i++) {
                float4 xv = *(const float4*)(xb + i * (HEADS * IN_DIM) + k);
                acc[i][0] = fmaf(xv.x, w0.x, acc[i][0]); acc[i][0] = fmaf(xv.y, w1.x, acc[i][0]);
                acc[i][0] = fmaf(xv.z, w2.x, acc[i][0]); acc[i][0] = fmaf(xv.w, w3.x, acc[i][0]);
                acc[i][1] = fmaf(xv.x, w0.y, acc[i][1]); acc[i][1] = fmaf(xv.y, w1.y, acc[i][1]);
                acc[i][1] = fmaf(xv.z, w2.y, acc[i][1]); acc[i][1] = fmaf(xv.w, w3.y, acc[i][1]);
                acc[i][2] = fmaf(xv.x, w0.z, acc[i][2]); acc[i][2] = fmaf(xv.y, w1.z, acc[i][2]);
                acc[i][2] = fmaf(xv.z, w2.z, acc[i][2]); acc[i][2] = fmaf(xv.w, w3.z, acc[i][2]);
                acc[i][3] = fmaf(xv.x, w0.w, acc[i][3]); acc[i][3] = fmaf(xv.y, w1.w, acc[i][3]);
                acc[i][3] = fmaf(xv.z, w2.w, acc[i][3]); acc[i][3] = fmaf(xv.w, w3.w, acc[i][3]);
            }
        }
        float4 bb = *(const float4*)(b1 + c0);
        #pragma unroll
        for (int i = 0; i < 4; i++) {
            float o0 = acc[i][0] + bb.x, o1 = acc[i][1] + bb.y;
            float o2 = acc[i][2] + bb.z, o3 = acc[i][3] + bb.w;
            o0 = o0 > 0.f ? o0 : __expf(o0) - 1.f;
            o1 = o1 > 0.f ? o1 : __expf(o1) - 1.f;
            o2 = o2 > 0.f ? o2 : __expf(o2) - 1.f;
            o3 = o3 > 0.f ? o3 : __expf(o3) - 1.f;
            float4 ov = {o0, o1, o2, o3};
            *(float4*)(act + (g * 4 + i) * ACT_STRIDE + c0) = ov;
        }
    }
    __syncthreads();

    {   // ---- Phase C: h2 = act @ W2 (col-split, full-k per thread) ----
        const int n  = t >> 4;                 // node 0..15
        const int c0 = (t & 15) * 4;           // cols 0..63
        float a0 = 0.f, a1 = 0.f, a2 = 0.f, a3 = 0.f;
        const float* abase = act + n * ACT_STRIDE;
        for (int k = 0; k < C1; k += 4) {
            float4 xv = *(const float4*)(abase + k);
            float4 w0 = *(const float4*)(W2 + (size_t)(k + 0) * OUT_DIM + c0);
            float4 w1 = *(const float4*)(W2 + (size_t)(k + 1) * OUT_DIM + c0);
            float4 w2 = *(const float4*)(W2 + (size_t)(k + 2) * OUT_DIM + c0);
            float4 w3 = *(const float4*)(W2 + (size_t)(k + 3) * OUT_DIM + c0);
            a0 = fmaf(xv.x, w0.x, a0); a0 = fmaf(xv.y, w1.x, a0);
            a0 = fmaf(xv.z, w2.x, a0); a0 = fmaf(xv.w, w3.x, a0);
            a1 = fmaf(xv.x, w0.y, a1); a1 = fmaf(xv.y, w1.y, a1);
            a1 = fmaf(xv.z, w2.y, a1); a1 = fmaf(xv.w, w3.y, a1);
            a2 = fmaf(xv.x, w0.z, a2); a2 = fmaf(xv.y, w1.z, a2);
            a2 = fmaf(xv.z, w2.z, a2); a2 = fmaf(xv.w, w3.z, a2);
            a3 = fmaf(xv.x, w0.w, a3); a3 = fmaf(xv.y, w1.w, a3);
            a3 = fmaf(xv.z, w2.w, a3); a3 = fmaf(xv.w, w3.w, a3);
        }
        const int node = nodeBase + n;
        float4 hv = {a0, a1, a2, a3};
        *(float4*)(h2 + (size_t)node * OUT_DIM + c0) = hv;
        float4 aw = *(const float4*)(a_src2 + c0);
        float4 dw = *(const float4*)(a_dst2 + c0);
        float s = a0 * aw.x + a1 * aw.y + a2 * aw.z + a3 * aw.w;
        float d = a0 * dw.x + a1 * dw.y + a2 * dw.z + a3 * dw.w;
        #pragma unroll
        for (int off = 8; off; off >>= 1) {
            s += __shfl_down(s, off, 16);
            d += __shfl_down(d, off, 16);
        }
        if ((t & 15) == 0) { as2[node] = s; ad2[node] = d; }
    }
}

// ---------------------------------------------------------------------------
// Layer-2 aggregation + bias + fc dot, fused, unroll x4. One wave per node.
// ---------------------------------------------------------------------------
__global__ __launch_bounds__(256) void agg2_final_kernel(
    const int* __restrict__ rowptr, const int* __restrict__ srcS,
    const float* __restrict__ h2, const float* __restrict__ as2,
    const float* __restrict__ ad2, const float* __restrict__ b2,
    const float* __restrict__ fc_w, const float* __restrict__ fc_b,
    float* __restrict__ out)
{
    int gid  = blockIdx.x * blockDim.x + threadIdx.x;
    int n    = gid >> 6;
    int lane = threadIdx.x & 63;
    if (n >= N_NODES) return;
    const float adh = ad2[n];
    const int e0 = rowptr[n], e1 = rowptr[n + 1];

    float acc = 0.f, den = 0.f;
    int e = e0;
    for (; e + 4 <= e1; e += 4) {
        int s0 = srcS[e], s1 = srcS[e + 1], s2 = srcS[e + 2], s3 = srcS[e + 3];
        float a0 = as2[s0] + adh;
        float a1 = as2[s1] + adh;
        float a2 = as2[s2] + adh;
        float a3 = as2[s3] + adh;
        float v0 = h2[(size_t)s0 * OUT_DIM + lane];
        float v1 = h2[(size_t)s1 * OUT_DIM + lane];
        float v2 = h2[(size_t)s2 * OUT_DIM + lane];
        float v3 = h2[(size_t)s3 * OUT_DIM + lane];
        a0 = a0 > 0.f ? a0 : NEG_SLOPE * a0;
        a1 = a1 > 0.f ? a1 : NEG_SLOPE * a1;
        a2 = a2 > 0.f ? a2 : NEG_SLOPE * a2;
        a3 = a3 > 0.f ? a3 : NEG_SLOPE * a3;
        float w0 = __expf(a0), w1 = __expf(a1), w2 = __expf(a2), w3 = __expf(a3);
        acc = fmaf(w0, v0, acc); acc = fmaf(w1, v1, acc);
        acc = fmaf(w2, v2, acc); acc = fmaf(w3, v3, acc);
        den += (w0 + w1) + (w2 + w3);
    }
    for (; e < e1; e++) {
        int s = srcS[e];
        float a = as2[s] + adh;
        a = a > 0.f ? a : NEG_SLOPE * a;
        float w = __expf(a);
        acc = fmaf(w, h2[(size_t)s * OUT_DIM + lane], acc);
        den += w;
    }
    float v = acc / (den + 1e-16f) + b2[lane];
    float r = v * fc_w[lane];
    #pragma unroll
    for (int off = 32; off; off >>= 1) r += __shfl_down(r, off, 64);
    if (lane == 0) out[n] = r + fc_b[0];
}

extern "C" void kernel_launch(void* const* d_in, const int* in_sizes, int n_in,
                              void* d_out, int out_size, void* d_ws, size_t ws_size,
                              hipStream_t stream)
{
    const float* x      = (const float*)d_in[0];
    const int*   ei     = (const int*)d_in[1];
    const float* W1     = (const float*)d_in[2];
    const float* a_src1 = (const float*)d_in[3];
    const float* a_dst1 = (const float*)d_in[4];
    const float* b1     = (const float*)d_in[5];
    const float* W2     = (const float*)d_in[6];
    const float* a_src2 = (const float*)d_in[7];
    const float* a_dst2 = (const float*)d_in[8];
    const float* b2     = (const float*)d_in[9];
    const float* fc_w   = (const float*)d_in[10];
    const float* fc_b   = (const float*)d_in[11];
    float* out = (float*)d_out;

    const int* srcA = ei;
    const int* dstA = ei + N_EDGES;

    // workspace layout
    float* ws = (float*)d_ws;
    size_t off = 0;
    float* xagg    = ws + off; off += (size_t)N_NODES * HEADS * IN_DIM;  // 102.4 MB
    float* h2      = ws + off; off += (size_t)N_NODES * OUT_DIM;         //  12.8 MB
    float* as1     = ws + off; off += (size_t)N_NODES * HEADS;
    float* ad1     = ws + off; off += (size_t)N_NODES * HEADS;
    float* as2     = ws + off; off += N_NODES;
    float* ad2     = ws + off; off += N_NODES;
    float* p_src   = ws + off; off += IN_DIM * HEADS;
    float* p_dst   = ws + off; off += IN_DIM * HEADS;
    int* rowptr    = (int*)(ws + off); off += N_NODES + 2;
    int* srcSorted = (int*)(ws + off); off += E_TOT;
    int* zstart    = (int*)(ws + off);
    int* deg       = (int*)(ws + off); off += N_NODES;
    int* cursor    = (int*)(ws + off); off += N_NODES;
    hipMemsetAsync(zstart, 0, 2 * N_NODES * sizeof(int), stream);

    // CSR build
    count_kernel<<<(E_TOT + 255) / 256, 256, 0, stream>>>(dstA, deg);
    scan_kernel<<<1, 1024, 0, stream>>>(deg, rowptr);
    fill_kernel<<<(E_TOT + 255) / 256, 256, 0, stream>>>(srcA, dstA, rowptr, cursor, srcSorted);

    // layer-1 logit projections (h1 never materialized)
    prep_kernel<<<1, 512, 0, stream>>>(W1, a_src1, a_dst1, p_src, p_dst);
    proj1_kernel<<<N_NODES / 4, 256, 0, stream>>>(x, p_src, p_dst, as1, ad1);

    // layer-1 aggregation in x-space (latency-bound, high occupancy)
    agg1x_kernel<<<(N_NODES * 64 + 255) / 256, 256, 0, stream>>>(rowptr, srcSorted, x, as1, ad1, xagg);

    // fused MLP (VALU-dense, W read once per block, slim LDS)
    mlp2_kernel<<<N_NODES / 16, 256, 0, stream>>>(xagg, W1, b1, W2, a_src2, a_dst2, h2, as2, ad2);

    // layer 2 + final
    agg2_final_kernel<<<(N_NODES * 64 + 255) / 256, 256, 0, stream>>>(rowptr, srcSorted, h2, as2, ad2, b2, fc_w, fc_b, out);
}

// Round 7
// 512.001 us; speedup vs baseline: 1.1949x; 1.1949x over previous
//
#include <hip/hip_runtime.h>

#define N_NODES 50000
#define N_EDGES 800000
#define E_TOT   850000           // edges + self loops
#define IN_DIM  128
#define HID     64
#define HEADS   4
#define C1      256              // HEADS*HID
#define OUT_DIM 64
#define NEG_SLOPE 0.2f

#define XS_STRIDE   516          // 512+4: row offset 4 banks -> g-rows 2-way (free)
#define ACT_STRIDE  (C1 + 4)     // 260
#define PC_STRIDE   68           // 64+4
#define PC_WCHUNK   (16 * PC_STRIDE)

// ---------------------------------------------------------------------------
// CSR build (by destination): count -> exclusive scan -> fill
// ---------------------------------------------------------------------------
__global__ void count_kernel(const int* __restrict__ dst_a, int* __restrict__ deg)
{
    int j = blockIdx.x * blockDim.x + threadIdx.x;
    if (j >= E_TOT) return;
    int d = (j < N_EDGES) ? dst_a[j] : (j - N_EDGES);   // self loop
    atomicAdd(&deg[d], 1);
}

__global__ __launch_bounds__(1024) void scan_kernel(const int* __restrict__ deg,
                                                    int* __restrict__ rowptr)
{
    __shared__ int psum[1024];
    const int t = threadIdx.x;
    const int CH = (N_NODES + 1023) / 1024;            // 49
    const int base = t * CH;
    int s = 0;
    for (int i = 0; i < CH; i++) {
        int idx = base + i;
        if (idx < N_NODES) s += deg[idx];
    }
    psum[t] = s;
    __syncthreads();
    for (int off = 1; off < 1024; off <<= 1) {         // Hillis-Steele inclusive
        int v = (t >= off) ? psum[t - off] : 0;
        __syncthreads();
        psum[t] += v;
        __syncthreads();
    }
    int run = (t > 0) ? psum[t - 1] : 0;
    for (int i = 0; i < CH; i++) {
        int idx = base + i;
        if (idx < N_NODES) { rowptr[idx] = run; run += deg[idx]; }
    }
    if (t == 0) rowptr[N_NODES] = E_TOT;
}

__global__ void fill_kernel(const int* __restrict__ src_a, const int* __restrict__ dst_a,
                            const int* __restrict__ rowptr, int* __restrict__ cursor,
                            int* __restrict__ srcSorted)
{
    int j = blockIdx.x * blockDim.x + threadIdx.x;
    if (j >= E_TOT) return;
    int s, d;
    if (j < N_EDGES) { s = src_a[j]; d = dst_a[j]; }
    else             { s = j - N_EDGES; d = s; }
    int pos = atomicAdd(&cursor[d], 1);
    srcSorted[rowptr[d] + pos] = s;
}

// ---------------------------------------------------------------------------
// prep: p_src[k][h] = sum_c W1[k][h*64+c] * a_src1[h][c]  (and p_dst).
// ---------------------------------------------------------------------------
__global__ __launch_bounds__(512) void prep_kernel(
    const float* __restrict__ W1, const float* __restrict__ a_src1,
    const float* __restrict__ a_dst1,
    float* __restrict__ p_src, float* __restrict__ p_dst)
{
    const int t = threadIdx.x;                 // 512 = 128 k * 4 h
    const int k = t >> 2, h = t & 3;
    const float* wrow = W1 + k * C1 + h * HID;
    const float* as = a_src1 + h * HID;
    const float* ad = a_dst1 + h * HID;
    float s = 0.f, d = 0.f;
    for (int c = 0; c < HID; c++) {
        float w = wrow[c];
        s = fmaf(w, as[c], s);
        d = fmaf(w, ad[c], d);
    }
    p_src[k * HEADS + h] = s;
    p_dst[k * HEADS + h] = d;
}

// ---------------------------------------------------------------------------
// proj1: as1/ad1[n][4] = x[n] @ p_src / p_dst. One wave per node.
// ---------------------------------------------------------------------------
__global__ __launch_bounds__(256) void proj1_kernel(
    const float* __restrict__ x, const float* __restrict__ p_src,
    const float* __restrict__ p_dst, float* __restrict__ as1, float* __restrict__ ad1)
{
    __shared__ float ps[IN_DIM * HEADS];       // 2 KB
    __shared__ float pd[IN_DIM * HEADS];       // 2 KB
    const int t = threadIdx.x;
    for (int i = t; i < IN_DIM * HEADS; i += 256) { ps[i] = p_src[i]; pd[i] = p_dst[i]; }
    __syncthreads();
    const int node = blockIdx.x * 4 + (t >> 6);
    const int lane = t & 63;
    float2 xv = *(const float2*)(x + (size_t)node * IN_DIM + lane * 2);
    float4 p0 = *(const float4*)(ps + (lane * 2) * HEADS);
    float4 p1 = *(const float4*)(ps + (lane * 2 + 1) * HEADS);
    float4 q0 = *(const float4*)(pd + (lane * 2) * HEADS);
    float4 q1 = *(const float4*)(pd + (lane * 2 + 1) * HEADS);
    float s0 = xv.x * p0.x + xv.y * p1.x;
    float s1 = xv.x * p0.y + xv.y * p1.y;
    float s2 = xv.x * p0.z + xv.y * p1.z;
    float s3 = xv.x * p0.w + xv.y * p1.w;
    float d0 = xv.x * q0.x + xv.y * q1.x;
    float d1 = xv.x * q0.y + xv.y * q1.y;
    float d2 = xv.x * q0.z + xv.y * q1.z;
    float d3 = xv.x * q0.w + xv.y * q1.w;
    #pragma unroll
    for (int off = 32; off; off >>= 1) {
        s0 += __shfl_down(s0, off, 64); s1 += __shfl_down(s1, off, 64);
        s2 += __shfl_down(s2, off, 64); s3 += __shfl_down(s3, off, 64);
        d0 += __shfl_down(d0, off, 64); d1 += __shfl_down(d1, off, 64);
        d2 += __shfl_down(d2, off, 64); d3 += __shfl_down(d3, off, 64);
    }
    if (lane == 0) {
        float4 sv = {s0, s1, s2, s3};
        float4 dv = {d0, d1, d2, d3};
        *(float4*)(as1 + node * 4) = sv;
        *(float4*)(ad1 + node * 4) = dv;
    }
}

// ---------------------------------------------------------------------------
// agg1x: xagg[n][h][k] = softmax-weighted sum of x[src] rows. One wave per
// dst node, lane = 2 k-channels, 4 head-accumulators.
// ---------------------------------------------------------------------------
__global__ __launch_bounds__(256) void agg1x_kernel(
    const int* __restrict__ rowptr, const int* __restrict__ srcS,
    const float* __restrict__ x, const float* __restrict__ as1,
    const float* __restrict__ ad1, float* __restrict__ xagg)
{
    int gid  = blockIdx.x * blockDim.x + threadIdx.x;
    int n    = gid >> 6;
    int lane = threadIdx.x & 63;
    if (n >= N_NODES) return;
    float4 adv = *(const float4*)(ad1 + n * 4);
    const int e0 = rowptr[n], e1 = rowptr[n + 1];

    float2 acc0 = {0,0}, acc1 = {0,0}, acc2 = {0,0}, acc3 = {0,0};
    float den0 = 0, den1 = 0, den2 = 0, den3 = 0;
    int e = e0;
    for (; e + 2 <= e1; e += 2) {              // 2 row-loads in flight
        int s0 = srcS[e], s1 = srcS[e + 1];
        float4 A0 = *(const float4*)(as1 + s0 * 4);
        float4 A1 = *(const float4*)(as1 + s1 * 4);
        float2 xv0 = *(const float2*)(x + (size_t)s0 * IN_DIM + lane * 2);
        float2 xv1 = *(const float2*)(x + (size_t)s1 * IN_DIM + lane * 2);
        float a0 = A0.x + adv.x, a1 = A0.y + adv.y, a2 = A0.z + adv.z, a3 = A0.w + adv.w;
        a0 = a0 > 0.f ? a0 : NEG_SLOPE * a0;  a1 = a1 > 0.f ? a1 : NEG_SLOPE * a1;
        a2 = a2 > 0.f ? a2 : NEG_SLOPE * a2;  a3 = a3 > 0.f ? a3 : NEG_SLOPE * a3;
        float w0 = __expf(a0), w1 = __expf(a1), w2 = __expf(a2), w3 = __expf(a3);
        float b0 = A1.x + adv.x, b1v = A1.y + adv.y, b2v = A1.z + adv.z, b3 = A1.w + adv.w;
        b0 = b0 > 0.f ? b0 : NEG_SLOPE * b0;    b1v = b1v > 0.f ? b1v : NEG_SLOPE * b1v;
        b2v = b2v > 0.f ? b2v : NEG_SLOPE * b2v; b3 = b3 > 0.f ? b3 : NEG_SLOPE * b3;
        float u0 = __expf(b0), u1 = __expf(b1v), u2 = __expf(b2v), u3 = __expf(b3);
        acc0.x = fmaf(w0, xv0.x, acc0.x); acc0.y = fmaf(w0, xv0.y, acc0.y);
        acc1.x = fmaf(w1, xv0.x, acc1.x); acc1.y = fmaf(w1, xv0.y, acc1.y);
        acc2.x = fmaf(w2, xv0.x, acc2.x); acc2.y = fmaf(w2, xv0.y, acc2.y);
        acc3.x = fmaf(w3, xv0.x, acc3.x); acc3.y = fmaf(w3, xv0.y, acc3.y);
        acc0.x = fmaf(u0, xv1.x, acc0.x); acc0.y = fmaf(u0, xv1.y, acc0.y);
        acc1.x = fmaf(u1, xv1.x, acc1.x); acc1.y = fmaf(u1, xv1.y, acc1.y);
        acc2.x = fmaf(u2, xv1.x, acc2.x); acc2.y = fmaf(u2, xv1.y, acc2.y);
        acc3.x = fmaf(u3, xv1.x, acc3.x); acc3.y = fmaf(u3, xv1.y, acc3.y);
        den0 += w0 + u0; den1 += w1 + u1; den2 += w2 + u2; den3 += w3 + u3;
    }
    for (; e < e1; e++) {
        int s = srcS[e];
        float4 A0 = *(const float4*)(as1 + s * 4);
        float2 xv = *(const float2*)(x + (size_t)s * IN_DIM + lane * 2);
        float a0 = A0.x + adv.x, a1 = A0.y + adv.y, a2 = A0.z + adv.z, a3 = A0.w + adv.w;
        a0 = a0 > 0.f ? a0 : NEG_SLOPE * a0;  a1 = a1 > 0.f ? a1 : NEG_SLOPE * a1;
        a2 = a2 > 0.f ? a2 : NEG_SLOPE * a2;  a3 = a3 > 0.f ? a3 : NEG_SLOPE * a3;
        float w0 = __expf(a0), w1 = __expf(a1), w2 = __expf(a2), w3 = __expf(a3);
        acc0.x = fmaf(w0, xv.x, acc0.x); acc0.y = fmaf(w0, xv.y, acc0.y);
        acc1.x = fmaf(w1, xv.x, acc1.x); acc1.y = fmaf(w1, xv.y, acc1.y);
        acc2.x = fmaf(w2, xv.x, acc2.x); acc2.y = fmaf(w2, xv.y, acc2.y);
        acc3.x = fmaf(w3, xv.x, acc3.x); acc3.y = fmaf(w3, xv.y, acc3.y);
        den0 += w0; den1 += w1; den2 += w2; den3 += w3;
    }
    float i0 = 1.f / (den0 + 1e-16f), i1 = 1.f / (den1 + 1e-16f);
    float i2 = 1.f / (den2 + 1e-16f), i3 = 1.f / (den3 + 1e-16f);
    float* o = xagg + (size_t)n * (HEADS * IN_DIM) + lane * 2;
    float2 r0 = {acc0.x * i0, acc0.y * i0};
    float2 r1 = {acc1.x * i1, acc1.y * i1};
    float2 r2 = {acc2.x * i2, acc2.y * i2};
    float2 r3 = {acc3.x * i3, acc3.y * i3};
    *(float2*)(o + 0 * IN_DIM) = r0;
    *(float2*)(o + 1 * IN_DIM) = r1;
    *(float2*)(o + 2 * IN_DIM) = r2;
    *(float2*)(o + 3 * IN_DIM) = r3;
}

// ---------------------------------------------------------------------------
// mlp3: 16 nodes per block, 256 threads, min 3 waves/EU (VGPR cap ~170 so the
// compiler can keep prefetched W tiles in flight — mlp2's VGPR=32 serialized).
//  Phase A: stage xagg tile -> LDS (flat mapping, conflict-free b128 writes)
//  Phase B: act = ELU(xs @ W1 + b1); wave = head (W1 once/block), W1
//           software-prefetched one k-iter ahead, xs via LDS broadcast.
//  Phase C: h2 = act @ W2, k-split across waves (W2 once/block), prefetched;
//           partials in LDS (aliasing xs), reduce + as2/ad2 epilogue.
// ---------------------------------------------------------------------------
__global__ __launch_bounds__(256, 3) void mlp3_kernel(
    const float* __restrict__ xagg,
    const float* __restrict__ W1, const float* __restrict__ b1,
    const float* __restrict__ W2,
    const float* __restrict__ a_src2, const float* __restrict__ a_dst2,
    float* __restrict__ h2, float* __restrict__ as2, float* __restrict__ ad2)
{
    __shared__ float xs[16 * XS_STRIDE];       // 33,024 B (aliased as pc later)
    __shared__ float act[16 * ACT_STRIDE];     // 16,640 B
    const int t = threadIdx.x;
    const int nodeBase = blockIdx.x * 16;
    const int wv = t >> 6;

    {   // ---- Phase A: stage 16x512 xagg tile, flat (lanes consecutive) ----
        const float* gsrc = xagg + (size_t)nodeBase * (HEADS * IN_DIM);
        #pragma unroll
        for (int i = 0; i < 8; i++) {
            int idx = i * 1024 + t * 4;        // 8192 floats total
            float4 v = *(const float4*)(gsrc + idx);
            int n = idx >> 9, c = idx & 511;
            *(float4*)(xs + n * XS_STRIDE + c) = v;
        }
    }
    __syncthreads();

    {   // ---- Phase B: act = ELU(xs @ W1 + b1). wave = head, W1 prefetch ----
        const int q  = t & 15;                 // col-quad within head
        const int g  = (t >> 4) & 3;           // node group (4 nodes)
        const int h  = wv;                     // head = wave
        const int c0 = h * HID + q * 4;
        const float* Wp = W1 + c0;
        float4 w0 = *(const float4*)(Wp + (size_t)0 * C1);
        float4 w1 = *(const float4*)(Wp + (size_t)1 * C1);
        float4 w2 = *(const float4*)(Wp + (size_t)2 * C1);
        float4 w3 = *(const float4*)(Wp + (size_t)3 * C1);
        float acc[4][4];
        #pragma unroll
        for (int i = 0; i < 4; i++)
            #pragma unroll
            for (int m = 0; m < 4; m++) acc[i][m] = 0.f;
        const float* xbase = xs + (g * 4) * XS_STRIDE + h * IN_DIM;
        for (int k = 0; k < IN_DIM; k += 4) {
            const int kn = (k + 4 < IN_DIM) ? k + 4 : k;   // clamped prefetch
            float4 nw0 = *(const float4*)(Wp + (size_t)(kn + 0) * C1);
            float4 nw1 = *(const float4*)(Wp + (size_t)(kn + 1) * C1);
            float4 nw2 = *(const float4*)(Wp + (size_t)(kn + 2) * C1);
            float4 nw3 = *(const float4*)(Wp + (size_t)(kn + 3) * C1);
            #pragma unroll
            for (int i = 0; i < 4; i++) {
                float4 xv = *(const float4*)(xbase + i * XS_STRIDE + k);
                acc[i][0] = fmaf(xv.x, w0.x, acc[i][0]); acc[i][0] = fmaf(xv.y, w1.x, acc[i][0]);
                acc[i][0] = fmaf(xv.z, w2.x, acc[i][0]); acc[i][0] = fmaf(xv.w, w3.x, acc[i][0]);
                acc[i][1] = fmaf(xv.x, w0.y, acc[i][1]); acc[i][1] = fmaf(xv.y, w1.y, acc[i][1]);
                acc[i][1] = fmaf(xv.z, w2.y, acc[i][1]); acc[i][1] = fmaf(xv.w, w3.y, acc[i][1]);
                acc[i][2] = fmaf(xv.x, w0.z, acc[i][2]); acc[i][2] = fmaf(xv.y, w1.z, acc[i][2]);
                acc[i][2] = fmaf(xv.z, w2.z, acc[i][2]); acc[i][2] = fmaf(xv.w, w3.z, acc[i][2]);
                acc[i][3] = fmaf(xv.x, w0.w, acc[i][3]); acc[i][3] = fmaf(xv.y, w1.w, acc[i][3]);
                acc[i][3] = fmaf(xv.z, w2.w, acc[i][3]); acc[i][3] = fmaf(xv.w, w3.w, acc[i][3]);
            }
            w0 = nw0; w1 = nw1; w2 = nw2; w3 = nw3;
        }
        float4 bb = *(const float4*)(b1 + c0);
        #pragma unroll
        for (int i = 0; i < 4; i++) {
            float o0 = acc[i][0] + bb.x, o1 = acc[i][1] + bb.y;
            float o2 = acc[i][2] + bb.z, o3 = acc[i][3] + bb.w;
            o0 = o0 > 0.f ? o0 : __expf(o0) - 1.f;
            o1 = o1 > 0.f ? o1 : __expf(o1) - 1.f;
            o2 = o2 > 0.f ? o2 : __expf(o2) - 1.f;
            o3 = o3 > 0.f ? o3 : __expf(o3) - 1.f;
            float4 ov = {o0, o1, o2, o3};
            *(float4*)(act + (g * 4 + i) * ACT_STRIDE + c0) = ov;
        }
    }
    __syncthreads();

    {   // ---- Phase C: h2 = act @ W2, k-split across waves, W2 prefetch ----
        const int q  = t & 15;                 // c-quad: cols q*4..q*4+3
        const int ng = (t >> 4) & 3;           // node group
        const int kb = wv * 64;                // this wave's k-chunk
        const float* Wp = W2 + q * 4;
        float4 w0 = *(const float4*)(Wp + (size_t)(kb + 0) * OUT_DIM);
        float4 w1 = *(const float4*)(Wp + (size_t)(kb + 1) * OUT_DIM);
        float4 w2 = *(const float4*)(Wp + (size_t)(kb + 2) * OUT_DIM);
        float4 w3 = *(const float4*)(Wp + (size_t)(kb + 3) * OUT_DIM);
        float a[4][4];
        #pragma unroll
        for (int i = 0; i < 4; i++)
            #pragma unroll
            for (int m = 0; m < 4; m++) a[i][m] = 0.f;
        for (int kk = 0; kk < 64; kk += 4) {
            const int knn = (kk + 4 < 64) ? kk + 4 : kk;
            const int kp = kb + knn;
            float4 nw0 = *(const float4*)(Wp + (size_t)(kp + 0) * OUT_DIM);
            float4 nw1 = *(const float4*)(Wp + (size_t)(kp + 1) * OUT_DIM);
            float4 nw2 = *(const float4*)(Wp + (size_t)(kp + 2) * OUT_DIM);
            float4 nw3 = *(const float4*)(Wp + (size_t)(kp + 3) * OUT_DIM);
            const int k = kb + kk;
            #pragma unroll
            for (int i = 0; i < 4; i++) {
                float4 xv = *(const float4*)(act + (ng * 4 + i) * ACT_STRIDE + k);
                a[i][0] = fmaf(xv.x, w0.x, a[i][0]); a[i][0] = fmaf(xv.y, w1.x, a[i][0]);
                a[i][0] = fmaf(xv.z, w2.x, a[i][0]); a[i][0] = fmaf(xv.w, w3.x, a[i][0]);
                a[i][1] = fmaf(xv.x, w0.y, a[i][1]); a[i][1] = fmaf(xv.y, w1.y, a[i][1]);
                a[i][1] = fmaf(xv.z, w2.y, a[i][1]); a[i][1] = fmaf(xv.w, w3.y, a[i][1]);
                a[i][2] = fmaf(xv.x, w0.z, a[i][2]); a[i][2] = fmaf(xv.y, w1.z, a[i][2]);
                a[i][2] = fmaf(xv.z, w2.z, a[i][2]); a[i][2] = fmaf(xv.w, w3.z, a[i][2]);
                a[i][3] = fmaf(xv.x, w0.w, a[i][3]); a[i][3] = fmaf(xv.y, w1.w, a[i][3]);
                a[i][3] = fmaf(xv.z, w2.w, a[i][3]); a[i][3] = fmaf(xv.w, w3.w, a[i][3]);
            }
            w0 = nw0; w1 = nw1; w2 = nw2; w3 = nw3;
        }
        float* pc = xs;                        // alias: xs no longer needed
        #pragma unroll
        for (int i = 0; i < 4; i++) {
            float4 pv = {a[i][0], a[i][1], a[i][2], a[i][3]};
            *(float4*)(pc + wv * PC_WCHUNK + (ng * 4 + i) * PC_STRIDE + q * 4) = pv;
        }
    }
    __syncthreads();

    {   // ---- Reduce partials + epilogue ----
        const float* pc = xs;
        const int n  = t >> 4;                 // node 0..15
        const int c0 = (t & 15) * 4;           // cols 0..63
        float4 r = {0, 0, 0, 0};
        #pragma unroll
        for (int w = 0; w < 4; w++) {
            float4 p = *(const float4*)(pc + w * PC_WCHUNK + n * PC_STRIDE + c0);
            r.x += p.x; r.y += p.y; r.z += p.z; r.w += p.w;
        }
        const int node = nodeBase + n;
        *(float4*)(h2 + (size_t)node * OUT_DIM + c0) = r;
        float4 aw = *(const float4*)(a_src2 + c0);
        float4 dw = *(const float4*)(a_dst2 + c0);
        float s = r.x * aw.x + r.y * aw.y + r.z * aw.z + r.w * aw.w;
        float d = r.x * dw.x + r.y * dw.y + r.z * dw.z + r.w * dw.w;
        #pragma unroll
        for (int off = 8; off; off >>= 1) {
            s += __shfl_down(s, off, 16);
            d += __shfl_down(d, off, 16);
        }
        if ((t & 15) == 0) { as2[node] = s; ad2[node] = d; }
    }
}

// ---------------------------------------------------------------------------
// Layer-2 aggregation + bias + fc dot, fused, unroll x4. One wave per node.
// ---------------------------------------------------------------------------
__global__ __launch_bounds__(256) void agg2_final_kernel(
    const int* __restrict__ rowptr, const int* __restrict__ srcS,
    const float* __restrict__ h2, const float* __restrict__ as2,
    const float* __restrict__ ad2, const float* __restrict__ b2,
    const float* __restrict__ fc_w, const float* __restrict__ fc_b,
    float* __restrict__ out)
{
    int gid  = blockIdx.x * blockDim.x + threadIdx.x;
    int n    = gid >> 6;
    int lane = threadIdx.x & 63;
    if (n >= N_NODES) return;
    const float adh = ad2[n];
    const int e0 = rowptr[n], e1 = rowptr[n + 1];

    float acc = 0.f, den = 0.f;
    int e = e0;
    for (; e + 4 <= e1; e += 4) {
        int s0 = srcS[e], s1 = srcS[e + 1], s2 = srcS[e + 2], s3 = srcS[e + 3];
        float a0 = as2[s0] + adh;
        float a1 = as2[s1] + adh;
        float a2 = as2[s2] + adh;
        float a3 = as2[s3] + adh;
        float v0 = h2[(size_t)s0 * OUT_DIM + lane];
        float v1 = h2[(size_t)s1 * OUT_DIM + lane];
        float v2 = h2[(size_t)s2 * OUT_DIM + lane];
        float v3 = h2[(size_t)s3 * OUT_DIM + lane];
        a0 = a0 > 0.f ? a0 : NEG_SLOPE * a0;
        a1 = a1 > 0.f ? a1 : NEG_SLOPE * a1;
        a2 = a2 > 0.f ? a2 : NEG_SLOPE * a2;
        a3 = a3 > 0.f ? a3 : NEG_SLOPE * a3;
        float w0 = __expf(a0), w1 = __expf(a1), w2 = __expf(a2), w3 = __expf(a3);
        acc = fmaf(w0, v0, acc); acc = fmaf(w1, v1, acc);
        acc = fmaf(w2, v2, acc); acc = fmaf(w3, v3, acc);
        den += (w0 + w1) + (w2 + w3);
    }
    for (; e < e1; e++) {
        int s = srcS[e];
        float a = as2[s] + adh;
        a = a > 0.f ? a : NEG_SLOPE * a;
        float w = __expf(a);
        acc = fmaf(w, h2[(size_t)s * OUT_DIM + lane], acc);
        den += w;
    }
    float v = acc / (den + 1e-16f) + b2[lane];
    float r = v * fc_w[lane];
    #pragma unroll
    for (int off = 32; off; off >>= 1) r += __shfl_down(r, off, 64);
    if (lane == 0) out[n] = r + fc_b[0];
}

extern "C" void kernel_launch(void* const* d_in, const int* in_sizes, int n_in,
                              void* d_out, int out_size, void* d_ws, size_t ws_size,
                              hipStream_t stream)
{
    const float* x      = (const float*)d_in[0];
    const int*   ei     = (const int*)d_in[1];
    const float* W1     = (const float*)d_in[2];
    const float* a_src1 = (const float*)d_in[3];
    const float* a_dst1 = (const float*)d_in[4];
    const float* b1     = (const float*)d_in[5];
    const float* W2     = (const float*)d_in[6];
    const float* a_src2 = (const float*)d_in[7];
    const float* a_dst2 = (const float*)d_in[8];
    const float* b2     = (const float*)d_in[9];
    const float* fc_w   = (const float*)d_in[10];
    const float* fc_b   = (const float*)d_in[11];
    float* out = (float*)d_out;

    const int* srcA = ei;
    const int* dstA = ei + N_EDGES;

    // workspace layout
    float* ws = (float*)d_ws;
    size_t off = 0;
    float* xagg    = ws + off; off += (size_t)N_NODES * HEADS * IN_DIM;  // 102.4 MB
    float* h2      = ws + off; off += (size_t)N_NODES * OUT_DIM;         //  12.8 MB
    float* as1     = ws + off; off += (size_t)N_NODES * HEADS;
    float* ad1     = ws + off; off += (size_t)N_NODES * HEADS;
    float* as2     = ws + off; off += N_NODES;
    float* ad2     = ws + off; off += N_NODES;
    float* p_src   = ws + off; off += IN_DIM * HEADS;
    float* p_dst   = ws + off; off += IN_DIM * HEADS;
    int* rowptr    = (int*)(ws + off); off += N_NODES + 2;
    int* srcSorted = (int*)(ws + off); off += E_TOT;
    int* zstart    = (int*)(ws + off);
    int* deg       = (int*)(ws + off); off += N_NODES;
    int* cursor    = (int*)(ws + off); off += N_NODES;
    hipMemsetAsync(zstart, 0, 2 * N_NODES * sizeof(int), stream);

    // CSR build
    count_kernel<<<(E_TOT + 255) / 256, 256, 0, stream>>>(dstA, deg);
    scan_kernel<<<1, 1024, 0, stream>>>(deg, rowptr);
    fill_kernel<<<(E_TOT + 255) / 256, 256, 0, stream>>>(srcA, dstA, rowptr, cursor, srcSorted);

    // layer-1 logit projections (h1 never materialized)
    prep_kernel<<<1, 512, 0, stream>>>(W1, a_src1, a_dst1, p_src, p_dst);
    proj1_kernel<<<N_NODES / 4, 256, 0, stream>>>(x, p_src, p_dst, as1, ad1);

    // layer-1 aggregation in x-space (latency-bound, high occupancy)
    agg1x_kernel<<<(N_NODES * 64 + 255) / 256, 256, 0, stream>>>(rowptr, srcSorted, x, as1, ad1, xagg);

    // fused MLP: LDS-staged, W once/block, prefetched
    mlp3_kernel<<<N_NODES / 16, 256, 0, stream>>>(xagg, W1, b1, W2, a_src2, a_dst2, h2, as2, ad2);

    // layer 2 + final
    agg2_final_kernel<<<(N_NODES * 64 + 255) / 256, 256, 0, stream>>>(rowptr, srcSorted, h2, as2, ad2, b2, fc_w, fc_b, out);
}

// Round 8
// 495.260 us; speedup vs baseline: 1.2353x; 1.0338x over previous
//
#include <hip/hip_runtime.h>

#define N_NODES 50000
#define N_EDGES 800000
#define E_TOT   850000           // edges + self loops
#define IN_DIM  128
#define HID     64
#define HEADS   4
#define C1      256              // HEADS*HID
#define OUT_DIM 64
#define NEG_SLOPE 0.2f

#define XS_STRIDE   516          // 512+4 floats
#define ACT_STRIDE  (C1 + 4)     // 260
#define PC_STRIDE   68           // 64+4
#define PC_WCHUNK   (16 * PC_STRIDE)

#define PROJ_BLOCKS (N_NODES / 4)                  // 12500
#define COUNT_BLOCKS ((E_TOT + 255) / 256)         // 3321

// ---- bf16 helpers (manual: bf16 = top 16 bits of fp32, RNE) ----------------
__device__ __forceinline__ unsigned int bf16_rne(float f) {
    unsigned int u = __float_as_uint(f);
    return (u + 0x7FFFu + ((u >> 16) & 1u)) >> 16;
}
__device__ __forceinline__ unsigned int bf16_pack2(float a, float b) {
    return bf16_rne(a) | (bf16_rne(b) << 16);
}
__device__ __forceinline__ float bf16_lo(unsigned int u) { return __uint_as_float(u << 16); }
__device__ __forceinline__ float bf16_hi(unsigned int u) { return __uint_as_float(u & 0xFFFF0000u); }

// ---------------------------------------------------------------------------
// prep: p_src[k][h] = sum_c W1[k][h*64+c] * a_src1[h][c]  (and p_dst).
// ---------------------------------------------------------------------------
__global__ __launch_bounds__(512) void prep_kernel(
    const float* __restrict__ W1, const float* __restrict__ a_src1,
    const float* __restrict__ a_dst1,
    float* __restrict__ p_src, float* __restrict__ p_dst)
{
    const int t = threadIdx.x;                 // 512 = 128 k * 4 h
    const int k = t >> 2, h = t & 3;
    const float* wrow = W1 + k * C1 + h * HID;
    const float* as = a_src1 + h * HID;
    const float* ad = a_dst1 + h * HID;
    float s = 0.f, d = 0.f;
    for (int c = 0; c < HID; c++) {
        float w = wrow[c];
        s = fmaf(w, as[c], s);
        d = fmaf(w, ad[c], d);
    }
    p_src[k * HEADS + h] = s;
    p_dst[k * HEADS + h] = d;
}

// ---------------------------------------------------------------------------
// convproj_count: fused launch.
//  Blocks [0, PROJ_BLOCKS): per-node logit projections as1/ad1 AND x -> bf16
//    (one pass over x). One wave per node, lane = 2 channels.
//  Blocks [PROJ_BLOCKS, +COUNT_BLOCKS): per-edge degree count (CSR step 1).
// ---------------------------------------------------------------------------
__global__ __launch_bounds__(256) void convproj_count_kernel(
    const float* __restrict__ x, const float* __restrict__ p_src,
    const float* __restrict__ p_dst, const int* __restrict__ dst_a,
    float* __restrict__ as1, float* __restrict__ ad1,
    unsigned int* __restrict__ xb, int* __restrict__ deg)
{
    if (blockIdx.x >= PROJ_BLOCKS) {           // ---- count part ----
        int j = (blockIdx.x - PROJ_BLOCKS) * 256 + threadIdx.x;
        if (j < E_TOT) {
            int d = (j < N_EDGES) ? dst_a[j] : (j - N_EDGES);   // self loop
            atomicAdd(&deg[d], 1);
        }
        return;
    }
    // ---- proj + convert part ----
    __shared__ float ps[IN_DIM * HEADS];       // 2 KB
    __shared__ float pd[IN_DIM * HEADS];       // 2 KB
    const int t = threadIdx.x;
    for (int i = t; i < IN_DIM * HEADS; i += 256) { ps[i] = p_src[i]; pd[i] = p_dst[i]; }
    __syncthreads();
    const int node = blockIdx.x * 4 + (t >> 6);
    const int lane = t & 63;
    float2 xv = *(const float2*)(x + (size_t)node * IN_DIM + lane * 2);
    xb[(size_t)node * 64 + lane] = bf16_pack2(xv.x, xv.y);
    float4 p0 = *(const float4*)(ps + (lane * 2) * HEADS);
    float4 p1 = *(const float4*)(ps + (lane * 2 + 1) * HEADS);
    float4 q0 = *(const float4*)(pd + (lane * 2) * HEADS);
    float4 q1 = *(const float4*)(pd + (lane * 2 + 1) * HEADS);
    float s0 = xv.x * p0.x + xv.y * p1.x;
    float s1 = xv.x * p0.y + xv.y * p1.y;
    float s2 = xv.x * p0.z + xv.y * p1.z;
    float s3 = xv.x * p0.w + xv.y * p1.w;
    float d0 = xv.x * q0.x + xv.y * q1.x;
    float d1 = xv.x * q0.y + xv.y * q1.y;
    float d2 = xv.x * q0.z + xv.y * q1.z;
    float d3 = xv.x * q0.w + xv.y * q1.w;
    #pragma unroll
    for (int off = 32; off; off >>= 1) {
        s0 += __shfl_down(s0, off, 64); s1 += __shfl_down(s1, off, 64);
        s2 += __shfl_down(s2, off, 64); s3 += __shfl_down(s3, off, 64);
        d0 += __shfl_down(d0, off, 64); d1 += __shfl_down(d1, off, 64);
        d2 += __shfl_down(d2, off, 64); d3 += __shfl_down(d3, off, 64);
    }
    if (lane == 0) {
        float4 sv = {s0, s1, s2, s3};
        float4 dv = {d0, d1, d2, d3};
        *(float4*)(as1 + node * 4) = sv;
        *(float4*)(ad1 + node * 4) = dv;
    }
}

// ---------------------------------------------------------------------------
// scan + fill: CSR steps 2/3
// ---------------------------------------------------------------------------
__global__ __launch_bounds__(1024) void scan_kernel(const int* __restrict__ deg,
                                                    int* __restrict__ rowptr)
{
    __shared__ int psum[1024];
    const int t = threadIdx.x;
    const int CH = (N_NODES + 1023) / 1024;            // 49
    const int base = t * CH;
    int s = 0;
    for (int i = 0; i < CH; i++) {
        int idx = base + i;
        if (idx < N_NODES) s += deg[idx];
    }
    psum[t] = s;
    __syncthreads();
    for (int off = 1; off < 1024; off <<= 1) {
        int v = (t >= off) ? psum[t - off] : 0;
        __syncthreads();
        psum[t] += v;
        __syncthreads();
    }
    int run = (t > 0) ? psum[t - 1] : 0;
    for (int i = 0; i < CH; i++) {
        int idx = base + i;
        if (idx < N_NODES) { rowptr[idx] = run; run += deg[idx]; }
    }
    if (t == 0) rowptr[N_NODES] = E_TOT;
}

__global__ void fill_kernel(const int* __restrict__ src_a, const int* __restrict__ dst_a,
                            const int* __restrict__ rowptr, int* __restrict__ cursor,
                            int* __restrict__ srcSorted)
{
    int j = blockIdx.x * blockDim.x + threadIdx.x;
    if (j >= E_TOT) return;
    int s, d;
    if (j < N_EDGES) { s = src_a[j]; d = dst_a[j]; }
    else             { s = j - N_EDGES; d = s; }
    int pos = atomicAdd(&cursor[d], 1);
    srcSorted[rowptr[d] + pos] = s;
}

// ---------------------------------------------------------------------------
// agg1x: xaggb[n][h][k] (bf16) = softmax-weighted sum of xb[src] rows (bf16).
// One wave per dst node, lane = 2 k-channels (one packed uint), fp32 accum.
// ---------------------------------------------------------------------------
__global__ __launch_bounds__(256) void agg1x_kernel(
    const int* __restrict__ rowptr, const int* __restrict__ srcS,
    const unsigned int* __restrict__ xb, const float* __restrict__ as1,
    const float* __restrict__ ad1, unsigned int* __restrict__ xaggb)
{
    int gid  = blockIdx.x * blockDim.x + threadIdx.x;
    int n    = gid >> 6;
    int lane = threadIdx.x & 63;
    if (n >= N_NODES) return;
    float4 adv = *(const float4*)(ad1 + n * 4);
    const int e0 = rowptr[n], e1 = rowptr[n + 1];

    float2 acc0 = {0,0}, acc1 = {0,0}, acc2 = {0,0}, acc3 = {0,0};
    float den0 = 0, den1 = 0, den2 = 0, den3 = 0;
    int e = e0;
    for (; e + 2 <= e1; e += 2) {
        int s0 = srcS[e], s1 = srcS[e + 1];
        float4 A0 = *(const float4*)(as1 + s0 * 4);
        float4 A1 = *(const float4*)(as1 + s1 * 4);
        unsigned int xu0 = xb[(size_t)s0 * 64 + lane];
        unsigned int xu1 = xb[(size_t)s1 * 64 + lane];
        float a0 = A0.x + adv.x, a1 = A0.y + adv.y, a2 = A0.z + adv.z, a3 = A0.w + adv.w;
        a0 = a0 > 0.f ? a0 : NEG_SLOPE * a0;  a1 = a1 > 0.f ? a1 : NEG_SLOPE * a1;
        a2 = a2 > 0.f ? a2 : NEG_SLOPE * a2;  a3 = a3 > 0.f ? a3 : NEG_SLOPE * a3;
        float w0 = __expf(a0), w1 = __expf(a1), w2 = __expf(a2), w3 = __expf(a3);
        float b0 = A1.x + adv.x, b1v = A1.y + adv.y, b2v = A1.z + adv.z, b3 = A1.w + adv.w;
        b0 = b0 > 0.f ? b0 : NEG_SLOPE * b0;    b1v = b1v > 0.f ? b1v : NEG_SLOPE * b1v;
        b2v = b2v > 0.f ? b2v : NEG_SLOPE * b2v; b3 = b3 > 0.f ? b3 : NEG_SLOPE * b3;
        float u0 = __expf(b0), u1 = __expf(b1v), u2 = __expf(b2v), u3 = __expf(b3);
        float xa = bf16_lo(xu0), xbv = bf16_hi(xu0);
        float ya = bf16_lo(xu1), ybv = bf16_hi(xu1);
        acc0.x = fmaf(w0, xa, acc0.x); acc0.y = fmaf(w0, xbv, acc0.y);
        acc1.x = fmaf(w1, xa, acc1.x); acc1.y = fmaf(w1, xbv, acc1.y);
        acc2.x = fmaf(w2, xa, acc2.x); acc2.y = fmaf(w2, xbv, acc2.y);
        acc3.x = fmaf(w3, xa, acc3.x); acc3.y = fmaf(w3, xbv, acc3.y);
        acc0.x = fmaf(u0, ya, acc0.x); acc0.y = fmaf(u0, ybv, acc0.y);
        acc1.x = fmaf(u1, ya, acc1.x); acc1.y = fmaf(u1, ybv, acc1.y);
        acc2.x = fmaf(u2, ya, acc2.x); acc2.y = fmaf(u2, ybv, acc2.y);
        acc3.x = fmaf(u3, ya, acc3.x); acc3.y = fmaf(u3, ybv, acc3.y);
        den0 += w0 + u0; den1 += w1 + u1; den2 += w2 + u2; den3 += w3 + u3;
    }
    for (; e < e1; e++) {
        int s = srcS[e];
        float4 A0 = *(const float4*)(as1 + s * 4);
        unsigned int xu = xb[(size_t)s * 64 + lane];
        float a0 = A0.x + adv.x, a1 = A0.y + adv.y, a2 = A0.z + adv.z, a3 = A0.w + adv.w;
        a0 = a0 > 0.f ? a0 : NEG_SLOPE * a0;  a1 = a1 > 0.f ? a1 : NEG_SLOPE * a1;
        a2 = a2 > 0.f ? a2 : NEG_SLOPE * a2;  a3 = a3 > 0.f ? a3 : NEG_SLOPE * a3;
        float w0 = __expf(a0), w1 = __expf(a1), w2 = __expf(a2), w3 = __expf(a3);
        float xa = bf16_lo(xu), xbv = bf16_hi(xu);
        acc0.x = fmaf(w0, xa, acc0.x); acc0.y = fmaf(w0, xbv, acc0.y);
        acc1.x = fmaf(w1, xa, acc1.x); acc1.y = fmaf(w1, xbv, acc1.y);
        acc2.x = fmaf(w2, xa, acc2.x); acc2.y = fmaf(w2, xbv, acc2.y);
        acc3.x = fmaf(w3, xa, acc3.x); acc3.y = fmaf(w3, xbv, acc3.y);
        den0 += w0; den1 += w1; den2 += w2; den3 += w3;
    }
    float i0 = 1.f / (den0 + 1e-16f), i1 = 1.f / (den1 + 1e-16f);
    float i2 = 1.f / (den2 + 1e-16f), i3 = 1.f / (den3 + 1e-16f);
    unsigned int* o = xaggb + (size_t)n * 256 + lane;      // row = 256 uints
    o[0 * 64] = bf16_pack2(acc0.x * i0, acc0.y * i0);
    o[1 * 64] = bf16_pack2(acc1.x * i1, acc1.y * i1);
    o[2 * 64] = bf16_pack2(acc2.x * i2, acc2.y * i2);
    o[3 * 64] = bf16_pack2(acc3.x * i3, acc3.y * i3);
}

// ---------------------------------------------------------------------------
// mlp4: 16 nodes/block, min 3 waves/EU.
//  Phase A: stage bf16 xagg tile -> fp32 LDS (convert on the fly)
//  Phase B: act = ELU(xs @ W1 + b1); wave = head (W1 once/block), prefetched
//  Phase C: h2 = act @ W2, k-split (W2 once/block), prefetched; LDS reduce.
//  Epilogue: h2 stored as bf16; as2/ad2 fp32.
// ---------------------------------------------------------------------------
__global__ __launch_bounds__(256, 3) void mlp4_kernel(
    const unsigned int* __restrict__ xaggb,
    const float* __restrict__ W1, const float* __restrict__ b1,
    const float* __restrict__ W2,
    const float* __restrict__ a_src2, const float* __restrict__ a_dst2,
    unsigned int* __restrict__ h2b, float* __restrict__ as2, float* __restrict__ ad2)
{
    __shared__ float xs[16 * XS_STRIDE];       // 33,024 B (aliased as pc later)
    __shared__ float act[16 * ACT_STRIDE];     // 16,640 B
    const int t = threadIdx.x;
    const int nodeBase = blockIdx.x * 16;
    const int wv = t >> 6;

    {   // ---- Phase A: stage 16x512ch (bf16) -> fp32 LDS ----
        const unsigned int* gsrc = xaggb + (size_t)nodeBase * 256;
        #pragma unroll
        for (int i = 0; i < 4; i++) {
            int iu = i * 1024 + t * 4;         // uint index in 4096-uint tile
            uint4 v = *(const uint4*)(gsrc + iu);
            int n = iu >> 8, c = (iu & 255) * 2;
            float4 f0 = {bf16_lo(v.x), bf16_hi(v.x), bf16_lo(v.y), bf16_hi(v.y)};
            float4 f1 = {bf16_lo(v.z), bf16_hi(v.z), bf16_lo(v.w), bf16_hi(v.w)};
            *(float4*)(xs + n * XS_STRIDE + c)     = f0;
            *(float4*)(xs + n * XS_STRIDE + c + 4) = f1;
        }
    }
    __syncthreads();

    {   // ---- Phase B: act = ELU(xs @ W1 + b1). wave = head, W1 prefetch ----
        const int q  = t & 15;
        const int g  = (t >> 4) & 3;
        const int h  = wv;
        const int c0 = h * HID + q * 4;
        const float* Wp = W1 + c0;
        float4 w0 = *(const float4*)(Wp + (size_t)0 * C1);
        float4 w1 = *(const float4*)(Wp + (size_t)1 * C1);
        float4 w2 = *(const float4*)(Wp + (size_t)2 * C1);
        float4 w3 = *(const float4*)(Wp + (size_t)3 * C1);
        float acc[4][4];
        #pragma unroll
        for (int i = 0; i < 4; i++)
            #pragma unroll
            for (int m = 0; m < 4; m++) acc[i][m] = 0.f;
        const float* xbase = xs + (g * 4) * XS_STRIDE + h * IN_DIM;
        for (int k = 0; k < IN_DIM; k += 4) {
            const int kn = (k + 4 < IN_DIM) ? k + 4 : k;
            float4 nw0 = *(const float4*)(Wp + (size_t)(kn + 0) * C1);
            float4 nw1 = *(const float4*)(Wp + (size_t)(kn + 1) * C1);
            float4 nw2 = *(const float4*)(Wp + (size_t)(kn + 2) * C1);
            float4 nw3 = *(const float4*)(Wp + (size_t)(kn + 3) * C1);
            #pragma unroll
            for (int i = 0; i < 4; i++) {
                float4 xv = *(const float4*)(xbase + i * XS_STRIDE + k);
                acc[i][0] = fmaf(xv.x, w0.x, acc[i][0]); acc[i][0] = fmaf(xv.y, w1.x, acc[i][0]);
                acc[i][0] = fmaf(xv.z, w2.x, acc[i][0]); acc[i][0] = fmaf(xv.w, w3.x, acc[i][0]);
                acc[i][1] = fmaf(xv.x, w0.y, acc[i][1]); acc[i][1] = fmaf(xv.y, w1.y, acc[i][1]);
                acc[i][1] = fmaf(xv.z, w2.y, acc[i][1]); acc[i][1] = fmaf(xv.w, w3.y, acc[i][1]);
                acc[i][2] = fmaf(xv.x, w0.z, acc[i][2]); acc[i][2] = fmaf(xv.y, w1.z, acc[i][2]);
                acc[i][2] = fmaf(xv.z, w2.z, acc[i][2]); acc[i][2] = fmaf(xv.w, w3.z, acc[i][2]);
                acc[i][3] = fmaf(xv.x, w0.w, acc[i][3]); acc[i][3] = fmaf(xv.y, w1.w, acc[i][3]);
                acc[i][3] = fmaf(xv.z, w2.w, acc[i][3]); acc[i][3] = fmaf(xv.w, w3.w, acc[i][3]);
            }
            w0 = nw0; w1 = nw1; w2 = nw2; w3 = nw3;
        }
        float4 bb = *(const float4*)(b1 + c0);
        #pragma unroll
        for (int i = 0; i < 4; i++) {
            float o0 = acc[i][0] + bb.x, o1 = acc[i][1] + bb.y;
            float o2 = acc[i][2] + bb.z, o3 = acc[i][3] + bb.w;
            o0 = o0 > 0.f ? o0 : __expf(o0) - 1.f;
            o1 = o1 > 0.f ? o1 : __expf(o1) - 1.f;
            o2 = o2 > 0.f ? o2 : __expf(o2) - 1.f;
            o3 = o3 > 0.f ? o3 : __expf(o3) - 1.f;
            float4 ov = {o0, o1, o2, o3};
            *(float4*)(act + (g * 4 + i) * ACT_STRIDE + c0) = ov;
        }
    }
    __syncthreads();

    {   // ---- Phase C: h2 = act @ W2, k-split across waves, W2 prefetch ----
        const int q  = t & 15;
        const int ng = (t >> 4) & 3;
        const int kb = wv * 64;
        const float* Wp = W2 + q * 4;
        float4 w0 = *(const float4*)(Wp + (size_t)(kb + 0) * OUT_DIM);
        float4 w1 = *(const float4*)(Wp + (size_t)(kb + 1) * OUT_DIM);
        float4 w2 = *(const float4*)(Wp + (size_t)(kb + 2) * OUT_DIM);
        float4 w3 = *(const float4*)(Wp + (size_t)(kb + 3) * OUT_DIM);
        float a[4][4];
        #pragma unroll
        for (int i = 0; i < 4; i++)
            #pragma unroll
            for (int m = 0; m < 4; m++) a[i][m] = 0.f;
        for (int kk = 0; kk < 64; kk += 4) {
            const int knn = (kk + 4 < 64) ? kk + 4 : kk;
            const int kp = kb + knn;
            float4 nw0 = *(const float4*)(Wp + (size_t)(kp + 0) * OUT_DIM);
            float4 nw1 = *(const float4*)(Wp + (size_t)(kp + 1) * OUT_DIM);
            float4 nw2 = *(const float4*)(Wp + (size_t)(kp + 2) * OUT_DIM);
            float4 nw3 = *(const float4*)(Wp + (size_t)(kp + 3) * OUT_DIM);
            const int k = kb + kk;
            #pragma unroll
            for (int i = 0; i < 4; i++) {
                float4 xv = *(const float4*)(act + (ng * 4 + i) * ACT_STRIDE + k);
                a[i][0] = fmaf(xv.x, w0.x, a[i][0]); a[i][0] = fmaf(xv.y, w1.x, a[i][0]);
                a[i][0] = fmaf(xv.z, w2.x, a[i][0]); a[i][0] = fmaf(xv.w, w3.x, a[i][0]);
                a[i][1] = fmaf(xv.x, w0.y, a[i][1]); a[i][1] = fmaf(xv.y, w1.y, a[i][1]);
                a[i][1] = fmaf(xv.z, w2.y, a[i][1]); a[i][1] = fmaf(xv.w, w3.y, a[i][1]);
                a[i][2] = fmaf(xv.x, w0.z, a[i][2]); a[i][2] = fmaf(xv.y, w1.z, a[i][2]);
                a[i][2] = fmaf(xv.z, w2.z, a[i][2]); a[i][2] = fmaf(xv.w, w3.z, a[i][2]);
                a[i][3] = fmaf(xv.x, w0.w, a[i][3]); a[i][3] = fmaf(xv.y, w1.w, a[i][3]);
                a[i][3] = fmaf(xv.z, w2.w, a[i][3]); a[i][3] = fmaf(xv.w, w3.w, a[i][3]);
            }
            w0 = nw0; w1 = nw1; w2 = nw2; w3 = nw3;
        }
        float* pc = xs;                        // alias: xs no longer needed
        #pragma unroll
        for (int i = 0; i < 4; i++) {
            float4 pv = {a[i][0], a[i][1], a[i][2], a[i][3]};
            *(float4*)(pc + wv * PC_WCHUNK + (ng * 4 + i) * PC_STRIDE + q * 4) = pv;
        }
    }
    __syncthreads();

    {   // ---- Reduce partials + epilogue (h2 -> bf16) ----
        const float* pc = xs;
        const int n  = t >> 4;                 // node 0..15
        const int c0 = (t & 15) * 4;           // cols 0..63
        float4 r = {0, 0, 0, 0};
        #pragma unroll
        for (int w = 0; w < 4; w++) {
            float4 p = *(const float4*)(pc + w * PC_WCHUNK + n * PC_STRIDE + c0);
            r.x += p.x; r.y += p.y; r.z += p.z; r.w += p.w;
        }
        const int node = nodeBase + n;
        uint2 hv = {bf16_pack2(r.x, r.y), bf16_pack2(r.z, r.w)};
        *(uint2*)(h2b + (size_t)node * 32 + (t & 15) * 2) = hv;   // row = 32 uints
        float4 aw = *(const float4*)(a_src2 + c0);
        float4 dw = *(const float4*)(a_dst2 + c0);
        float s = r.x * aw.x + r.y * aw.y + r.z * aw.z + r.w * aw.w;
        float d = r.x * dw.x + r.y * dw.y + r.z * dw.z + r.w * dw.w;
        #pragma unroll
        for (int off = 8; off; off >>= 1) {
            s += __shfl_down(s, off, 16);
            d += __shfl_down(d, off, 16);
        }
        if ((t & 15) == 0) { as2[node] = s; ad2[node] = d; }
    }
}

// ---------------------------------------------------------------------------
// Layer-2 aggregation + bias + fc dot, fused, unroll x4. One wave per node,
// lane = channel; h2 gathered as bf16 (2 B/lane), fp32 accumulation.
// ---------------------------------------------------------------------------
__global__ __launch_bounds__(256) void agg2_final_kernel(
    const int* __restrict__ rowptr, const int* __restrict__ srcS,
    const unsigned short* __restrict__ h2b, const float* __restrict__ as2,
    const float* __restrict__ ad2, const float* __restrict__ b2,
    const float* __restrict__ fc_w, const float* __restrict__ fc_b,
    float* __restrict__ out)
{
    int gid  = blockIdx.x * blockDim.x + threadIdx.x;
    int n    = gid >> 6;
    int lane = threadIdx.x & 63;
    if (n >= N_NODES) return;
    const float adh = ad2[n];
    const int e0 = rowptr[n], e1 = rowptr[n + 1];

    float acc = 0.f, den = 0.f;
    int e = e0;
    for (; e + 4 <= e1; e += 4) {
        int s0 = srcS[e], s1 = srcS[e + 1], s2 = srcS[e + 2], s3 = srcS[e + 3];
        float a0 = as2[s0] + adh;
        float a1 = as2[s1] + adh;
        float a2 = as2[s2] + adh;
        float a3 = as2[s3] + adh;
        unsigned short h0 = h2b[(size_t)s0 * OUT_DIM + lane];
        unsigned short h1 = h2b[(size_t)s1 * OUT_DIM + lane];
        unsigned short h2v = h2b[(size_t)s2 * OUT_DIM + lane];
        unsigned short h3 = h2b[(size_t)s3 * OUT_DIM + lane];
        a0 = a0 > 0.f ? a0 : NEG_SLOPE * a0;
        a1 = a1 > 0.f ? a1 : NEG_SLOPE * a1;
        a2 = a2 > 0.f ? a2 : NEG_SLOPE * a2;
        a3 = a3 > 0.f ? a3 : NEG_SLOPE * a3;
        float w0 = __expf(a0), w1 = __expf(a1), w2 = __expf(a2), w3 = __expf(a3);
        acc = fmaf(w0, __uint_as_float((unsigned int)h0 << 16), acc);
        acc = fmaf(w1, __uint_as_float((unsigned int)h1 << 16), acc);
        acc = fmaf(w2, __uint_as_float((unsigned int)h2v << 16), acc);
        acc = fmaf(w3, __uint_as_float((unsigned int)h3 << 16), acc);
        den += (w0 + w1) + (w2 + w3);
    }
    for (; e < e1; e++) {
        int s = srcS[e];
        float a = as2[s] + adh;
        a = a > 0.f ? a : NEG_SLOPE * a;
        float w = __expf(a);
        unsigned short hv = h2b[(size_t)s * OUT_DIM + lane];
        acc = fmaf(w, __uint_as_float((unsigned int)hv << 16), acc);
        den += w;
    }
    float v = acc / (den + 1e-16f) + b2[lane];
    float r = v * fc_w[lane];
    #pragma unroll
    for (int off = 32; off; off >>= 1) r += __shfl_down(r, off, 64);
    if (lane == 0) out[n] = r + fc_b[0];
}

extern "C" void kernel_launch(void* const* d_in, const int* in_sizes, int n_in,
                              void* d_out, int out_size, void* d_ws, size_t ws_size,
                              hipStream_t stream)
{
    const float* x      = (const float*)d_in[0];
    const int*   ei     = (const int*)d_in[1];
    const float* W1     = (const float*)d_in[2];
    const float* a_src1 = (const float*)d_in[3];
    const float* a_dst1 = (const float*)d_in[4];
    const float* b1     = (const float*)d_in[5];
    const float* W2     = (const float*)d_in[6];
    const float* a_src2 = (const float*)d_in[7];
    const float* a_dst2 = (const float*)d_in[8];
    const float* b2     = (const float*)d_in[9];
    const float* fc_w   = (const float*)d_in[10];
    const float* fc_b   = (const float*)d_in[11];
    float* out = (float*)d_out;

    const int* srcA = ei;
    const int* dstA = ei + N_EDGES;

    // workspace layout
    float* ws = (float*)d_ws;
    size_t off = 0;
    unsigned int* xaggb = (unsigned int*)(ws + off); off += (size_t)N_NODES * 256;  // 51.2 MB
    unsigned int* xb    = (unsigned int*)(ws + off); off += (size_t)N_NODES * 64;   // 12.8 MB
    unsigned int* h2b   = (unsigned int*)(ws + off); off += (size_t)N_NODES * 32;   //  6.4 MB
    float* as1     = ws + off; off += (size_t)N_NODES * HEADS;
    float* ad1     = ws + off; off += (size_t)N_NODES * HEADS;
    float* as2     = ws + off; off += N_NODES;
    float* ad2     = ws + off; off += N_NODES;
    float* p_src   = ws + off; off += IN_DIM * HEADS;
    float* p_dst   = ws + off; off += IN_DIM * HEADS;
    int* rowptr    = (int*)(ws + off); off += N_NODES + 2;
    int* srcSorted = (int*)(ws + off); off += E_TOT;
    int* zstart    = (int*)(ws + off);
    int* deg       = (int*)(ws + off); off += N_NODES;
    int* cursor    = (int*)(ws + off); off += N_NODES;
    hipMemsetAsync(zstart, 0, 2 * N_NODES * sizeof(int), stream);

    // layer-1 logit projection matrix (h1 never materialized)
    prep_kernel<<<1, 512, 0, stream>>>(W1, a_src1, a_dst1, p_src, p_dst);

    // fused: per-node proj + x->bf16 convert, plus CSR degree count
    convproj_count_kernel<<<PROJ_BLOCKS + COUNT_BLOCKS, 256, 0, stream>>>(
        x, p_src, p_dst, dstA, as1, ad1, xb, deg);

    // CSR: scan + fill
    scan_kernel<<<1, 1024, 0, stream>>>(deg, rowptr);
    fill_kernel<<<COUNT_BLOCKS, 256, 0, stream>>>(srcA, dstA, rowptr, cursor, srcSorted);

    // layer-1 aggregation in bf16 x-space
    agg1x_kernel<<<(N_NODES * 64 + 255) / 256, 256, 0, stream>>>(rowptr, srcSorted, xb, as1, ad1, xaggb);

    // fused MLP: bf16-staged, W once/block, prefetched
    mlp4_kernel<<<N_NODES / 16, 256, 0, stream>>>(xaggb, W1, b1, W2, a_src2, a_dst2, h2b, as2, ad2);

    // layer 2 + final (bf16 h2 gather)
    agg2_final_kernel<<<(N_NODES * 64 + 255) / 256, 256, 0, stream>>>(
        rowptr, srcSorted, (const unsigned short*)h2b, as2, ad2, b2, fc_w, fc_b, out);
}

// Round 9
// 482.757 us; speedup vs baseline: 1.2673x; 1.0259x over previous
//
#include <hip/hip_runtime.h>

#define N_NODES 50000
#define N_EDGES 800000
#define E_TOT   850000           // edges + self loops
#define IN_DIM  128
#define HID     64
#define HEADS   4
#define C1      256              // HEADS*HID
#define OUT_DIM 64
#define NEG_SLOPE 0.2f

#define XS_STRIDE   516          // 512+4 floats
#define ACT_STRIDE  (C1 + 4)     // 260

#define PROJ_BLOCKS (N_NODES / 4)                  // 12500
#define COUNT_BLOCKS ((E_TOT + 255) / 256)         // 3321

// ---- bf16 helpers (manual: bf16 = top 16 bits of fp32, RNE) ----------------
__device__ __forceinline__ unsigned int bf16_rne(float f) {
    unsigned int u = __float_as_uint(f);
    return (u + 0x7FFFu + ((u >> 16) & 1u)) >> 16;
}
__device__ __forceinline__ unsigned int bf16_pack2(float a, float b) {
    return bf16_rne(a) | (bf16_rne(b) << 16);
}
__device__ __forceinline__ float bf16_lo(unsigned int u) { return __uint_as_float(u << 16); }
__device__ __forceinline__ float bf16_hi(unsigned int u) { return __uint_as_float(u & 0xFFFF0000u); }

// ---------------------------------------------------------------------------
// prep: p_src[k][h] = sum_c W1[k][h*64+c]*a_src1[h][c] (and p_dst), collapsing
// the layer-1 logit projection.  NEW: v_s = W2@a_src2, v_d = W2@a_dst2,
// v_z = W2@fc_w (collapses ALL consumers of h2), cst = b2.fc_w + fc_b.
// ---------------------------------------------------------------------------
__global__ __launch_bounds__(512) void prep_kernel(
    const float* __restrict__ W1, const float* __restrict__ a_src1,
    const float* __restrict__ a_dst1,
    const float* __restrict__ W2, const float* __restrict__ a_src2,
    const float* __restrict__ a_dst2, const float* __restrict__ b2,
    const float* __restrict__ fc_w, const float* __restrict__ fc_b,
    float* __restrict__ p_src, float* __restrict__ p_dst,
    float* __restrict__ v_s, float* __restrict__ v_d, float* __restrict__ v_z,
    float* __restrict__ cst)
{
    const int t = threadIdx.x;                 // 512 = 128 k * 4 h
    const int k = t >> 2, h = t & 3;
    const float* wrow = W1 + k * C1 + h * HID;
    const float* as = a_src1 + h * HID;
    const float* ad = a_dst1 + h * HID;
    float s = 0.f, d = 0.f;
    for (int c = 0; c < HID; c++) {
        float w = wrow[c];
        s = fmaf(w, as[c], s);
        d = fmaf(w, ad[c], d);
    }
    p_src[k * HEADS + h] = s;
    p_dst[k * HEADS + h] = d;

    if (t < C1) {                              // layer-2 collapse vectors
        const float* w2row = W2 + t * OUT_DIM;
        float vs = 0.f, vd = 0.f, vz = 0.f;
        for (int c = 0; c < OUT_DIM; c++) {
            float w = w2row[c];
            vs = fmaf(w, a_src2[c], vs);
            vd = fmaf(w, a_dst2[c], vd);
            vz = fmaf(w, fc_w[c], vz);
        }
        v_s[t] = vs; v_d[t] = vd; v_z[t] = vz;
    }
    if (t == 0) {
        float s2 = 0.f;
        for (int c = 0; c < OUT_DIM; c++) s2 = fmaf(b2[c], fc_w[c], s2);
        cst[0] = s2 + fc_b[0];
    }
}

// ---------------------------------------------------------------------------
// convproj_count: fused launch.
//  Blocks [0, PROJ_BLOCKS): per-node logit projections as1/ad1 AND x -> bf16.
//  Blocks [PROJ_BLOCKS, +COUNT_BLOCKS): per-edge degree count (CSR step 1).
// ---------------------------------------------------------------------------
__global__ __launch_bounds__(256) void convproj_count_kernel(
    const float* __restrict__ x, const float* __restrict__ p_src,
    const float* __restrict__ p_dst, const int* __restrict__ dst_a,
    float* __restrict__ as1, float* __restrict__ ad1,
    unsigned int* __restrict__ xb, int* __restrict__ deg)
{
    if (blockIdx.x >= PROJ_BLOCKS) {           // ---- count part ----
        int j = (blockIdx.x - PROJ_BLOCKS) * 256 + threadIdx.x;
        if (j < E_TOT) {
            int d = (j < N_EDGES) ? dst_a[j] : (j - N_EDGES);   // self loop
            atomicAdd(&deg[d], 1);
        }
        return;
    }
    // ---- proj + convert part ----
    __shared__ float ps[IN_DIM * HEADS];       // 2 KB
    __shared__ float pd[IN_DIM * HEADS];       // 2 KB
    const int t = threadIdx.x;
    for (int i = t; i < IN_DIM * HEADS; i += 256) { ps[i] = p_src[i]; pd[i] = p_dst[i]; }
    __syncthreads();
    const int node = blockIdx.x * 4 + (t >> 6);
    const int lane = t & 63;
    float2 xv = *(const float2*)(x + (size_t)node * IN_DIM + lane * 2);
    xb[(size_t)node * 64 + lane] = bf16_pack2(xv.x, xv.y);
    float4 p0 = *(const float4*)(ps + (lane * 2) * HEADS);
    float4 p1 = *(const float4*)(ps + (lane * 2 + 1) * HEADS);
    float4 q0 = *(const float4*)(pd + (lane * 2) * HEADS);
    float4 q1 = *(const float4*)(pd + (lane * 2 + 1) * HEADS);
    float s0 = xv.x * p0.x + xv.y * p1.x;
    float s1 = xv.x * p0.y + xv.y * p1.y;
    float s2 = xv.x * p0.z + xv.y * p1.z;
    float s3 = xv.x * p0.w + xv.y * p1.w;
    float d0 = xv.x * q0.x + xv.y * q1.x;
    float d1 = xv.x * q0.y + xv.y * q1.y;
    float d2 = xv.x * q0.z + xv.y * q1.z;
    float d3 = xv.x * q0.w + xv.y * q1.w;
    #pragma unroll
    for (int off = 32; off; off >>= 1) {
        s0 += __shfl_down(s0, off, 64); s1 += __shfl_down(s1, off, 64);
        s2 += __shfl_down(s2, off, 64); s3 += __shfl_down(s3, off, 64);
        d0 += __shfl_down(d0, off, 64); d1 += __shfl_down(d1, off, 64);
        d2 += __shfl_down(d2, off, 64); d3 += __shfl_down(d3, off, 64);
    }
    if (lane == 0) {
        float4 sv = {s0, s1, s2, s3};
        float4 dv = {d0, d1, d2, d3};
        *(float4*)(as1 + node * 4) = sv;
        *(float4*)(ad1 + node * 4) = dv;
    }
}

// ---------------------------------------------------------------------------
// scan + fill: CSR steps 2/3
// ---------------------------------------------------------------------------
__global__ __launch_bounds__(1024) void scan_kernel(const int* __restrict__ deg,
                                                    int* __restrict__ rowptr)
{
    __shared__ int psum[1024];
    const int t = threadIdx.x;
    const int CH = (N_NODES + 1023) / 1024;            // 49
    const int base = t * CH;
    int s = 0;
    for (int i = 0; i < CH; i++) {
        int idx = base + i;
        if (idx < N_NODES) s += deg[idx];
    }
    psum[t] = s;
    __syncthreads();
    for (int off = 1; off < 1024; off <<= 1) {
        int v = (t >= off) ? psum[t - off] : 0;
        __syncthreads();
        psum[t] += v;
        __syncthreads();
    }
    int run = (t > 0) ? psum[t - 1] : 0;
    for (int i = 0; i < CH; i++) {
        int idx = base + i;
        if (idx < N_NODES) { rowptr[idx] = run; run += deg[idx]; }
    }
    if (t == 0) rowptr[N_NODES] = E_TOT;
}

__global__ void fill_kernel(const int* __restrict__ src_a, const int* __restrict__ dst_a,
                            const int* __restrict__ rowptr, int* __restrict__ cursor,
                            int* __restrict__ srcSorted)
{
    int j = blockIdx.x * blockDim.x + threadIdx.x;
    if (j >= E_TOT) return;
    int s, d;
    if (j < N_EDGES) { s = src_a[j]; d = dst_a[j]; }
    else             { s = j - N_EDGES; d = s; }
    int pos = atomicAdd(&cursor[d], 1);
    srcSorted[rowptr[d] + pos] = s;
}

// ---------------------------------------------------------------------------
// agg1x: xaggb[n][h][k] (bf16) = softmax-weighted sum of xb[src] rows (bf16).
// One wave per dst node, lane = 2 k-channels (one packed uint), fp32 accum.
// ---------------------------------------------------------------------------
__global__ __launch_bounds__(256) void agg1x_kernel(
    const int* __restrict__ rowptr, const int* __restrict__ srcS,
    const unsigned int* __restrict__ xb, const float* __restrict__ as1,
    const float* __restrict__ ad1, unsigned int* __restrict__ xaggb)
{
    int gid  = blockIdx.x * blockDim.x + threadIdx.x;
    int n    = gid >> 6;
    int lane = threadIdx.x & 63;
    if (n >= N_NODES) return;
    float4 adv = *(const float4*)(ad1 + n * 4);
    const int e0 = rowptr[n], e1 = rowptr[n + 1];

    float2 acc0 = {0,0}, acc1 = {0,0}, acc2 = {0,0}, acc3 = {0,0};
    float den0 = 0, den1 = 0, den2 = 0, den3 = 0;
    int e = e0;
    for (; e + 2 <= e1; e += 2) {
        int s0 = srcS[e], s1 = srcS[e + 1];
        float4 A0 = *(const float4*)(as1 + s0 * 4);
        float4 A1 = *(const float4*)(as1 + s1 * 4);
        unsigned int xu0 = xb[(size_t)s0 * 64 + lane];
        unsigned int xu1 = xb[(size_t)s1 * 64 + lane];
        float a0 = A0.x + adv.x, a1 = A0.y + adv.y, a2 = A0.z + adv.z, a3 = A0.w + adv.w;
        a0 = a0 > 0.f ? a0 : NEG_SLOPE * a0;  a1 = a1 > 0.f ? a1 : NEG_SLOPE * a1;
        a2 = a2 > 0.f ? a2 : NEG_SLOPE * a2;  a3 = a3 > 0.f ? a3 : NEG_SLOPE * a3;
        float w0 = __expf(a0), w1 = __expf(a1), w2 = __expf(a2), w3 = __expf(a3);
        float b0 = A1.x + adv.x, b1v = A1.y + adv.y, b2v = A1.z + adv.z, b3 = A1.w + adv.w;
        b0 = b0 > 0.f ? b0 : NEG_SLOPE * b0;    b1v = b1v > 0.f ? b1v : NEG_SLOPE * b1v;
        b2v = b2v > 0.f ? b2v : NEG_SLOPE * b2v; b3 = b3 > 0.f ? b3 : NEG_SLOPE * b3;
        float u0 = __expf(b0), u1 = __expf(b1v), u2 = __expf(b2v), u3 = __expf(b3);
        float xa = bf16_lo(xu0), xbv = bf16_hi(xu0);
        float ya = bf16_lo(xu1), ybv = bf16_hi(xu1);
        acc0.x = fmaf(w0, xa, acc0.x); acc0.y = fmaf(w0, xbv, acc0.y);
        acc1.x = fmaf(w1, xa, acc1.x); acc1.y = fmaf(w1, xbv, acc1.y);
        acc2.x = fmaf(w2, xa, acc2.x); acc2.y = fmaf(w2, xbv, acc2.y);
        acc3.x = fmaf(w3, xa, acc3.x); acc3.y = fmaf(w3, xbv, acc3.y);
        acc0.x = fmaf(u0, ya, acc0.x); acc0.y = fmaf(u0, ybv, acc0.y);
        acc1.x = fmaf(u1, ya, acc1.x); acc1.y = fmaf(u1, ybv, acc1.y);
        acc2.x = fmaf(u2, ya, acc2.x); acc2.y = fmaf(u2, ybv, acc2.y);
        acc3.x = fmaf(u3, ya, acc3.x); acc3.y = fmaf(u3, ybv, acc3.y);
        den0 += w0 + u0; den1 += w1 + u1; den2 += w2 + u2; den3 += w3 + u3;
    }
    for (; e < e1; e++) {
        int s = srcS[e];
        float4 A0 = *(const float4*)(as1 + s * 4);
        unsigned int xu = xb[(size_t)s * 64 + lane];
        float a0 = A0.x + adv.x, a1 = A0.y + adv.y, a2 = A0.z + adv.z, a3 = A0.w + adv.w;
        a0 = a0 > 0.f ? a0 : NEG_SLOPE * a0;  a1 = a1 > 0.f ? a1 : NEG_SLOPE * a1;
        a2 = a2 > 0.f ? a2 : NEG_SLOPE * a2;  a3 = a3 > 0.f ? a3 : NEG_SLOPE * a3;
        float w0 = __expf(a0), w1 = __expf(a1), w2 = __expf(a2), w3 = __expf(a3);
        float xa = bf16_lo(xu), xbv = bf16_hi(xu);
        acc0.x = fmaf(w0, xa, acc0.x); acc0.y = fmaf(w0, xbv, acc0.y);
        acc1.x = fmaf(w1, xa, acc1.x); acc1.y = fmaf(w1, xbv, acc1.y);
        acc2.x = fmaf(w2, xa, acc2.x); acc2.y = fmaf(w2, xbv, acc2.y);
        acc3.x = fmaf(w3, xa, acc3.x); acc3.y = fmaf(w3, xbv, acc3.y);
        den0 += w0; den1 += w1; den2 += w2; den3 += w3;
    }
    float i0 = 1.f / (den0 + 1e-16f), i1 = 1.f / (den1 + 1e-16f);
    float i2 = 1.f / (den2 + 1e-16f), i3 = 1.f / (den3 + 1e-16f);
    unsigned int* o = xaggb + (size_t)n * 256 + lane;      // row = 256 uints
    o[0 * 64] = bf16_pack2(acc0.x * i0, acc0.y * i0);
    o[1 * 64] = bf16_pack2(acc1.x * i1, acc1.y * i1);
    o[2 * 64] = bf16_pack2(acc2.x * i2, acc2.y * i2);
    o[3 * 64] = bf16_pack2(acc3.x * i3, acc3.y * i3);
}

// ---------------------------------------------------------------------------
// mlp5: 16 nodes/block, min 3 waves/EU. Phase C collapsed away (v_s/v_d/v_z).
//  Phase A: stage bf16 xagg tile -> fp32 LDS
//  Phase B: act = ELU(xs @ W1 + b1); wave = head (W1 once/block), prefetched.
//           Lane = 8 cols x 2 nodes -> each ds_read_b128 feeds 32 FMA
//           (halves LDS instrs vs the 4x4 tile).
//  Epilogue: as2 = act.v_s, ad2 = act.v_d, z = act.v_z; store az=(as2,z), ad2.
// ---------------------------------------------------------------------------
__global__ __launch_bounds__(256, 3) void mlp5_kernel(
    const unsigned int* __restrict__ xaggb,
    const float* __restrict__ W1, const float* __restrict__ b1,
    const float* __restrict__ v_s, const float* __restrict__ v_d,
    const float* __restrict__ v_z,
    float2* __restrict__ az, float* __restrict__ ad2)
{
    __shared__ float xs[16 * XS_STRIDE];       // 33,024 B
    __shared__ float act[16 * ACT_STRIDE];     // 16,640 B
    const int t = threadIdx.x;
    const int nodeBase = blockIdx.x * 16;
    const int wv = t >> 6;

    {   // ---- Phase A: stage 16x512ch (bf16) -> fp32 LDS ----
        const unsigned int* gsrc = xaggb + (size_t)nodeBase * 256;
        #pragma unroll
        for (int i = 0; i < 4; i++) {
            int iu = i * 1024 + t * 4;         // uint index in 4096-uint tile
            uint4 v = *(const uint4*)(gsrc + iu);
            int n = iu >> 8, c = (iu & 255) * 2;
            float4 f0 = {bf16_lo(v.x), bf16_hi(v.x), bf16_lo(v.y), bf16_hi(v.y)};
            float4 f1 = {bf16_lo(v.z), bf16_hi(v.z), bf16_lo(v.w), bf16_hi(v.w)};
            *(float4*)(xs + n * XS_STRIDE + c)     = f0;
            *(float4*)(xs + n * XS_STRIDE + c + 4) = f1;
        }
    }
    __syncthreads();

    {   // ---- Phase B: act = ELU(xs @ W1 + b1). wave = head. ----
        const int cq = t & 7;                  // col quads cq and cq+8 of head
        const int ng = (t >> 3) & 7;           // nodes 2ng, 2ng+1
        const int h  = wv;
        const int ca = h * HID + cq * 4;
        const int cb = ca + 32;
        const float* Wa = W1 + ca;
        const float* Wb = W1 + cb;
        float4 wa0 = *(const float4*)(Wa + 0 * C1);
        float4 wa1 = *(const float4*)(Wa + 1 * C1);
        float4 wa2 = *(const float4*)(Wa + 2 * C1);
        float4 wa3 = *(const float4*)(Wa + 3 * C1);
        float4 wb0 = *(const float4*)(Wb + 0 * C1);
        float4 wb1 = *(const float4*)(Wb + 1 * C1);
        float4 wb2 = *(const float4*)(Wb + 2 * C1);
        float4 wb3 = *(const float4*)(Wb + 3 * C1);
        float acc[2][8];
        #pragma unroll
        for (int i = 0; i < 2; i++)
            #pragma unroll
            for (int m = 0; m < 8; m++) acc[i][m] = 0.f;
        const float* xb0 = xs + (ng * 2) * XS_STRIDE + h * IN_DIM;
        const float* xb1 = xb0 + XS_STRIDE;
        for (int k = 0; k < IN_DIM; k += 4) {
            const int kn = (k + 4 < IN_DIM) ? k + 4 : k;   // clamped prefetch
            float4 na0 = *(const float4*)(Wa + (size_t)(kn + 0) * C1);
            float4 na1 = *(const float4*)(Wa + (size_t)(kn + 1) * C1);
            float4 na2 = *(const float4*)(Wa + (size_t)(kn + 2) * C1);
            float4 na3 = *(const float4*)(Wa + (size_t)(kn + 3) * C1);
            float4 nb0 = *(const float4*)(Wb + (size_t)(kn + 0) * C1);
            float4 nb1 = *(const float4*)(Wb + (size_t)(kn + 1) * C1);
            float4 nb2 = *(const float4*)(Wb + (size_t)(kn + 2) * C1);
            float4 nb3 = *(const float4*)(Wb + (size_t)(kn + 3) * C1);
            float4 xv0 = *(const float4*)(xb0 + k);
            float4 xv1 = *(const float4*)(xb1 + k);
            #pragma unroll
            for (int i = 0; i < 2; i++) {
                float4 xv = i ? xv1 : xv0;
                acc[i][0] = fmaf(xv.x, wa0.x, acc[i][0]); acc[i][0] = fmaf(xv.y, wa1.x, acc[i][0]);
                acc[i][0] = fmaf(xv.z, wa2.x, acc[i][0]); acc[i][0] = fmaf(xv.w, wa3.x, acc[i][0]);
                acc[i][1] = fmaf(xv.x, wa0.y, acc[i][1]); acc[i][1] = fmaf(xv.y, wa1.y, acc[i][1]);
                acc[i][1] = fmaf(xv.z, wa2.y, acc[i][1]); acc[i][1] = fmaf(xv.w, wa3.y, acc[i][1]);
                acc[i][2] = fmaf(xv.x, wa0.z, acc[i][2]); acc[i][2] = fmaf(xv.y, wa1.z, acc[i][2]);
                acc[i][2] = fmaf(xv.z, wa2.z, acc[i][2]); acc[i][2] = fmaf(xv.w, wa3.z, acc[i][2]);
                acc[i][3] = fmaf(xv.x, wa0.w, acc[i][3]); acc[i][3] = fmaf(xv.y, wa1.w, acc[i][3]);
                acc[i][3] = fmaf(xv.z, wa2.w, acc[i][3]); acc[i][3] = fmaf(xv.w, wa3.w, acc[i][3]);
                acc[i][4] = fmaf(xv.x, wb0.x, acc[i][4]); acc[i][4] = fmaf(xv.y, wb1.x, acc[i][4]);
                acc[i][4] = fmaf(xv.z, wb2.x, acc[i][4]); acc[i][4] = fmaf(xv.w, wb3.x, acc[i][4]);
                acc[i][5] = fmaf(xv.x, wb0.y, acc[i][5]); acc[i][5] = fmaf(xv.y, wb1.y, acc[i][5]);
                acc[i][5] = fmaf(xv.z, wb2.y, acc[i][5]); acc[i][5] = fmaf(xv.w, wb3.y, acc[i][5]);
                acc[i][6] = fmaf(xv.x, wb0.z, acc[i][6]); acc[i][6] = fmaf(xv.y, wb1.z, acc[i][6]);
                acc[i][6] = fmaf(xv.z, wb2.z, acc[i][6]); acc[i][6] = fmaf(xv.w, wb3.z, acc[i][6]);
                acc[i][7] = fmaf(xv.x, wb0.w, acc[i][7]); acc[i][7] = fmaf(xv.y, wb1.w, acc[i][7]);
                acc[i][7] = fmaf(xv.z, wb2.w, acc[i][7]); acc[i][7] = fmaf(xv.w, wb3.w, acc[i][7]);
            }
            wa0 = na0; wa1 = na1; wa2 = na2; wa3 = na3;
            wb0 = nb0; wb1 = nb1; wb2 = nb2; wb3 = nb3;
        }
        float4 ba = *(const float4*)(b1 + ca);
        float4 bb = *(const float4*)(b1 + cb);
        #pragma unroll
        for (int i = 0; i < 2; i++) {
            const int row = (ng * 2 + i) * ACT_STRIDE;
            float o0 = acc[i][0] + ba.x, o1 = acc[i][1] + ba.y;
            float o2 = acc[i][2] + ba.z, o3 = acc[i][3] + ba.w;
            float o4 = acc[i][4] + bb.x, o5 = acc[i][5] + bb.y;
            float o6 = acc[i][6] + bb.z, o7 = acc[i][7] + bb.w;
            o0 = o0 > 0.f ? o0 : __expf(o0) - 1.f;
            o1 = o1 > 0.f ? o1 : __expf(o1) - 1.f;
            o2 = o2 > 0.f ? o2 : __expf(o2) - 1.f;
            o3 = o3 > 0.f ? o3 : __expf(o3) - 1.f;
            o4 = o4 > 0.f ? o4 : __expf(o4) - 1.f;
            o5 = o5 > 0.f ? o5 : __expf(o5) - 1.f;
            o6 = o6 > 0.f ? o6 : __expf(o6) - 1.f;
            o7 = o7 > 0.f ? o7 : __expf(o7) - 1.f;
            float4 va = {o0, o1, o2, o3};
            float4 vb = {o4, o5, o6, o7};
            *(float4*)(act + row + ca) = va;
            *(float4*)(act + row + cb) = vb;
        }
    }
    __syncthreads();

    {   // ---- Epilogue: as2/ad2/z via v_s, v_d, v_z (phase C collapsed) ----
        const int n  = t >> 4;                 // node 0..15
        const int j0 = (t & 15) * 16;          // 16 act elems per lane
        const float* ar = act + n * ACT_STRIDE + j0;
        float s = 0.f, d = 0.f, z = 0.f;
        #pragma unroll
        for (int j = 0; j < 16; j += 4) {
            float4 a4  = *(const float4*)(ar + j);
            float4 vs4 = *(const float4*)(v_s + j0 + j);
            float4 vd4 = *(const float4*)(v_d + j0 + j);
            float4 vz4 = *(const float4*)(v_z + j0 + j);
            s = fmaf(a4.x, vs4.x, s); s = fmaf(a4.y, vs4.y, s);
            s = fmaf(a4.z, vs4.z, s); s = fmaf(a4.w, vs4.w, s);
            d = fmaf(a4.x, vd4.x, d); d = fmaf(a4.y, vd4.y, d);
            d = fmaf(a4.z, vd4.z, d); d = fmaf(a4.w, vd4.w, d);
            z = fmaf(a4.x, vz4.x, z); z = fmaf(a4.y, vz4.y, z);
            z = fmaf(a4.z, vz4.z, z); z = fmaf(a4.w, vz4.w, z);
        }
        #pragma unroll
        for (int off = 8; off; off >>= 1) {
            s += __shfl_down(s, off, 16);
            d += __shfl_down(d, off, 16);
            z += __shfl_down(z, off, 16);
        }
        if ((t & 15) == 0) {
            const int node = nodeBase + n;
            float2 azv = {s, z};
            az[node]  = azv;
            ad2[node] = d;
        }
    }
}

// ---------------------------------------------------------------------------
// agg2z: out[n] = sum_e w_e * z[src] / sum_e w_e + cst.  Gather is 8 B/edge
// (az = (as2, z) float2) instead of a 128 B h2 row.  8 lanes per node.
// ---------------------------------------------------------------------------
__global__ __launch_bounds__(256) void agg2z_kernel(
    const int* __restrict__ rowptr, const int* __restrict__ srcS,
    const float2* __restrict__ az, const float* __restrict__ ad2,
    const float* __restrict__ cst, float* __restrict__ out)
{
    int gid  = blockIdx.x * blockDim.x + threadIdx.x;
    int n    = gid >> 3;                       // 8 lanes per node
    int sl   = threadIdx.x & 7;
    if (n >= N_NODES) return;
    const float adh = ad2[n];
    const int e0 = rowptr[n], e1 = rowptr[n + 1];

    float acc = 0.f, den = 0.f;
    for (int e = e0 + sl; e < e1; e += 8) {
        int s = srcS[e];
        float2 v = az[s];
        float a = v.x + adh;
        a = a > 0.f ? a : NEG_SLOPE * a;
        float w = __expf(a);
        acc = fmaf(w, v.y, acc);
        den += w;
    }
    #pragma unroll
    for (int off = 4; off; off >>= 1) {
        acc += __shfl_down(acc, off, 8);
        den += __shfl_down(den, off, 8);
    }
    if (sl == 0) out[n] = acc / (den + 1e-16f) + cst[0];
}

extern "C" void kernel_launch(void* const* d_in, const int* in_sizes, int n_in,
                              void* d_out, int out_size, void* d_ws, size_t ws_size,
                              hipStream_t stream)
{
    const float* x      = (const float*)d_in[0];
    const int*   ei     = (const int*)d_in[1];
    const float* W1     = (const float*)d_in[2];
    const float* a_src1 = (const float*)d_in[3];
    const float* a_dst1 = (const float*)d_in[4];
    const float* b1     = (const float*)d_in[5];
    const float* W2     = (const float*)d_in[6];
    const float* a_src2 = (const float*)d_in[7];
    const float* a_dst2 = (const float*)d_in[8];
    const float* b2     = (const float*)d_in[9];
    const float* fc_w   = (const float*)d_in[10];
    const float* fc_b   = (const float*)d_in[11];
    float* out = (float*)d_out;

    const int* srcA = ei;
    const int* dstA = ei + N_EDGES;

    // workspace layout
    float* ws = (float*)d_ws;
    size_t off = 0;
    unsigned int* xaggb = (unsigned int*)(ws + off); off += (size_t)N_NODES * 256;  // 51.2 MB
    unsigned int* xb    = (unsigned int*)(ws + off); off += (size_t)N_NODES * 64;   // 12.8 MB
    float* as1     = ws + off; off += (size_t)N_NODES * HEADS;
    float* ad1     = ws + off; off += (size_t)N_NODES * HEADS;
    float2* az     = (float2*)(ws + off); off += (size_t)N_NODES * 2;
    float* ad2     = ws + off; off += N_NODES;
    float* p_src   = ws + off; off += IN_DIM * HEADS;
    float* p_dst   = ws + off; off += IN_DIM * HEADS;
    float* v_s     = ws + off; off += C1;
    float* v_d     = ws + off; off += C1;
    float* v_z     = ws + off; off += C1;
    float* cst     = ws + off; off += 2;
    int* rowptr    = (int*)(ws + off); off += N_NODES + 2;
    int* srcSorted = (int*)(ws + off); off += E_TOT;
    int* zstart    = (int*)(ws + off);
    int* deg       = (int*)(ws + off); off += N_NODES;
    int* cursor    = (int*)(ws + off); off += N_NODES;
    hipMemsetAsync(zstart, 0, 2 * N_NODES * sizeof(int), stream);

    // projection collapses: p_src/p_dst (layer 1), v_s/v_d/v_z + cst (layer 2)
    prep_kernel<<<1, 512, 0, stream>>>(W1, a_src1, a_dst1, W2, a_src2, a_dst2,
                                       b2, fc_w, fc_b, p_src, p_dst, v_s, v_d, v_z, cst);

    // fused: per-node proj + x->bf16 convert, plus CSR degree count
    convproj_count_kernel<<<PROJ_BLOCKS + COUNT_BLOCKS, 256, 0, stream>>>(
        x, p_src, p_dst, dstA, as1, ad1, xb, deg);

    // CSR: scan + fill
    scan_kernel<<<1, 1024, 0, stream>>>(deg, rowptr);
    fill_kernel<<<COUNT_BLOCKS, 256, 0, stream>>>(srcA, dstA, rowptr, cursor, srcSorted);

    // layer-1 aggregation in bf16 x-space
    agg1x_kernel<<<(N_NODES * 64 + 255) / 256, 256, 0, stream>>>(rowptr, srcSorted, xb, as1, ad1, xaggb);

    // fused MLP (phase C collapsed into 3 dot products)
    mlp5_kernel<<<N_NODES / 16, 256, 0, stream>>>(xaggb, W1, b1, v_s, v_d, v_z, az, ad2);

    // layer 2 + final: scalar gather
    agg2z_kernel<<<(N_NODES * 8 + 255) / 256, 256, 0, stream>>>(rowptr, srcSorted, az, ad2, cst, out);
}

// Round 10
// 442.482 us; speedup vs baseline: 1.3827x; 1.0910x over previous
//
#include <hip/hip_runtime.h>

#define N_NODES 50000
#define N_EDGES 800000
#define E_TOT   850000           // edges + self loops
#define IN_DIM  128
#define HID     64
#define HEADS   4
#define C1      256              // HEADS*HID
#define OUT_DIM 64
#define NEG_SLOPE 0.2f

#define XS_STRIDE   516          // 512+4 floats

#define PROJ_BLOCKS (N_NODES / 4)                  // 12500
#define COUNT_BLOCKS ((E_TOT + 255) / 256)         // 3321

// ---- bf16 helpers (manual: bf16 = top 16 bits of fp32, RNE) ----------------
__device__ __forceinline__ unsigned int bf16_rne(float f) {
    unsigned int u = __float_as_uint(f);
    return (u + 0x7FFFu + ((u >> 16) & 1u)) >> 16;
}
__device__ __forceinline__ unsigned int bf16_pack2(float a, float b) {
    return bf16_rne(a) | (bf16_rne(b) << 16);
}
__device__ __forceinline__ float bf16_lo(unsigned int u) { return __uint_as_float(u << 16); }
__device__ __forceinline__ float bf16_hi(unsigned int u) { return __uint_as_float(u & 0xFFFF0000u); }

// ---------------------------------------------------------------------------
// prep: p_src/p_dst collapse the layer-1 logit projection; v_s/v_d/v_z
// collapse ALL consumers of h2 (as2, ad2, fc dot); cst = b2.fc_w + fc_b.
// ---------------------------------------------------------------------------
__global__ __launch_bounds__(512) void prep_kernel(
    const float* __restrict__ W1, const float* __restrict__ a_src1,
    const float* __restrict__ a_dst1,
    const float* __restrict__ W2, const float* __restrict__ a_src2,
    const float* __restrict__ a_dst2, const float* __restrict__ b2,
    const float* __restrict__ fc_w, const float* __restrict__ fc_b,
    float* __restrict__ p_src, float* __restrict__ p_dst,
    float* __restrict__ v_s, float* __restrict__ v_d, float* __restrict__ v_z,
    float* __restrict__ cst)
{
    const int t = threadIdx.x;                 // 512 = 128 k * 4 h
    const int k = t >> 2, h = t & 3;
    const float* wrow = W1 + k * C1 + h * HID;
    const float* as = a_src1 + h * HID;
    const float* ad = a_dst1 + h * HID;
    float s = 0.f, d = 0.f;
    for (int c = 0; c < HID; c++) {
        float w = wrow[c];
        s = fmaf(w, as[c], s);
        d = fmaf(w, ad[c], d);
    }
    p_src[k * HEADS + h] = s;
    p_dst[k * HEADS + h] = d;

    if (t < C1) {                              // layer-2 collapse vectors
        const float* w2row = W2 + t * OUT_DIM;
        float vs = 0.f, vd = 0.f, vz = 0.f;
        for (int c = 0; c < OUT_DIM; c++) {
            float w = w2row[c];
            vs = fmaf(w, a_src2[c], vs);
            vd = fmaf(w, a_dst2[c], vd);
            vz = fmaf(w, fc_w[c], vz);
        }
        v_s[t] = vs; v_d[t] = vd; v_z[t] = vz;
    }
    if (t == 0) {
        float s2 = 0.f;
        for (int c = 0; c < OUT_DIM; c++) s2 = fmaf(b2[c], fc_w[c], s2);
        cst[0] = s2 + fc_b[0];
    }
}

// ---------------------------------------------------------------------------
// convproj_count: fused launch.
//  Blocks [0, PROJ_BLOCKS): per-node logit projections as1/ad1 AND x -> bf16.
//  Blocks [PROJ_BLOCKS, +COUNT_BLOCKS): per-edge degree count (CSR step 1).
// ---------------------------------------------------------------------------
__global__ __launch_bounds__(256) void convproj_count_kernel(
    const float* __restrict__ x, const float* __restrict__ p_src,
    const float* __restrict__ p_dst, const int* __restrict__ dst_a,
    float* __restrict__ as1, float* __restrict__ ad1,
    unsigned int* __restrict__ xb, int* __restrict__ deg)
{
    if (blockIdx.x >= PROJ_BLOCKS) {           // ---- count part ----
        int j = (blockIdx.x - PROJ_BLOCKS) * 256 + threadIdx.x;
        if (j < E_TOT) {
            int d = (j < N_EDGES) ? dst_a[j] : (j - N_EDGES);   // self loop
            atomicAdd(&deg[d], 1);
        }
        return;
    }
    // ---- proj + convert part ----
    __shared__ float ps[IN_DIM * HEADS];       // 2 KB
    __shared__ float pd[IN_DIM * HEADS];       // 2 KB
    const int t = threadIdx.x;
    for (int i = t; i < IN_DIM * HEADS; i += 256) { ps[i] = p_src[i]; pd[i] = p_dst[i]; }
    __syncthreads();
    const int node = blockIdx.x * 4 + (t >> 6);
    const int lane = t & 63;
    float2 xv = *(const float2*)(x + (size_t)node * IN_DIM + lane * 2);
    xb[(size_t)node * 64 + lane] = bf16_pack2(xv.x, xv.y);
    float4 p0 = *(const float4*)(ps + (lane * 2) * HEADS);
    float4 p1 = *(const float4*)(ps + (lane * 2 + 1) * HEADS);
    float4 q0 = *(const float4*)(pd + (lane * 2) * HEADS);
    float4 q1 = *(const float4*)(pd + (lane * 2 + 1) * HEADS);
    float s0 = xv.x * p0.x + xv.y * p1.x;
    float s1 = xv.x * p0.y + xv.y * p1.y;
    float s2 = xv.x * p0.z + xv.y * p1.z;
    float s3 = xv.x * p0.w + xv.y * p1.w;
    float d0 = xv.x * q0.x + xv.y * q1.x;
    float d1 = xv.x * q0.y + xv.y * q1.y;
    float d2 = xv.x * q0.z + xv.y * q1.z;
    float d3 = xv.x * q0.w + xv.y * q1.w;
    #pragma unroll
    for (int off = 32; off; off >>= 1) {
        s0 += __shfl_down(s0, off, 64); s1 += __shfl_down(s1, off, 64);
        s2 += __shfl_down(s2, off, 64); s3 += __shfl_down(s3, off, 64);
        d0 += __shfl_down(d0, off, 64); d1 += __shfl_down(d1, off, 64);
        d2 += __shfl_down(d2, off, 64); d3 += __shfl_down(d3, off, 64);
    }
    if (lane == 0) {
        float4 sv = {s0, s1, s2, s3};
        float4 dv = {d0, d1, d2, d3};
        *(float4*)(as1 + node * 4) = sv;
        *(float4*)(ad1 + node * 4) = dv;
    }
}

// ---------------------------------------------------------------------------
// scan + fill: CSR steps 2/3
// ---------------------------------------------------------------------------
__global__ __launch_bounds__(1024) void scan_kernel(const int* __restrict__ deg,
                                                    int* __restrict__ rowptr)
{
    __shared__ int psum[1024];
    const int t = threadIdx.x;
    const int CH = (N_NODES + 1023) / 1024;            // 49
    const int base = t * CH;
    int s = 0;
    for (int i = 0; i < CH; i++) {
        int idx = base + i;
        if (idx < N_NODES) s += deg[idx];
    }
    psum[t] = s;
    __syncthreads();
    for (int off = 1; off < 1024; off <<= 1) {
        int v = (t >= off) ? psum[t - off] : 0;
        __syncthreads();
        psum[t] += v;
        __syncthreads();
    }
    int run = (t > 0) ? psum[t - 1] : 0;
    for (int i = 0; i < CH; i++) {
        int idx = base + i;
        if (idx < N_NODES) { rowptr[idx] = run; run += deg[idx]; }
    }
    if (t == 0) rowptr[N_NODES] = E_TOT;
}

__global__ void fill_kernel(const int* __restrict__ src_a, const int* __restrict__ dst_a,
                            const int* __restrict__ rowptr, int* __restrict__ cursor,
                            int* __restrict__ srcSorted)
{
    int j = blockIdx.x * blockDim.x + threadIdx.x;
    if (j >= E_TOT) return;
    int s, d;
    if (j < N_EDGES) { s = src_a[j]; d = dst_a[j]; }
    else             { s = j - N_EDGES; d = s; }
    int pos = atomicAdd(&cursor[d], 1);
    srcSorted[rowptr[d] + pos] = s;
}

// ---------------------------------------------------------------------------
// agg1x: xaggb[n][h][k] (bf16) = softmax-weighted sum of xb[src] rows (bf16).
// One wave per dst node, lane = 2 k-channels (one packed uint), fp32 accum.
// ---------------------------------------------------------------------------
__global__ __launch_bounds__(256) void agg1x_kernel(
    const int* __restrict__ rowptr, const int* __restrict__ srcS,
    const unsigned int* __restrict__ xb, const float* __restrict__ as1,
    const float* __restrict__ ad1, unsigned int* __restrict__ xaggb)
{
    int gid  = blockIdx.x * blockDim.x + threadIdx.x;
    int n    = gid >> 6;
    int lane = threadIdx.x & 63;
    if (n >= N_NODES) return;
    float4 adv = *(const float4*)(ad1 + n * 4);
    const int e0 = rowptr[n], e1 = rowptr[n + 1];

    float2 acc0 = {0,0}, acc1 = {0,0}, acc2 = {0,0}, acc3 = {0,0};
    float den0 = 0, den1 = 0, den2 = 0, den3 = 0;
    int e = e0;
    for (; e + 2 <= e1; e += 2) {
        int s0 = srcS[e], s1 = srcS[e + 1];
        float4 A0 = *(const float4*)(as1 + s0 * 4);
        float4 A1 = *(const float4*)(as1 + s1 * 4);
        unsigned int xu0 = xb[(size_t)s0 * 64 + lane];
        unsigned int xu1 = xb[(size_t)s1 * 64 + lane];
        float a0 = A0.x + adv.x, a1 = A0.y + adv.y, a2 = A0.z + adv.z, a3 = A0.w + adv.w;
        a0 = a0 > 0.f ? a0 : NEG_SLOPE * a0;  a1 = a1 > 0.f ? a1 : NEG_SLOPE * a1;
        a2 = a2 > 0.f ? a2 : NEG_SLOPE * a2;  a3 = a3 > 0.f ? a3 : NEG_SLOPE * a3;
        float w0 = __expf(a0), w1 = __expf(a1), w2 = __expf(a2), w3 = __expf(a3);
        float b0 = A1.x + adv.x, b1v = A1.y + adv.y, b2v = A1.z + adv.z, b3 = A1.w + adv.w;
        b0 = b0 > 0.f ? b0 : NEG_SLOPE * b0;    b1v = b1v > 0.f ? b1v : NEG_SLOPE * b1v;
        b2v = b2v > 0.f ? b2v : NEG_SLOPE * b2v; b3 = b3 > 0.f ? b3 : NEG_SLOPE * b3;
        float u0 = __expf(b0), u1 = __expf(b1v), u2 = __expf(b2v), u3 = __expf(b3);
        float xa = bf16_lo(xu0), xbv = bf16_hi(xu0);
        float ya = bf16_lo(xu1), ybv = bf16_hi(xu1);
        acc0.x = fmaf(w0, xa, acc0.x); acc0.y = fmaf(w0, xbv, acc0.y);
        acc1.x = fmaf(w1, xa, acc1.x); acc1.y = fmaf(w1, xbv, acc1.y);
        acc2.x = fmaf(w2, xa, acc2.x); acc2.y = fmaf(w2, xbv, acc2.y);
        acc3.x = fmaf(w3, xa, acc3.x); acc3.y = fmaf(w3, xbv, acc3.y);
        acc0.x = fmaf(u0, ya, acc0.x); acc0.y = fmaf(u0, ybv, acc0.y);
        acc1.x = fmaf(u1, ya, acc1.x); acc1.y = fmaf(u1, ybv, acc1.y);
        acc2.x = fmaf(u2, ya, acc2.x); acc2.y = fmaf(u2, ybv, acc2.y);
        acc3.x = fmaf(u3, ya, acc3.x); acc3.y = fmaf(u3, ybv, acc3.y);
        den0 += w0 + u0; den1 += w1 + u1; den2 += w2 + u2; den3 += w3 + u3;
    }
    for (; e < e1; e++) {
        int s = srcS[e];
        float4 A0 = *(const float4*)(as1 + s * 4);
        unsigned int xu = xb[(size_t)s * 64 + lane];
        float a0 = A0.x + adv.x, a1 = A0.y + adv.y, a2 = A0.z + adv.z, a3 = A0.w + adv.w;
        a0 = a0 > 0.f ? a0 : NEG_SLOPE * a0;  a1 = a1 > 0.f ? a1 : NEG_SLOPE * a1;
        a2 = a2 > 0.f ? a2 : NEG_SLOPE * a2;  a3 = a3 > 0.f ? a3 : NEG_SLOPE * a3;
        float w0 = __expf(a0), w1 = __expf(a1), w2 = __expf(a2), w3 = __expf(a3);
        float xa = bf16_lo(xu), xbv = bf16_hi(xu);
        acc0.x = fmaf(w0, xa, acc0.x); acc0.y = fmaf(w0, xbv, acc0.y);
        acc1.x = fmaf(w1, xa, acc1.x); acc1.y = fmaf(w1, xbv, acc1.y);
        acc2.x = fmaf(w2, xa, acc2.x); acc2.y = fmaf(w2, xbv, acc2.y);
        acc3.x = fmaf(w3, xa, acc3.x); acc3.y = fmaf(w3, xbv, acc3.y);
        den0 += w0; den1 += w1; den2 += w2; den3 += w3;
    }
    float i0 = 1.f / (den0 + 1e-16f), i1 = 1.f / (den1 + 1e-16f);
    float i2 = 1.f / (den2 + 1e-16f), i3 = 1.f / (den3 + 1e-16f);
    unsigned int* o = xaggb + (size_t)n * 256 + lane;      // row = 256 uints
    o[0 * 64] = bf16_pack2(acc0.x * i0, acc0.y * i0);
    o[1 * 64] = bf16_pack2(acc1.x * i1, acc1.y * i1);
    o[2 * 64] = bf16_pack2(acc2.x * i2, acc2.y * i2);
    o[3 * 64] = bf16_pack2(acc3.x * i3, acc3.y * i3);
}

// ---------------------------------------------------------------------------
// mlp6: 16 nodes/block, min 4 waves/EU (33.8 KB LDS -> 4 blocks/CU).
//  Phase A: stage bf16 xagg tile -> fp32 LDS.
//  Phase B: mlp4's proven 4col x 4node mapping (8 float4 W regs: prefetch
//           fits the register budget, unlike mlp5's 16); wave = head so W1
//           is read once per block.
//  Epilogue IN REGISTERS: act=ELU(acc+b1) then s/d/z dots with v_s/v_d/v_z,
//           width-16 shuffle reduce, 768 B LDS cross-wave reduce. The act
//           LDS tile and its barrier round-trip are gone.
// ---------------------------------------------------------------------------
__global__ __launch_bounds__(256, 4) void mlp6_kernel(
    const unsigned int* __restrict__ xaggb,
    const float* __restrict__ W1, const float* __restrict__ b1,
    const float* __restrict__ v_s, const float* __restrict__ v_d,
    const float* __restrict__ v_z,
    float2* __restrict__ az, float* __restrict__ ad2)
{
    __shared__ float xs[16 * XS_STRIDE];       // 33,024 B
    __shared__ float pr[4 * 16 * 3];           // 768 B cross-wave partials
    const int t = threadIdx.x;
    const int nodeBase = blockIdx.x * 16;
    const int wv = t >> 6;

    {   // ---- Phase A: stage 16x512ch (bf16) -> fp32 LDS ----
        const unsigned int* gsrc = xaggb + (size_t)nodeBase * 256;
        #pragma unroll
        for (int i = 0; i < 4; i++) {
            int iu = i * 1024 + t * 4;         // uint index in 4096-uint tile
            uint4 v = *(const uint4*)(gsrc + iu);
            int n = iu >> 8, c = (iu & 255) * 2;
            float4 f0 = {bf16_lo(v.x), bf16_hi(v.x), bf16_lo(v.y), bf16_hi(v.y)};
            float4 f1 = {bf16_lo(v.z), bf16_hi(v.z), bf16_lo(v.w), bf16_hi(v.w)};
            *(float4*)(xs + n * XS_STRIDE + c)     = f0;
            *(float4*)(xs + n * XS_STRIDE + c + 4) = f1;
        }
    }
    __syncthreads();

    {   // ---- Phase B + register epilogue ----
        const int q  = t & 15;                 // col-quad within head
        const int g  = (t >> 4) & 3;           // node group (4 nodes)
        const int h  = wv;                     // head = wave
        const int c0 = h * HID + q * 4;
        const float* Wp = W1 + c0;
        float4 w0 = *(const float4*)(Wp + (size_t)0 * C1);
        float4 w1 = *(const float4*)(Wp + (size_t)1 * C1);
        float4 w2 = *(const float4*)(Wp + (size_t)2 * C1);
        float4 w3 = *(const float4*)(Wp + (size_t)3 * C1);
        float acc[4][4];
        #pragma unroll
        for (int i = 0; i < 4; i++)
            #pragma unroll
            for (int m = 0; m < 4; m++) acc[i][m] = 0.f;
        const float* xbase = xs + (g * 4) * XS_STRIDE + h * IN_DIM;
        for (int k = 0; k < IN_DIM; k += 4) {
            const int kn = (k + 4 < IN_DIM) ? k + 4 : k;   // clamped prefetch
            float4 nw0 = *(const float4*)(Wp + (size_t)(kn + 0) * C1);
            float4 nw1 = *(const float4*)(Wp + (size_t)(kn + 1) * C1);
            float4 nw2 = *(const float4*)(Wp + (size_t)(kn + 2) * C1);
            float4 nw3 = *(const float4*)(Wp + (size_t)(kn + 3) * C1);
            #pragma unroll
            for (int i = 0; i < 4; i++) {
                float4 xv = *(const float4*)(xbase + i * XS_STRIDE + k);
                acc[i][0] = fmaf(xv.x, w0.x, acc[i][0]); acc[i][0] = fmaf(xv.y, w1.x, acc[i][0]);
                acc[i][0] = fmaf(xv.z, w2.x, acc[i][0]); acc[i][0] = fmaf(xv.w, w3.x, acc[i][0]);
                acc[i][1] = fmaf(xv.x, w0.y, acc[i][1]); acc[i][1] = fmaf(xv.y, w1.y, acc[i][1]);
                acc[i][1] = fmaf(xv.z, w2.y, acc[i][1]); acc[i][1] = fmaf(xv.w, w3.y, acc[i][1]);
                acc[i][2] = fmaf(xv.x, w0.z, acc[i][2]); acc[i][2] = fmaf(xv.y, w1.z, acc[i][2]);
                acc[i][2] = fmaf(xv.z, w2.z, acc[i][2]); acc[i][2] = fmaf(xv.w, w3.z, acc[i][2]);
                acc[i][3] = fmaf(xv.x, w0.w, acc[i][3]); acc[i][3] = fmaf(xv.y, w1.w, acc[i][3]);
                acc[i][3] = fmaf(xv.z, w2.w, acc[i][3]); acc[i][3] = fmaf(xv.w, w3.w, acc[i][3]);
            }
            w0 = nw0; w1 = nw1; w2 = nw2; w3 = nw3;
        }
        float4 bb  = *(const float4*)(b1 + c0);
        float4 vs4 = *(const float4*)(v_s + c0);
        float4 vd4 = *(const float4*)(v_d + c0);
        float4 vz4 = *(const float4*)(v_z + c0);
        float S[4], D[4], Z[4];
        #pragma unroll
        for (int i = 0; i < 4; i++) {
            float o0 = acc[i][0] + bb.x, o1 = acc[i][1] + bb.y;
            float o2 = acc[i][2] + bb.z, o3 = acc[i][3] + bb.w;
            o0 = o0 > 0.f ? o0 : __expf(o0) - 1.f;     // ELU in registers
            o1 = o1 > 0.f ? o1 : __expf(o1) - 1.f;
            o2 = o2 > 0.f ? o2 : __expf(o2) - 1.f;
            o3 = o3 > 0.f ? o3 : __expf(o3) - 1.f;
            S[i] = o0 * vs4.x + o1 * vs4.y + o2 * vs4.z + o3 * vs4.w;
            D[i] = o0 * vd4.x + o1 * vd4.y + o2 * vd4.z + o3 * vd4.w;
            Z[i] = o0 * vz4.x + o1 * vz4.y + o2 * vz4.z + o3 * vz4.w;
        }
        #pragma unroll
        for (int off = 8; off; off >>= 1) {
            #pragma unroll
            for (int i = 0; i < 4; i++) {
                S[i] += __shfl_down(S[i], off, 16);
                D[i] += __shfl_down(D[i], off, 16);
                Z[i] += __shfl_down(Z[i], off, 16);
            }
        }
        if (q == 0) {
            #pragma unroll
            for (int i = 0; i < 4; i++) {
                const int ln = g * 4 + i;      // local node 0..15
                pr[(wv * 16 + ln) * 3 + 0] = S[i];
                pr[(wv * 16 + ln) * 3 + 1] = D[i];
                pr[(wv * 16 + ln) * 3 + 2] = Z[i];
            }
        }
    }
    __syncthreads();

    if (t < 16) {   // ---- cross-wave reduce + store ----
        float s = 0.f, d = 0.f, z = 0.f;
        #pragma unroll
        for (int w = 0; w < 4; w++) {
            s += pr[(w * 16 + t) * 3 + 0];
            d += pr[(w * 16 + t) * 3 + 1];
            z += pr[(w * 16 + t) * 3 + 2];
        }
        const int node = nodeBase + t;
        float2 azv = {s, z};
        az[node]  = azv;
        ad2[node] = d;
    }
}

// ---------------------------------------------------------------------------
// agg2z: out[n] = sum_e w_e * z[src] / sum_e w_e + cst.  8 B/edge gather.
// ---------------------------------------------------------------------------
__global__ __launch_bounds__(256) void agg2z_kernel(
    const int* __restrict__ rowptr, const int* __restrict__ srcS,
    const float2* __restrict__ az, const float* __restrict__ ad2,
    const float* __restrict__ cst, float* __restrict__ out)
{
    int gid  = blockIdx.x * blockDim.x + threadIdx.x;
    int n    = gid >> 3;                       // 8 lanes per node
    int sl   = threadIdx.x & 7;
    if (n >= N_NODES) return;
    const float adh = ad2[n];
    const int e0 = rowptr[n], e1 = rowptr[n + 1];

    float acc = 0.f, den = 0.f;
    for (int e = e0 + sl; e < e1; e += 8) {
        int s = srcS[e];
        float2 v = az[s];
        float a = v.x + adh;
        a = a > 0.f ? a : NEG_SLOPE * a;
        float w = __expf(a);
        acc = fmaf(w, v.y, acc);
        den += w;
    }
    #pragma unroll
    for (int off = 4; off; off >>= 1) {
        acc += __shfl_down(acc, off, 8);
        den += __shfl_down(den, off, 8);
    }
    if (sl == 0) out[n] = acc / (den + 1e-16f) + cst[0];
}

extern "C" void kernel_launch(void* const* d_in, const int* in_sizes, int n_in,
                              void* d_out, int out_size, void* d_ws, size_t ws_size,
                              hipStream_t stream)
{
    const float* x      = (const float*)d_in[0];
    const int*   ei     = (const int*)d_in[1];
    const float* W1     = (const float*)d_in[2];
    const float* a_src1 = (const float*)d_in[3];
    const float* a_dst1 = (const float*)d_in[4];
    const float* b1     = (const float*)d_in[5];
    const float* W2     = (const float*)d_in[6];
    const float* a_src2 = (const float*)d_in[7];
    const float* a_dst2 = (const float*)d_in[8];
    const float* b2     = (const float*)d_in[9];
    const float* fc_w   = (const float*)d_in[10];
    const float* fc_b   = (const float*)d_in[11];
    float* out = (float*)d_out;

    const int* srcA = ei;
    const int* dstA = ei + N_EDGES;

    // workspace layout
    float* ws = (float*)d_ws;
    size_t off = 0;
    unsigned int* xaggb = (unsigned int*)(ws + off); off += (size_t)N_NODES * 256;  // 51.2 MB
    unsigned int* xb    = (unsigned int*)(ws + off); off += (size_t)N_NODES * 64;   // 12.8 MB
    float* as1     = ws + off; off += (size_t)N_NODES * HEADS;
    float* ad1     = ws + off; off += (size_t)N_NODES * HEADS;
    float2* az     = (float2*)(ws + off); off += (size_t)N_NODES * 2;
    float* ad2     = ws + off; off += N_NODES;
    float* p_src   = ws + off; off += IN_DIM * HEADS;
    float* p_dst   = ws + off; off += IN_DIM * HEADS;
    float* v_s     = ws + off; off += C1;
    float* v_d     = ws + off; off += C1;
    float* v_z     = ws + off; off += C1;
    float* cst     = ws + off; off += 2;
    int* rowptr    = (int*)(ws + off); off += N_NODES + 2;
    int* srcSorted = (int*)(ws + off); off += E_TOT;
    int* zstart    = (int*)(ws + off);
    int* deg       = (int*)(ws + off); off += N_NODES;
    int* cursor    = (int*)(ws + off); off += N_NODES;
    hipMemsetAsync(zstart, 0, 2 * N_NODES * sizeof(int), stream);

    // projection collapses: p_src/p_dst (layer 1), v_s/v_d/v_z + cst (layer 2)
    prep_kernel<<<1, 512, 0, stream>>>(W1, a_src1, a_dst1, W2, a_src2, a_dst2,
                                       b2, fc_w, fc_b, p_src, p_dst, v_s, v_d, v_z, cst);

    // fused: per-node proj + x->bf16 convert, plus CSR degree count
    convproj_count_kernel<<<PROJ_BLOCKS + COUNT_BLOCKS, 256, 0, stream>>>(
        x, p_src, p_dst, dstA, as1, ad1, xb, deg);

    // CSR: scan + fill
    scan_kernel<<<1, 1024, 0, stream>>>(deg, rowptr);
    fill_kernel<<<COUNT_BLOCKS, 256, 0, stream>>>(srcA, dstA, rowptr, cursor, srcSorted);

    // layer-1 aggregation in bf16 x-space
    agg1x_kernel<<<(N_NODES * 64 + 255) / 256, 256, 0, stream>>>(rowptr, srcSorted, xb, as1, ad1, xaggb);

    // fused MLP (phase C collapsed; epilogue in registers)
    mlp6_kernel<<<N_NODES / 16, 256, 0, stream>>>(xaggb, W1, b1, v_s, v_d, v_z, az, ad2);

    // layer 2 + final: scalar gather
    agg2z_kernel<<<(N_NODES * 8 + 255) / 256, 256, 0, stream>>>(rowptr, srcSorted, az, ad2, cst, out);
}

// Round 12
// 356.329 us; speedup vs baseline: 1.7170x; 1.2418x over previous
//
#include <hip/hip_runtime.h>

#define N_NODES 50000
#define N_EDGES 800000
#define E_TOT   850000           // edges + self loops
#define IN_DIM  128
#define HID     64
#define HEADS   4
#define C1      256              // HEADS*HID
#define OUT_DIM 64
#define NEG_SLOPE 0.2f

#define XS_STRIDE   516          // 512+4 floats

#define PROJ_BLOCKS (N_NODES / 4)                  // 12500
#define COUNT_BLOCKS ((E_TOT + 255) / 256)         // 3321
#define NB_SCAN ((N_NODES + 255) / 256)            // 196

// ---- bf16 helpers (manual: bf16 = top 16 bits of fp32, RNE) ----------------
__device__ __forceinline__ unsigned int bf16_rne(float f) {
    unsigned int u = __float_as_uint(f);
    return (u + 0x7FFFu + ((u >> 16) & 1u)) >> 16;
}
__device__ __forceinline__ unsigned int bf16_pack2(float a, float b) {
    return bf16_rne(a) | (bf16_rne(b) << 16);
}
__device__ __forceinline__ float bf16_lo(unsigned int u) { return __uint_as_float(u << 16); }
__device__ __forceinline__ float bf16_hi(unsigned int u) { return __uint_as_float(u & 0xFFFF0000u); }

// ---------------------------------------------------------------------------
// prep: p_src/p_dst collapse the layer-1 logit projection; v_s/v_d/v_z
// collapse ALL consumers of h2 (as2, ad2, fc dot); cst = b2.fc_w + fc_b.
// ---------------------------------------------------------------------------
__global__ __launch_bounds__(512) void prep_kernel(
    const float* __restrict__ W1, const float* __restrict__ a_src1,
    const float* __restrict__ a_dst1,
    const float* __restrict__ W2, const float* __restrict__ a_src2,
    const float* __restrict__ a_dst2, const float* __restrict__ b2,
    const float* __restrict__ fc_w, const float* __restrict__ fc_b,
    float* __restrict__ p_src, float* __restrict__ p_dst,
    float* __restrict__ v_s, float* __restrict__ v_d, float* __restrict__ v_z,
    float* __restrict__ cst)
{
    const int t = threadIdx.x;                 // 512 = 128 k * 4 h
    const int k = t >> 2, h = t & 3;
    const float* wrow = W1 + k * C1 + h * HID;
    const float* as = a_src1 + h * HID;
    const float* ad = a_dst1 + h * HID;
    float s = 0.f, d = 0.f;
    for (int c = 0; c < HID; c++) {
        float w = wrow[c];
        s = fmaf(w, as[c], s);
        d = fmaf(w, ad[c], d);
    }
    p_src[k * HEADS + h] = s;
    p_dst[k * HEADS + h] = d;

    if (t < C1) {                              // layer-2 collapse vectors
        const float* w2row = W2 + t * OUT_DIM;
        float vs = 0.f, vd = 0.f, vz = 0.f;
        for (int c = 0; c < OUT_DIM; c++) {
            float w = w2row[c];
            vs = fmaf(w, a_src2[c], vs);
            vd = fmaf(w, a_dst2[c], vd);
            vz = fmaf(w, fc_w[c], vz);
        }
        v_s[t] = vs; v_d[t] = vd; v_z[t] = vz;
    }
    if (t == 0) {
        float s2 = 0.f;
        for (int c = 0; c < OUT_DIM; c++) s2 = fmaf(b2[c], fc_w[c], s2);
        cst[0] = s2 + fc_b[0];
    }
}

// ---------------------------------------------------------------------------
// convproj_count: fused launch.
//  Blocks [0, PROJ_BLOCKS): per-node logit projections as1/ad1 AND x -> bf16.
//  Blocks [PROJ_BLOCKS, +COUNT_BLOCKS): per-edge degree count (CSR step 1).
// ---------------------------------------------------------------------------
__global__ __launch_bounds__(256) void convproj_count_kernel(
    const float* __restrict__ x, const float* __restrict__ p_src,
    const float* __restrict__ p_dst, const int* __restrict__ dst_a,
    float* __restrict__ as1, float* __restrict__ ad1,
    unsigned int* __restrict__ xb, int* __restrict__ deg)
{
    if (blockIdx.x >= PROJ_BLOCKS) {           // ---- count part ----
        int j = (blockIdx.x - PROJ_BLOCKS) * 256 + threadIdx.x;
        if (j < E_TOT) {
            int d = (j < N_EDGES) ? dst_a[j] : (j - N_EDGES);   // self loop
            atomicAdd(&deg[d], 1);
        }
        return;
    }
    // ---- proj + convert part ----
    __shared__ float ps[IN_DIM * HEADS];       // 2 KB
    __shared__ float pd[IN_DIM * HEADS];       // 2 KB
    const int t = threadIdx.x;
    for (int i = t; i < IN_DIM * HEADS; i += 256) { ps[i] = p_src[i]; pd[i] = p_dst[i]; }
    __syncthreads();
    const int node = blockIdx.x * 4 + (t >> 6);
    const int lane = t & 63;
    float2 xv = *(const float2*)(x + (size_t)node * IN_DIM + lane * 2);
    xb[(size_t)node * 64 + lane] = bf16_pack2(xv.x, xv.y);
    float4 p0 = *(const float4*)(ps + (lane * 2) * HEADS);
    float4 p1 = *(const float4*)(ps + (lane * 2 + 1) * HEADS);
    float4 q0 = *(const float4*)(pd + (lane * 2) * HEADS);
    float4 q1 = *(const float4*)(pd + (lane * 2 + 1) * HEADS);
    float s0 = xv.x * p0.x + xv.y * p1.x;
    float s1 = xv.x * p0.y + xv.y * p1.y;
    float s2 = xv.x * p0.z + xv.y * p1.z;
    float s3 = xv.x * p0.w + xv.y * p1.w;
    float d0 = xv.x * q0.x + xv.y * q1.x;
    float d1 = xv.x * q0.y + xv.y * q1.y;
    float d2 = xv.x * q0.z + xv.y * q1.z;
    float d3 = xv.x * q0.w + xv.y * q1.w;
    #pragma unroll
    for (int off = 32; off; off >>= 1) {
        s0 += __shfl_down(s0, off, 64); s1 += __shfl_down(s1, off, 64);
        s2 += __shfl_down(s2, off, 64); s3 += __shfl_down(s3, off, 64);
        d0 += __shfl_down(d0, off, 64); d1 += __shfl_down(d1, off, 64);
        d2 += __shfl_down(d2, off, 64); d3 += __shfl_down(d3, off, 64);
    }
    if (lane == 0) {
        float4 sv = {s0, s1, s2, s3};
        float4 dv = {d0, d1, d2, d3};
        *(float4*)(as1 + node * 4) = sv;
        *(float4*)(ad1 + node * 4) = dv;
    }
}

// ---------------------------------------------------------------------------
// Parallel CSR scan (replaces the 92 us single-block scan):
//  blocksum: per-256-chunk sums (plain LDS tree reduce — no shuffles)
//  scanbsum: one small block scans the NB_SCAN sums -> exclusive offsets
//  expand:   per-chunk 256-wide LDS scan + offset -> rowptr (incl. [N_NODES])
// ---------------------------------------------------------------------------
__global__ __launch_bounds__(256) void blocksum_kernel(
    const int* __restrict__ deg, int* __restrict__ bsum)
{
    __shared__ int ps[256];
    const int t = threadIdx.x;
    int i = blockIdx.x * 256 + t;
    ps[t] = (i < N_NODES) ? deg[i] : 0;
    __syncthreads();
    for (int off = 128; off; off >>= 1) {
        if (t < off) ps[t] += ps[t + off];
        __syncthreads();
    }
    if (t == 0) bsum[blockIdx.x] = ps[0];
}

__global__ __launch_bounds__(256) void scanbsum_kernel(
    const int* __restrict__ bsum, int* __restrict__ boff)
{
    __shared__ int ps[256];
    const int t = threadIdx.x;
    ps[t] = (t < NB_SCAN) ? bsum[t] : 0;
    __syncthreads();
    for (int off = 1; off < 256; off <<= 1) {
        int u = (t >= off) ? ps[t - off] : 0;
        __syncthreads();
        ps[t] += u;
        __syncthreads();
    }
    boff[t] = (t > 0) ? ps[t - 1] : 0;         // exclusive
}

__global__ __launch_bounds__(256) void expand_kernel(
    const int* __restrict__ deg, const int* __restrict__ boff,
    int* __restrict__ rowptr)
{
    __shared__ int ps[256];
    const int t = threadIdx.x;
    int i = blockIdx.x * 256 + t;
    int v = (i < N_NODES) ? deg[i] : 0;
    ps[t] = v;
    __syncthreads();
    for (int off = 1; off < 256; off <<= 1) {
        int u = (t >= off) ? ps[t - off] : 0;
        __syncthreads();
        ps[t] += u;
        __syncthreads();
    }
    if (i <= N_NODES) rowptr[i] = boff[blockIdx.x] + ps[t] - v;   // exclusive
}

__global__ void fill_kernel(const int* __restrict__ src_a, const int* __restrict__ dst_a,
                            const int* __restrict__ rowptr, int* __restrict__ cursor,
                            int* __restrict__ srcSorted)
{
    int j = blockIdx.x * blockDim.x + threadIdx.x;
    if (j >= E_TOT) return;
    int s, d;
    if (j < N_EDGES) { s = src_a[j]; d = dst_a[j]; }
    else             { s = j - N_EDGES; d = s; }
    int pos = atomicAdd(&cursor[d], 1);
    srcSorted[rowptr[d] + pos] = s;
}

// ---------------------------------------------------------------------------
// agg1x: xaggb[n][h][k] (bf16) = softmax-weighted sum of xb[src] rows (bf16).
// One wave per dst node, lane = 2 k-channels (one packed uint), fp32 accum.
// ---------------------------------------------------------------------------
__global__ __launch_bounds__(256) void agg1x_kernel(
    const int* __restrict__ rowptr, const int* __restrict__ srcS,
    const unsigned int* __restrict__ xb, const float* __restrict__ as1,
    const float* __restrict__ ad1, unsigned int* __restrict__ xaggb)
{
    int gid  = blockIdx.x * blockDim.x + threadIdx.x;
    int n    = gid >> 6;
    int lane = threadIdx.x & 63;
    if (n >= N_NODES) return;
    float4 adv = *(const float4*)(ad1 + n * 4);
    const int e0 = rowptr[n], e1 = rowptr[n + 1];

    float2 acc0 = {0,0}, acc1 = {0,0}, acc2 = {0,0}, acc3 = {0,0};
    float den0 = 0, den1 = 0, den2 = 0, den3 = 0;
    int e = e0;
    for (; e + 2 <= e1; e += 2) {
        int s0 = srcS[e], s1 = srcS[e + 1];
        float4 A0 = *(const float4*)(as1 + s0 * 4);
        float4 A1 = *(const float4*)(as1 + s1 * 4);
        unsigned int xu0 = xb[(size_t)s0 * 64 + lane];
        unsigned int xu1 = xb[(size_t)s1 * 64 + lane];
        float a0 = A0.x + adv.x, a1 = A0.y + adv.y, a2 = A0.z + adv.z, a3 = A0.w + adv.w;
        a0 = a0 > 0.f ? a0 : NEG_SLOPE * a0;  a1 = a1 > 0.f ? a1 : NEG_SLOPE * a1;
        a2 = a2 > 0.f ? a2 : NEG_SLOPE * a2;  a3 = a3 > 0.f ? a3 : NEG_SLOPE * a3;
        float w0 = __expf(a0), w1 = __expf(a1), w2 = __expf(a2), w3 = __expf(a3);
        float b0 = A1.x + adv.x, b1v = A1.y + adv.y, b2v = A1.z + adv.z, b3 = A1.w + adv.w;
        b0 = b0 > 0.f ? b0 : NEG_SLOPE * b0;    b1v = b1v > 0.f ? b1v : NEG_SLOPE * b1v;
        b2v = b2v > 0.f ? b2v : NEG_SLOPE * b2v; b3 = b3 > 0.f ? b3 : NEG_SLOPE * b3;
        float u0 = __expf(b0), u1 = __expf(b1v), u2 = __expf(b2v), u3 = __expf(b3);
        float xa = bf16_lo(xu0), xbv = bf16_hi(xu0);
        float ya = bf16_lo(xu1), ybv = bf16_hi(xu1);
        acc0.x = fmaf(w0, xa, acc0.x); acc0.y = fmaf(w0, xbv, acc0.y);
        acc1.x = fmaf(w1, xa, acc1.x); acc1.y = fmaf(w1, xbv, acc1.y);
        acc2.x = fmaf(w2, xa, acc2.x); acc2.y = fmaf(w2, xbv, acc2.y);
        acc3.x = fmaf(w3, xa, acc3.x); acc3.y = fmaf(w3, xbv, acc3.y);
        acc0.x = fmaf(u0, ya, acc0.x); acc0.y = fmaf(u0, ybv, acc0.y);
        acc1.x = fmaf(u1, ya, acc1.x); acc1.y = fmaf(u1, ybv, acc1.y);
        acc2.x = fmaf(u2, ya, acc2.x); acc2.y = fmaf(u2, ybv, acc2.y);
        acc3.x = fmaf(u3, ya, acc3.x); acc3.y = fmaf(u3, ybv, acc3.y);
        den0 += w0 + u0; den1 += w1 + u1; den2 += w2 + u2; den3 += w3 + u3;
    }
    for (; e < e1; e++) {
        int s = srcS[e];
        float4 A0 = *(const float4*)(as1 + s * 4);
        unsigned int xu = xb[(size_t)s * 64 + lane];
        float a0 = A0.x + adv.x, a1 = A0.y + adv.y, a2 = A0.z + adv.z, a3 = A0.w + adv.w;
        a0 = a0 > 0.f ? a0 : NEG_SLOPE * a0;  a1 = a1 > 0.f ? a1 : NEG_SLOPE * a1;
        a2 = a2 > 0.f ? a2 : NEG_SLOPE * a2;  a3 = a3 > 0.f ? a3 : NEG_SLOPE * a3;
        float w0 = __expf(a0), w1 = __expf(a1), w2 = __expf(a2), w3 = __expf(a3);
        float xa = bf16_lo(xu), xbv = bf16_hi(xu);
        acc0.x = fmaf(w0, xa, acc0.x); acc0.y = fmaf(w0, xbv, acc0.y);
        acc1.x = fmaf(w1, xa, acc1.x); acc1.y = fmaf(w1, xbv, acc1.y);
        acc2.x = fmaf(w2, xa, acc2.x); acc2.y = fmaf(w2, xbv, acc2.y);
        acc3.x = fmaf(w3, xa, acc3.x); acc3.y = fmaf(w3, xbv, acc3.y);
        den0 += w0; den1 += w1; den2 += w2; den3 += w3;
    }
    float i0 = 1.f / (den0 + 1e-16f), i1 = 1.f / (den1 + 1e-16f);
    float i2 = 1.f / (den2 + 1e-16f), i3 = 1.f / (den3 + 1e-16f);
    unsigned int* o = xaggb + (size_t)n * 256 + lane;      // row = 256 uints
    o[0 * 64] = bf16_pack2(acc0.x * i0, acc0.y * i0);
    o[1 * 64] = bf16_pack2(acc1.x * i1, acc1.y * i1);
    o[2 * 64] = bf16_pack2(acc2.x * i2, acc2.y * i2);
    o[3 * 64] = bf16_pack2(acc3.x * i3, acc3.y * i3);
}

// ---------------------------------------------------------------------------
// mlp6: 16 nodes/block, min 4 waves/EU (33.8 KB LDS -> 4 blocks/CU).
//  Phase A: stage bf16 xagg tile -> fp32 LDS.
//  Phase B: proven 4col x 4node mapping; wave = head (W1 once/block),
//           software prefetch one k-iter ahead.
//  Epilogue in registers: ELU then v_s/v_d/v_z dots, shuffle + LDS reduce.
// ---------------------------------------------------------------------------
__global__ __launch_bounds__(256, 4) void mlp6_kernel(
    const unsigned int* __restrict__ xaggb,
    const float* __restrict__ W1, const float* __restrict__ b1,
    const float* __restrict__ v_s, const float* __restrict__ v_d,
    const float* __restrict__ v_z,
    float2* __restrict__ az, float* __restrict__ ad2)
{
    __shared__ float xs[16 * XS_STRIDE];       // 33,024 B
    __shared__ float pr[4 * 16 * 3];           // 768 B cross-wave partials
    const int t = threadIdx.x;
    const int nodeBase = blockIdx.x * 16;
    const int wv = t >> 6;

    {   // ---- Phase A: stage 16x512ch (bf16) -> fp32 LDS ----
        const unsigned int* gsrc = xaggb + (size_t)nodeBase * 256;
        #pragma unroll
        for (int i = 0; i < 4; i++) {
            int iu = i * 1024 + t * 4;         // uint index in 4096-uint tile
            uint4 v = *(const uint4*)(gsrc + iu);
            int n = iu >> 8, c = (iu & 255) * 2;
            float4 f0 = {bf16_lo(v.x), bf16_hi(v.x), bf16_lo(v.y), bf16_hi(v.y)};
            float4 f1 = {bf16_lo(v.z), bf16_hi(v.z), bf16_lo(v.w), bf16_hi(v.w)};
            *(float4*)(xs + n * XS_STRIDE + c)     = f0;
            *(float4*)(xs + n * XS_STRIDE + c + 4) = f1;
        }
    }
    __syncthreads();

    {   // ---- Phase B + register epilogue ----
        const int q  = t & 15;                 // col-quad within head
        const int g  = (t >> 4) & 3;           // node group (4 nodes)
        const int h  = wv;                     // head = wave
        const int c0 = h * HID + q * 4;
        const float* Wp = W1 + c0;
        float4 w0 = *(const float4*)(Wp + (size_t)0 * C1);
        float4 w1 = *(const float4*)(Wp + (size_t)1 * C1);
        float4 w2 = *(const float4*)(Wp + (size_t)2 * C1);
        float4 w3 = *(const float4*)(Wp + (size_t)3 * C1);
        float acc[4][4];
        #pragma unroll
        for (int i = 0; i < 4; i++)
            #pragma unroll
            for (int m = 0; m < 4; m++) acc[i][m] = 0.f;
        const float* xbase = xs + (g * 4) * XS_STRIDE + h * IN_DIM;
        for (int k = 0; k < IN_DIM; k += 4) {
            const int kn = (k + 4 < IN_DIM) ? k + 4 : k;   // clamped prefetch
            float4 nw0 = *(const float4*)(Wp + (size_t)(kn + 0) * C1);
            float4 nw1 = *(const float4*)(Wp + (size_t)(kn + 1) * C1);
            float4 nw2 = *(const float4*)(Wp + (size_t)(kn + 2) * C1);
            float4 nw3 = *(const float4*)(Wp + (size_t)(kn + 3) * C1);
            #pragma unroll
            for (int i = 0; i < 4; i++) {
                float4 xv = *(const float4*)(xbase + i * XS_STRIDE + k);
                acc[i][0] = fmaf(xv.x, w0.x, acc[i][0]); acc[i][0] = fmaf(xv.y, w1.x, acc[i][0]);
                acc[i][0] = fmaf(xv.z, w2.x, acc[i][0]); acc[i][0] = fmaf(xv.w, w3.x, acc[i][0]);
                acc[i][1] = fmaf(xv.x, w0.y, acc[i][1]); acc[i][1] = fmaf(xv.y, w1.y, acc[i][1]);
                acc[i][1] = fmaf(xv.z, w2.y, acc[i][1]); acc[i][1] = fmaf(xv.w, w3.y, acc[i][1]);
                acc[i][2] = fmaf(xv.x, w0.z, acc[i][2]); acc[i][2] = fmaf(xv.y, w1.z, acc[i][2]);
                acc[i][2] = fmaf(xv.z, w2.z, acc[i][2]); acc[i][2] = fmaf(xv.w, w3.z, acc[i][2]);
                acc[i][3] = fmaf(xv.x, w0.w, acc[i][3]); acc[i][3] = fmaf(xv.y, w1.w, acc[i][3]);
                acc[i][3] = fmaf(xv.z, w2.w, acc[i][3]); acc[i][3] = fmaf(xv.w, w3.w, acc[i][3]);
            }
            w0 = nw0; w1 = nw1; w2 = nw2; w3 = nw3;
        }
        float4 bb  = *(const float4*)(b1 + c0);
        float4 vs4 = *(const float4*)(v_s + c0);
        float4 vd4 = *(const float4*)(v_d + c0);
        float4 vz4 = *(const float4*)(v_z + c0);
        float S[4], D[4], Z[4];
        #pragma unroll
        for (int i = 0; i < 4; i++) {
            float o0 = acc[i][0] + bb.x, o1 = acc[i][1] + bb.y;
            float o2 = acc[i][2] + bb.z, o3 = acc[i][3] + bb.w;
            o0 = o0 > 0.f ? o0 : __expf(o0) - 1.f;     // ELU in registers
            o1 = o1 > 0.f ? o1 : __expf(o1) - 1.f;
            o2 = o2 > 0.f ? o2 : __expf(o2) - 1.f;
            o3 = o3 > 0.f ? o3 : __expf(o3) - 1.f;
            S[i] = o0 * vs4.x + o1 * vs4.y + o2 * vs4.z + o3 * vs4.w;
            D[i] = o0 * vd4.x + o1 * vd4.y + o2 * vd4.z + o3 * vd4.w;
            Z[i] = o0 * vz4.x + o1 * vz4.y + o2 * vz4.z + o3 * vz4.w;
        }
        #pragma unroll
        for (int off = 8; off; off >>= 1) {
            #pragma unroll
            for (int i = 0; i < 4; i++) {
                S[i] += __shfl_down(S[i], off, 16);
                D[i] += __shfl_down(D[i], off, 16);
                Z[i] += __shfl_down(Z[i], off, 16);
            }
        }
        if (q == 0) {
            #pragma unroll
            for (int i = 0; i < 4; i++) {
                const int ln = g * 4 + i;      // local node 0..15
                pr[(wv * 16 + ln) * 3 + 0] = S[i];
                pr[(wv * 16 + ln) * 3 + 1] = D[i];
                pr[(wv * 16 + ln) * 3 + 2] = Z[i];
            }
        }
    }
    __syncthreads();

    if (t < 16) {   // ---- cross-wave reduce + store ----
        float s = 0.f, d = 0.f, z = 0.f;
        #pragma unroll
        for (int w = 0; w < 4; w++) {
            s += pr[(w * 16 + t) * 3 + 0];
            d += pr[(w * 16 + t) * 3 + 1];
            z += pr[(w * 16 + t) * 3 + 2];
        }
        const int node = nodeBase + t;
        float2 azv = {s, z};
        az[node]  = azv;
        ad2[node] = d;
    }
}

// ---------------------------------------------------------------------------
// agg2z: out[n] = sum_e w_e * z[src] / sum_e w_e + cst.  8 B/edge gather.
// ---------------------------------------------------------------------------
__global__ __launch_bounds__(256) void agg2z_kernel(
    const int* __restrict__ rowptr, const int* __restrict__ srcS,
    const float2* __restrict__ az, const float* __restrict__ ad2,
    const float* __restrict__ cst, float* __restrict__ out)
{
    int gid  = blockIdx.x * blockDim.x + threadIdx.x;
    int n    = gid >> 3;                       // 8 lanes per node
    int sl   = threadIdx.x & 7;
    if (n >= N_NODES) return;
    const float adh = ad2[n];
    const int e0 = rowptr[n], e1 = rowptr[n + 1];

    float acc = 0.f, den = 0.f;
    for (int e = e0 + sl; e < e1; e += 8) {
        int s = srcS[e];
        float2 v = az[s];
        float a = v.x + adh;
        a = a > 0.f ? a : NEG_SLOPE * a;
        float w = __expf(a);
        acc = fmaf(w, v.y, acc);
        den += w;
    }
    #pragma unroll
    for (int off = 4; off; off >>= 1) {
        acc += __shfl_down(acc, off, 8);
        den += __shfl_down(den, off, 8);
    }
    if (sl == 0) out[n] = acc / (den + 1e-16f) + cst[0];
}

extern "C" void kernel_launch(void* const* d_in, const int* in_sizes, int n_in,
                              void* d_out, int out_size, void* d_ws, size_t ws_size,
                              hipStream_t stream)
{
    const float* x      = (const float*)d_in[0];
    const int*   ei     = (const int*)d_in[1];
    const float* W1     = (const float*)d_in[2];
    const float* a_src1 = (const float*)d_in[3];
    const float* a_dst1 = (const float*)d_in[4];
    const float* b1     = (const float*)d_in[5];
    const float* W2     = (const float*)d_in[6];
    const float* a_src2 = (const float*)d_in[7];
    const float* a_dst2 = (const float*)d_in[8];
    const float* b2     = (const float*)d_in[9];
    const float* fc_w   = (const float*)d_in[10];
    const float* fc_b   = (const float*)d_in[11];
    float* out = (float*)d_out;

    const int* srcA = ei;
    const int* dstA = ei + N_EDGES;

    // workspace layout (pads after rowptr/srcSorted as OOB insurance)
    float* ws = (float*)d_ws;
    size_t off = 0;
    unsigned int* xaggb = (unsigned int*)(ws + off); off += (size_t)N_NODES * 256;  // 51.2 MB
    unsigned int* xb    = (unsigned int*)(ws + off); off += (size_t)N_NODES * 64;   // 12.8 MB
    float* as1     = ws + off; off += (size_t)N_NODES * HEADS;
    float* ad1     = ws + off; off += (size_t)N_NODES * HEADS;
    float2* az     = (float2*)(ws + off); off += (size_t)N_NODES * 2;
    float* ad2     = ws + off; off += N_NODES;
    float* p_src   = ws + off; off += IN_DIM * HEADS;
    float* p_dst   = ws + off; off += IN_DIM * HEADS;
    float* v_s     = ws + off; off += C1;
    float* v_d     = ws + off; off += C1;
    float* v_z     = ws + off; off += C1;
    float* cst     = ws + off; off += 2;
    int* rowptr    = (int*)(ws + off); off += N_NODES + 1 + 256;     // +pad
    int* srcSorted = (int*)(ws + off); off += E_TOT + 256;           // +pad
    int* bsum      = (int*)(ws + off); off += 256;
    int* boff      = (int*)(ws + off); off += 256;
    int* zstart    = (int*)(ws + off);
    int* deg       = (int*)(ws + off); off += N_NODES;
    int* cursor    = (int*)(ws + off); off += N_NODES;
    hipMemsetAsync(zstart, 0, 2 * N_NODES * sizeof(int), stream);

    // projection collapses: p_src/p_dst (layer 1), v_s/v_d/v_z + cst (layer 2)
    prep_kernel<<<1, 512, 0, stream>>>(W1, a_src1, a_dst1, W2, a_src2, a_dst2,
                                       b2, fc_w, fc_b, p_src, p_dst, v_s, v_d, v_z, cst);

    // fused: per-node proj + x->bf16 convert, plus CSR degree count
    convproj_count_kernel<<<PROJ_BLOCKS + COUNT_BLOCKS, 256, 0, stream>>>(
        x, p_src, p_dst, dstA, as1, ad1, xb, deg);

    // CSR: parallel scan (blocksum -> scanbsum -> expand) + fill
    blocksum_kernel<<<NB_SCAN, 256, 0, stream>>>(deg, bsum);
    scanbsum_kernel<<<1, 256, 0, stream>>>(bsum, boff);
    expand_kernel<<<NB_SCAN, 256, 0, stream>>>(deg, boff, rowptr);
    fill_kernel<<<COUNT_BLOCKS, 256, 0, stream>>>(srcA, dstA, rowptr, cursor, srcSorted);

    // layer-1 aggregation in bf16 x-space
    agg1x_kernel<<<(N_NODES * 64 + 255) / 256, 256, 0, stream>>>(rowptr, srcSorted, xb, as1, ad1, xaggb);

    // fused MLP (phase C collapsed; epilogue in registers)
    mlp6_kernel<<<N_NODES / 16, 256, 0, stream>>>(xaggb, W1, b1, v_s, v_d, v_z, az, ad2);

    // layer 2 + final: scalar gather
    agg2z_kernel<<<(N_NODES * 8 + 255) / 256, 256, 0, stream>>>(rowptr, srcSorted, az, ad2, cst, out);
}

// Round 13
// 344.542 us; speedup vs baseline: 1.7757x; 1.0342x over previous
//
#include <hip/hip_runtime.h>

#define N_NODES 50000
#define N_EDGES 800000
#define E_TOT   850000           // edges + self loops
#define IN_DIM  128
#define HID     64
#define HEADS   4
#define C1      256              // HEADS*HID
#define OUT_DIM 64
#define NEG_SLOPE 0.2f

#define XS_STRIDE   516          // 512+4 floats

#define PROJ_BLOCKS (N_NODES / 4)                  // 12500
#define COUNT_BLOCKS ((E_TOT + 255) / 256)         // 3321
#define NB_SCAN ((N_NODES + 255) / 256)            // 196

// ---- bf16 helpers (manual: bf16 = top 16 bits of fp32, RNE) ----------------
__device__ __forceinline__ unsigned int bf16_rne(float f) {
    unsigned int u = __float_as_uint(f);
    return (u + 0x7FFFu + ((u >> 16) & 1u)) >> 16;
}
__device__ __forceinline__ unsigned int bf16_pack2(float a, float b) {
    return bf16_rne(a) | (bf16_rne(b) << 16);
}
__device__ __forceinline__ float bf16_lo(unsigned int u) { return __uint_as_float(u << 16); }
__device__ __forceinline__ float bf16_hi(unsigned int u) { return __uint_as_float(u & 0xFFFF0000u); }

// ---------------------------------------------------------------------------
// prep: p_src/p_dst collapse the layer-1 logit projection; v_s/v_d/v_z
// collapse ALL consumers of h2 (as2, ad2, fc dot); cst = b2.fc_w + fc_b.
// ---------------------------------------------------------------------------
__global__ __launch_bounds__(512) void prep_kernel(
    const float* __restrict__ W1, const float* __restrict__ a_src1,
    const float* __restrict__ a_dst1,
    const float* __restrict__ W2, const float* __restrict__ a_src2,
    const float* __restrict__ a_dst2, const float* __restrict__ b2,
    const float* __restrict__ fc_w, const float* __restrict__ fc_b,
    float* __restrict__ p_src, float* __restrict__ p_dst,
    float* __restrict__ v_s, float* __restrict__ v_d, float* __restrict__ v_z,
    float* __restrict__ cst)
{
    const int t = threadIdx.x;                 // 512 = 128 k * 4 h
    const int k = t >> 2, h = t & 3;
    const float* wrow = W1 + k * C1 + h * HID;
    const float* as = a_src1 + h * HID;
    const float* ad = a_dst1 + h * HID;
    float s = 0.f, d = 0.f;
    for (int c = 0; c < HID; c++) {
        float w = wrow[c];
        s = fmaf(w, as[c], s);
        d = fmaf(w, ad[c], d);
    }
    p_src[k * HEADS + h] = s;
    p_dst[k * HEADS + h] = d;

    if (t < C1) {                              // layer-2 collapse vectors
        const float* w2row = W2 + t * OUT_DIM;
        float vs = 0.f, vd = 0.f, vz = 0.f;
        for (int c = 0; c < OUT_DIM; c++) {
            float w = w2row[c];
            vs = fmaf(w, a_src2[c], vs);
            vd = fmaf(w, a_dst2[c], vd);
            vz = fmaf(w, fc_w[c], vz);
        }
        v_s[t] = vs; v_d[t] = vd; v_z[t] = vz;
    }
    if (t == 0) {
        float s2 = 0.f;
        for (int c = 0; c < OUT_DIM; c++) s2 = fmaf(b2[c], fc_w[c], s2);
        cst[0] = s2 + fc_b[0];
    }
}

// ---------------------------------------------------------------------------
// convproj_count: fused launch.
//  Blocks [0, PROJ_BLOCKS): per-node logit projections as1/ad1 AND x -> bf16.
//  Blocks [PROJ_BLOCKS, +COUNT_BLOCKS): per-edge degree count (CSR step 1).
// ---------------------------------------------------------------------------
__global__ __launch_bounds__(256) void convproj_count_kernel(
    const float* __restrict__ x, const float* __restrict__ p_src,
    const float* __restrict__ p_dst, const int* __restrict__ dst_a,
    float* __restrict__ as1, float* __restrict__ ad1,
    unsigned int* __restrict__ xb, int* __restrict__ deg)
{
    if (blockIdx.x >= PROJ_BLOCKS) {           // ---- count part ----
        int j = (blockIdx.x - PROJ_BLOCKS) * 256 + threadIdx.x;
        if (j < E_TOT) {
            int d = (j < N_EDGES) ? dst_a[j] : (j - N_EDGES);   // self loop
            atomicAdd(&deg[d], 1);
        }
        return;
    }
    // ---- proj + convert part ----
    __shared__ float ps[IN_DIM * HEADS];       // 2 KB
    __shared__ float pd[IN_DIM * HEADS];       // 2 KB
    const int t = threadIdx.x;
    for (int i = t; i < IN_DIM * HEADS; i += 256) { ps[i] = p_src[i]; pd[i] = p_dst[i]; }
    __syncthreads();
    const int node = blockIdx.x * 4 + (t >> 6);
    const int lane = t & 63;
    float2 xv = *(const float2*)(x + (size_t)node * IN_DIM + lane * 2);
    xb[(size_t)node * 64 + lane] = bf16_pack2(xv.x, xv.y);
    float4 p0 = *(const float4*)(ps + (lane * 2) * HEADS);
    float4 p1 = *(const float4*)(ps + (lane * 2 + 1) * HEADS);
    float4 q0 = *(const float4*)(pd + (lane * 2) * HEADS);
    float4 q1 = *(const float4*)(pd + (lane * 2 + 1) * HEADS);
    float s0 = xv.x * p0.x + xv.y * p1.x;
    float s1 = xv.x * p0.y + xv.y * p1.y;
    float s2 = xv.x * p0.z + xv.y * p1.z;
    float s3 = xv.x * p0.w + xv.y * p1.w;
    float d0 = xv.x * q0.x + xv.y * q1.x;
    float d1 = xv.x * q0.y + xv.y * q1.y;
    float d2 = xv.x * q0.z + xv.y * q1.z;
    float d3 = xv.x * q0.w + xv.y * q1.w;
    #pragma unroll
    for (int off = 32; off; off >>= 1) {
        s0 += __shfl_down(s0, off, 64); s1 += __shfl_down(s1, off, 64);
        s2 += __shfl_down(s2, off, 64); s3 += __shfl_down(s3, off, 64);
        d0 += __shfl_down(d0, off, 64); d1 += __shfl_down(d1, off, 64);
        d2 += __shfl_down(d2, off, 64); d3 += __shfl_down(d3, off, 64);
    }
    if (lane == 0) {
        float4 sv = {s0, s1, s2, s3};
        float4 dv = {d0, d1, d2, d3};
        *(float4*)(as1 + node * 4) = sv;
        *(float4*)(ad1 + node * 4) = dv;
    }
}

// ---------------------------------------------------------------------------
// Parallel CSR scan: blocksum -> scanbsum -> expand
// ---------------------------------------------------------------------------
__global__ __launch_bounds__(256) void blocksum_kernel(
    const int* __restrict__ deg, int* __restrict__ bsum)
{
    __shared__ int ps[256];
    const int t = threadIdx.x;
    int i = blockIdx.x * 256 + t;
    ps[t] = (i < N_NODES) ? deg[i] : 0;
    __syncthreads();
    for (int off = 128; off; off >>= 1) {
        if (t < off) ps[t] += ps[t + off];
        __syncthreads();
    }
    if (t == 0) bsum[blockIdx.x] = ps[0];
}

__global__ __launch_bounds__(256) void scanbsum_kernel(
    const int* __restrict__ bsum, int* __restrict__ boff)
{
    __shared__ int ps[256];
    const int t = threadIdx.x;
    ps[t] = (t < NB_SCAN) ? bsum[t] : 0;
    __syncthreads();
    for (int off = 1; off < 256; off <<= 1) {
        int u = (t >= off) ? ps[t - off] : 0;
        __syncthreads();
        ps[t] += u;
        __syncthreads();
    }
    boff[t] = (t > 0) ? ps[t - 1] : 0;         // exclusive
}

__global__ __launch_bounds__(256) void expand_kernel(
    const int* __restrict__ deg, const int* __restrict__ boff,
    int* __restrict__ rowptr)
{
    __shared__ int ps[256];
    const int t = threadIdx.x;
    int i = blockIdx.x * 256 + t;
    int v = (i < N_NODES) ? deg[i] : 0;
    ps[t] = v;
    __syncthreads();
    for (int off = 1; off < 256; off <<= 1) {
        int u = (t >= off) ? ps[t - off] : 0;
        __syncthreads();
        ps[t] += u;
        __syncthreads();
    }
    if (i <= N_NODES) rowptr[i] = boff[blockIdx.x] + ps[t] - v;   // exclusive
}

// ---------------------------------------------------------------------------
// fillw: CSR fill + PER-EDGE attention weights (computed ONCE per edge here,
// instead of 64x redundantly in agg1x). wS[slot] = exp(leakyrelu(as1[s]+ad1[d]))
// for the 4 heads, stored in sorted edge order.
// ---------------------------------------------------------------------------
__global__ void fillw_kernel(const int* __restrict__ src_a, const int* __restrict__ dst_a,
                             const int* __restrict__ rowptr, int* __restrict__ cursor,
                             const float* __restrict__ as1, const float* __restrict__ ad1,
                             int* __restrict__ srcSorted, float4* __restrict__ wS)
{
    int j = blockIdx.x * blockDim.x + threadIdx.x;
    if (j >= E_TOT) return;
    int s, d;
    if (j < N_EDGES) { s = src_a[j]; d = dst_a[j]; }
    else             { s = j - N_EDGES; d = s; }
    int pos = atomicAdd(&cursor[d], 1);
    int slot = rowptr[d] + pos;
    srcSorted[slot] = s;
    float4 A  = *(const float4*)(as1 + s * 4);
    float4 Dv = *(const float4*)(ad1 + d * 4);
    float a0 = A.x + Dv.x, a1 = A.y + Dv.y, a2 = A.z + Dv.z, a3 = A.w + Dv.w;
    a0 = a0 > 0.f ? a0 : NEG_SLOPE * a0;
    a1 = a1 > 0.f ? a1 : NEG_SLOPE * a1;
    a2 = a2 > 0.f ? a2 : NEG_SLOPE * a2;
    a3 = a3 > 0.f ? a3 : NEG_SLOPE * a3;
    float4 w = {__expf(a0), __expf(a1), __expf(a2), __expf(a3)};
    wS[slot] = w;
}

// ---------------------------------------------------------------------------
// agg1x: xaggb[n][h][k] (bf16) = softmax-weighted sum of xb[src] rows (bf16).
// One wave per dst node, lane = 2 k-channels; weights pre-computed (wS).
// ---------------------------------------------------------------------------
__global__ __launch_bounds__(256) void agg1x_kernel(
    const int* __restrict__ rowptr, const int* __restrict__ srcS,
    const float4* __restrict__ wS, const unsigned int* __restrict__ xb,
    unsigned int* __restrict__ xaggb)
{
    int gid  = blockIdx.x * blockDim.x + threadIdx.x;
    int n    = gid >> 6;
    int lane = threadIdx.x & 63;
    if (n >= N_NODES) return;
    const int e0 = rowptr[n], e1 = rowptr[n + 1];

    float2 acc0 = {0,0}, acc1 = {0,0}, acc2 = {0,0}, acc3 = {0,0};
    float den0 = 0, den1 = 0, den2 = 0, den3 = 0;
    int e = e0;
    for (; e + 2 <= e1; e += 2) {              // 2 gathers in flight
        int s0 = srcS[e], s1 = srcS[e + 1];
        float4 W0 = wS[e];
        float4 W1 = wS[e + 1];
        unsigned int xu0 = xb[(size_t)s0 * 64 + lane];
        unsigned int xu1 = xb[(size_t)s1 * 64 + lane];
        float xa = bf16_lo(xu0), xbv = bf16_hi(xu0);
        float ya = bf16_lo(xu1), ybv = bf16_hi(xu1);
        acc0.x = fmaf(W0.x, xa, acc0.x); acc0.y = fmaf(W0.x, xbv, acc0.y);
        acc1.x = fmaf(W0.y, xa, acc1.x); acc1.y = fmaf(W0.y, xbv, acc1.y);
        acc2.x = fmaf(W0.z, xa, acc2.x); acc2.y = fmaf(W0.z, xbv, acc2.y);
        acc3.x = fmaf(W0.w, xa, acc3.x); acc3.y = fmaf(W0.w, xbv, acc3.y);
        acc0.x = fmaf(W1.x, ya, acc0.x); acc0.y = fmaf(W1.x, ybv, acc0.y);
        acc1.x = fmaf(W1.y, ya, acc1.x); acc1.y = fmaf(W1.y, ybv, acc1.y);
        acc2.x = fmaf(W1.z, ya, acc2.x); acc2.y = fmaf(W1.z, ybv, acc2.y);
        acc3.x = fmaf(W1.w, ya, acc3.x); acc3.y = fmaf(W1.w, ybv, acc3.y);
        den0 += W0.x + W1.x; den1 += W0.y + W1.y;
        den2 += W0.z + W1.z; den3 += W0.w + W1.w;
    }
    for (; e < e1; e++) {
        int s = srcS[e];
        float4 W0 = wS[e];
        unsigned int xu = xb[(size_t)s * 64 + lane];
        float xa = bf16_lo(xu), xbv = bf16_hi(xu);
        acc0.x = fmaf(W0.x, xa, acc0.x); acc0.y = fmaf(W0.x, xbv, acc0.y);
        acc1.x = fmaf(W0.y, xa, acc1.x); acc1.y = fmaf(W0.y, xbv, acc1.y);
        acc2.x = fmaf(W0.z, xa, acc2.x); acc2.y = fmaf(W0.z, xbv, acc2.y);
        acc3.x = fmaf(W0.w, xa, acc3.x); acc3.y = fmaf(W0.w, xbv, acc3.y);
        den0 += W0.x; den1 += W0.y; den2 += W0.z; den3 += W0.w;
    }
    float i0 = 1.f / (den0 + 1e-16f), i1 = 1.f / (den1 + 1e-16f);
    float i2 = 1.f / (den2 + 1e-16f), i3 = 1.f / (den3 + 1e-16f);
    unsigned int* o = xaggb + (size_t)n * 256 + lane;      // row = 256 uints
    o[0 * 64] = bf16_pack2(acc0.x * i0, acc0.y * i0);
    o[1 * 64] = bf16_pack2(acc1.x * i1, acc1.y * i1);
    o[2 * 64] = bf16_pack2(acc2.x * i2, acc2.y * i2);
    o[3 * 64] = bf16_pack2(acc3.x * i3, acc3.y * i3);
}

// ---------------------------------------------------------------------------
// mlp6: 16 nodes/block, min 4 waves/EU (33.8 KB LDS -> 4 blocks/CU).
//  Phase A: stage bf16 xagg tile -> fp32 LDS.
//  Phase B: proven 4col x 4node mapping; wave = head (W1 once/block),
//           software prefetch one k-iter ahead.
//  Epilogue in registers: ELU then v_s/v_d/v_z dots, shuffle + LDS reduce.
// ---------------------------------------------------------------------------
__global__ __launch_bounds__(256, 4) void mlp6_kernel(
    const unsigned int* __restrict__ xaggb,
    const float* __restrict__ W1, const float* __restrict__ b1,
    const float* __restrict__ v_s, const float* __restrict__ v_d,
    const float* __restrict__ v_z,
    float2* __restrict__ az, float* __restrict__ ad2)
{
    __shared__ float xs[16 * XS_STRIDE];       // 33,024 B
    __shared__ float pr[4 * 16 * 3];           // 768 B cross-wave partials
    const int t = threadIdx.x;
    const int nodeBase = blockIdx.x * 16;
    const int wv = t >> 6;

    {   // ---- Phase A: stage 16x512ch (bf16) -> fp32 LDS ----
        const unsigned int* gsrc = xaggb + (size_t)nodeBase * 256;
        #pragma unroll
        for (int i = 0; i < 4; i++) {
            int iu = i * 1024 + t * 4;         // uint index in 4096-uint tile
            uint4 v = *(const uint4*)(gsrc + iu);
            int n = iu >> 8, c = (iu & 255) * 2;
            float4 f0 = {bf16_lo(v.x), bf16_hi(v.x), bf16_lo(v.y), bf16_hi(v.y)};
            float4 f1 = {bf16_lo(v.z), bf16_hi(v.z), bf16_lo(v.w), bf16_hi(v.w)};
            *(float4*)(xs + n * XS_STRIDE + c)     = f0;
            *(float4*)(xs + n * XS_STRIDE + c + 4) = f1;
        }
    }
    __syncthreads();

    {   // ---- Phase B + register epilogue ----
        const int q  = t & 15;                 // col-quad within head
        const int g  = (t >> 4) & 3;           // node group (4 nodes)
        const int h  = wv;                     // head = wave
        const int c0 = h * HID + q * 4;
        const float* Wp = W1 + c0;
        float4 w0 = *(const float4*)(Wp + (size_t)0 * C1);
        float4 w1 = *(const float4*)(Wp + (size_t)1 * C1);
        float4 w2 = *(const float4*)(Wp + (size_t)2 * C1);
        float4 w3 = *(const float4*)(Wp + (size_t)3 * C1);
        float acc[4][4];
        #pragma unroll
        for (int i = 0; i < 4; i++)
            #pragma unroll
            for (int m = 0; m < 4; m++) acc[i][m] = 0.f;
        const float* xbase = xs + (g * 4) * XS_STRIDE + h * IN_DIM;
        for (int k = 0; k < IN_DIM; k += 4) {
            const int kn = (k + 4 < IN_DIM) ? k + 4 : k;   // clamped prefetch
            float4 nw0 = *(const float4*)(Wp + (size_t)(kn + 0) * C1);
            float4 nw1 = *(const float4*)(Wp + (size_t)(kn + 1) * C1);
            float4 nw2 = *(const float4*)(Wp + (size_t)(kn + 2) * C1);
            float4 nw3 = *(const float4*)(Wp + (size_t)(kn + 3) * C1);
            #pragma unroll
            for (int i = 0; i < 4; i++) {
                float4 xv = *(const float4*)(xbase + i * XS_STRIDE + k);
                acc[i][0] = fmaf(xv.x, w0.x, acc[i][0]); acc[i][0] = fmaf(xv.y, w1.x, acc[i][0]);
                acc[i][0] = fmaf(xv.z, w2.x, acc[i][0]); acc[i][0] = fmaf(xv.w, w3.x, acc[i][0]);
                acc[i][1] = fmaf(xv.x, w0.y, acc[i][1]); acc[i][1] = fmaf(xv.y, w1.y, acc[i][1]);
                acc[i][1] = fmaf(xv.z, w2.y, acc[i][1]); acc[i][1] = fmaf(xv.w, w3.y, acc[i][1]);
                acc[i][2] = fmaf(xv.x, w0.z, acc[i][2]); acc[i][2] = fmaf(xv.y, w1.z, acc[i][2]);
                acc[i][2] = fmaf(xv.z, w2.z, acc[i][2]); acc[i][2] = fmaf(xv.w, w3.z, acc[i][2]);
                acc[i][3] = fmaf(xv.x, w0.w, acc[i][3]); acc[i][3] = fmaf(xv.y, w1.w, acc[i][3]);
                acc[i][3] = fmaf(xv.z, w2.w, acc[i][3]); acc[i][3] = fmaf(xv.w, w3.w, acc[i][3]);
            }
            w0 = nw0; w1 = nw1; w2 = nw2; w3 = nw3;
        }
        float4 bb  = *(const float4*)(b1 + c0);
        float4 vs4 = *(const float4*)(v_s + c0);
        float4 vd4 = *(const float4*)(v_d + c0);
        float4 vz4 = *(const float4*)(v_z + c0);
        float S[4], D[4], Z[4];
        #pragma unroll
        for (int i = 0; i < 4; i++) {
            float o0 = acc[i][0] + bb.x, o1 = acc[i][1] + bb.y;
            float o2 = acc[i][2] + bb.z, o3 = acc[i][3] + bb.w;
            o0 = o0 > 0.f ? o0 : __expf(o0) - 1.f;     // ELU in registers
            o1 = o1 > 0.f ? o1 : __expf(o1) - 1.f;
            o2 = o2 > 0.f ? o2 : __expf(o2) - 1.f;
            o3 = o3 > 0.f ? o3 : __expf(o3) - 1.f;
            S[i] = o0 * vs4.x + o1 * vs4.y + o2 * vs4.z + o3 * vs4.w;
            D[i] = o0 * vd4.x + o1 * vd4.y + o2 * vd4.z + o3 * vd4.w;
            Z[i] = o0 * vz4.x + o1 * vz4.y + o2 * vz4.z + o3 * vz4.w;
        }
        #pragma unroll
        for (int off = 8; off; off >>= 1) {
            #pragma unroll
            for (int i = 0; i < 4; i++) {
                S[i] += __shfl_down(S[i], off, 16);
                D[i] += __shfl_down(D[i], off, 16);
                Z[i] += __shfl_down(Z[i], off, 16);
            }
        }
        if (q == 0) {
            #pragma unroll
            for (int i = 0; i < 4; i++) {
                const int ln = g * 4 + i;      // local node 0..15
                pr[(wv * 16 + ln) * 3 + 0] = S[i];
                pr[(wv * 16 + ln) * 3 + 1] = D[i];
                pr[(wv * 16 + ln) * 3 + 2] = Z[i];
            }
        }
    }
    __syncthreads();

    if (t < 16) {   // ---- cross-wave reduce + store ----
        float s = 0.f, d = 0.f, z = 0.f;
        #pragma unroll
        for (int w = 0; w < 4; w++) {
            s += pr[(w * 16 + t) * 3 + 0];
            d += pr[(w * 16 + t) * 3 + 1];
            z += pr[(w * 16 + t) * 3 + 2];
        }
        const int node = nodeBase + t;
        float2 azv = {s, z};
        az[node]  = azv;
        ad2[node] = d;
    }
}

// ---------------------------------------------------------------------------
// agg2z: out[n] = sum_e w_e * z[src] / sum_e w_e + cst.  8 B/edge gather.
// ---------------------------------------------------------------------------
__global__ __launch_bounds__(256) void agg2z_kernel(
    const int* __restrict__ rowptr, const int* __restrict__ srcS,
    const float2* __restrict__ az, const float* __restrict__ ad2,
    const float* __restrict__ cst, float* __restrict__ out)
{
    int gid  = blockIdx.x * blockDim.x + threadIdx.x;
    int n    = gid >> 3;                       // 8 lanes per node
    int sl   = threadIdx.x & 7;
    if (n >= N_NODES) return;
    const float adh = ad2[n];
    const int e0 = rowptr[n], e1 = rowptr[n + 1];

    float acc = 0.f, den = 0.f;
    for (int e = e0 + sl; e < e1; e += 8) {
        int s = srcS[e];
        float2 v = az[s];
        float a = v.x + adh;
        a = a > 0.f ? a : NEG_SLOPE * a;
        float w = __expf(a);
        acc = fmaf(w, v.y, acc);
        den += w;
    }
    #pragma unroll
    for (int off = 4; off; off >>= 1) {
        acc += __shfl_down(acc, off, 8);
        den += __shfl_down(den, off, 8);
    }
    if (sl == 0) out[n] = acc / (den + 1e-16f) + cst[0];
}

extern "C" void kernel_launch(void* const* d_in, const int* in_sizes, int n_in,
                              void* d_out, int out_size, void* d_ws, size_t ws_size,
                              hipStream_t stream)
{
    const float* x      = (const float*)d_in[0];
    const int*   ei     = (const int*)d_in[1];
    const float* W1     = (const float*)d_in[2];
    const float* a_src1 = (const float*)d_in[3];
    const float* a_dst1 = (const float*)d_in[4];
    const float* b1     = (const float*)d_in[5];
    const float* W2     = (const float*)d_in[6];
    const float* a_src2 = (const float*)d_in[7];
    const float* a_dst2 = (const float*)d_in[8];
    const float* b2     = (const float*)d_in[9];
    const float* fc_w   = (const float*)d_in[10];
    const float* fc_b   = (const float*)d_in[11];
    float* out = (float*)d_out;

    const int* srcA = ei;
    const int* dstA = ei + N_EDGES;

    // workspace layout (pads after rowptr/srcSorted as OOB insurance)
    float* ws = (float*)d_ws;
    size_t off = 0;
    unsigned int* xaggb = (unsigned int*)(ws + off); off += (size_t)N_NODES * 256;  // 51.2 MB
    unsigned int* xb    = (unsigned int*)(ws + off); off += (size_t)N_NODES * 64;   // 12.8 MB
    float4* wS     = (float4*)(ws + off); off += (size_t)E_TOT * 4 + 4;             // 13.6 MB
    float* as1     = ws + off; off += (size_t)N_NODES * HEADS;
    float* ad1     = ws + off; off += (size_t)N_NODES * HEADS;
    float2* az     = (float2*)(ws + off); off += (size_t)N_NODES * 2;
    float* ad2     = ws + off; off += N_NODES;
    float* p_src   = ws + off; off += IN_DIM * HEADS;
    float* p_dst   = ws + off; off += IN_DIM * HEADS;
    float* v_s     = ws + off; off += C1;
    float* v_d     = ws + off; off += C1;
    float* v_z     = ws + off; off += C1;
    float* cst     = ws + off; off += 2;
    int* rowptr    = (int*)(ws + off); off += N_NODES + 1 + 256;     // +pad
    int* srcSorted = (int*)(ws + off); off += E_TOT + 256;           // +pad
    int* bsum      = (int*)(ws + off); off += 256;
    int* boff      = (int*)(ws + off); off += 256;
    int* zstart    = (int*)(ws + off);
    int* deg       = (int*)(ws + off); off += N_NODES;
    int* cursor    = (int*)(ws + off); off += N_NODES;
    hipMemsetAsync(zstart, 0, 2 * N_NODES * sizeof(int), stream);

    // projection collapses: p_src/p_dst (layer 1), v_s/v_d/v_z + cst (layer 2)
    prep_kernel<<<1, 512, 0, stream>>>(W1, a_src1, a_dst1, W2, a_src2, a_dst2,
                                       b2, fc_w, fc_b, p_src, p_dst, v_s, v_d, v_z, cst);

    // fused: per-node proj + x->bf16 convert, plus CSR degree count
    convproj_count_kernel<<<PROJ_BLOCKS + COUNT_BLOCKS, 256, 0, stream>>>(
        x, p_src, p_dst, dstA, as1, ad1, xb, deg);

    // CSR: parallel scan + fill-with-weights (w computed once per edge)
    blocksum_kernel<<<NB_SCAN, 256, 0, stream>>>(deg, bsum);
    scanbsum_kernel<<<1, 256, 0, stream>>>(bsum, boff);
    expand_kernel<<<NB_SCAN, 256, 0, stream>>>(deg, boff, rowptr);
    fillw_kernel<<<COUNT_BLOCKS, 256, 0, stream>>>(srcA, dstA, rowptr, cursor,
                                                   as1, ad1, srcSorted, wS);

    // layer-1 aggregation in bf16 x-space (weights pre-computed)
    agg1x_kernel<<<(N_NODES * 64 + 255) / 256, 256, 0, stream>>>(rowptr, srcSorted, wS, xb, xaggb);

    // fused MLP (phase C collapsed; epilogue in registers)
    mlp6_kernel<<<N_NODES / 16, 256, 0, stream>>>(xaggb, W1, b1, v_s, v_d, v_z, az, ad2);

    // layer 2 + final: scalar gather
    agg2z_kernel<<<(N_NODES * 8 + 255) / 256, 256, 0, stream>>>(rowptr, srcSorted, az, ad2, cst, out);
}

// Round 14
// 305.073 us; speedup vs baseline: 2.0055x; 1.1294x over previous
//
#include <hip/hip_runtime.h>

#define N_NODES 50000
#define N_EDGES 800000
#define E_TOT   850000           // edges + self loops
#define IN_DIM  128
#define HID     64
#define HEADS   4
#define C1      256              // HEADS*HID
#define OUT_DIM 64
#define NEG_SLOPE 0.2f

#define PROJ_BLOCKS (N_NODES / 4)                  // 12500
#define COUNT_BLOCKS ((E_TOT + 255) / 256)         // 3321
#define NB_SCAN ((N_NODES + 255) / 256)            // 196

typedef __attribute__((ext_vector_type(8))) short v8s;   // 8 bf16 (4 VGPRs)
typedef __attribute__((ext_vector_type(4))) float v4f;   // MFMA accumulator

// ---- bf16 helpers (manual: bf16 = top 16 bits of fp32, RNE) ----------------
__device__ __forceinline__ unsigned int bf16_rne(float f) {
    unsigned int u = __float_as_uint(f);
    return (u + 0x7FFFu + ((u >> 16) & 1u)) >> 16;
}
__device__ __forceinline__ unsigned int bf16_pack2(float a, float b) {
    return bf16_rne(a) | (bf16_rne(b) << 16);
}
__device__ __forceinline__ float bf16_lo(unsigned int u) { return __uint_as_float(u << 16); }
__device__ __forceinline__ float bf16_hi(unsigned int u) { return __uint_as_float(u & 0xFFFF0000u); }

// ---------------------------------------------------------------------------
// prep: p_src/p_dst collapse the layer-1 logit projection; v_s/v_d/v_z
// collapse ALL consumers of h2; cst = b2.fc_w + fc_b. NEW: pack W1 -> bf16
// in MFMA B-fragment order: uint4 index ((h*4+nt)*4+kk)*64 + lane holds
// B[k = kk*32 + (lane>>4)*8 + j][n = h*64 + nt*16 + (lane&15)], j=0..7.
// ---------------------------------------------------------------------------
__global__ __launch_bounds__(512) void prep_kernel(
    const float* __restrict__ W1, const float* __restrict__ a_src1,
    const float* __restrict__ a_dst1,
    const float* __restrict__ W2, const float* __restrict__ a_src2,
    const float* __restrict__ a_dst2, const float* __restrict__ b2,
    const float* __restrict__ fc_w, const float* __restrict__ fc_b,
    float* __restrict__ p_src, float* __restrict__ p_dst,
    float* __restrict__ v_s, float* __restrict__ v_d, float* __restrict__ v_z,
    float* __restrict__ cst, unsigned int* __restrict__ W1b)
{
    const int t = threadIdx.x;                 // 512 = 128 k * 4 h
    const int k = t >> 2, h = t & 3;
    const float* wrow = W1 + k * C1 + h * HID;
    const float* as = a_src1 + h * HID;
    const float* ad = a_dst1 + h * HID;
    float s = 0.f, d = 0.f;
    for (int c = 0; c < HID; c++) {
        float w = wrow[c];
        s = fmaf(w, as[c], s);
        d = fmaf(w, ad[c], d);
    }
    p_src[k * HEADS + h] = s;
    p_dst[k * HEADS + h] = d;

    if (t < C1) {                              // layer-2 collapse vectors
        const float* w2row = W2 + t * OUT_DIM;
        float vs = 0.f, vd = 0.f, vz = 0.f;
        for (int c = 0; c < OUT_DIM; c++) {
            float w = w2row[c];
            vs = fmaf(w, a_src2[c], vs);
            vd = fmaf(w, a_dst2[c], vd);
            vz = fmaf(w, fc_w[c], vz);
        }
        v_s[t] = vs; v_d[t] = vd; v_z[t] = vz;
    }
    if (t == 0) {
        float s2 = 0.f;
        for (int c = 0; c < OUT_DIM; c++) s2 = fmaf(b2[c], fc_w[c], s2);
        cst[0] = s2 + fc_b[0];
    }

    // W1 -> bf16 B-fragment packing (16384 uints = 64 KB)
    for (int idx = t; idx < 16384; idx += 512) {
        int i    = idx & 3;
        int lane = (idx >> 2) & 63;
        int kk   = (idx >> 8) & 3;
        int nt   = (idx >> 10) & 3;
        int hh   = idx >> 12;
        int k0 = kk * 32 + (lane >> 4) * 8 + i * 2;
        int c  = hh * 64 + nt * 16 + (lane & 15);
        W1b[idx] = bf16_pack2(W1[(size_t)k0 * C1 + c], W1[(size_t)(k0 + 1) * C1 + c]);
    }
}

// ---------------------------------------------------------------------------
// convproj_count: fused launch.
//  Blocks [0, PROJ_BLOCKS): per-node logit projections as1/ad1 AND x -> bf16.
//  Blocks [PROJ_BLOCKS, +COUNT_BLOCKS): per-edge degree count (CSR step 1).
// ---------------------------------------------------------------------------
__global__ __launch_bounds__(256) void convproj_count_kernel(
    const float* __restrict__ x, const float* __restrict__ p_src,
    const float* __restrict__ p_dst, const int* __restrict__ dst_a,
    float* __restrict__ as1, float* __restrict__ ad1,
    unsigned int* __restrict__ xb, int* __restrict__ deg)
{
    if (blockIdx.x >= PROJ_BLOCKS) {           // ---- count part ----
        int j = (blockIdx.x - PROJ_BLOCKS) * 256 + threadIdx.x;
        if (j < E_TOT) {
            int d = (j < N_EDGES) ? dst_a[j] : (j - N_EDGES);   // self loop
            atomicAdd(&deg[d], 1);
        }
        return;
    }
    // ---- proj + convert part ----
    __shared__ float ps[IN_DIM * HEADS];       // 2 KB
    __shared__ float pd[IN_DIM * HEADS];       // 2 KB
    const int t = threadIdx.x;
    for (int i = t; i < IN_DIM * HEADS; i += 256) { ps[i] = p_src[i]; pd[i] = p_dst[i]; }
    __syncthreads();
    const int node = blockIdx.x * 4 + (t >> 6);
    const int lane = t & 63;
    float2 xv = *(const float2*)(x + (size_t)node * IN_DIM + lane * 2);
    xb[(size_t)node * 64 + lane] = bf16_pack2(xv.x, xv.y);
    float4 p0 = *(const float4*)(ps + (lane * 2) * HEADS);
    float4 p1 = *(const float4*)(ps + (lane * 2 + 1) * HEADS);
    float4 q0 = *(const float4*)(pd + (lane * 2) * HEADS);
    float4 q1 = *(const float4*)(pd + (lane * 2 + 1) * HEADS);
    float s0 = xv.x * p0.x + xv.y * p1.x;
    float s1 = xv.x * p0.y + xv.y * p1.y;
    float s2 = xv.x * p0.z + xv.y * p1.z;
    float s3 = xv.x * p0.w + xv.y * p1.w;
    float d0 = xv.x * q0.x + xv.y * q1.x;
    float d1 = xv.x * q0.y + xv.y * q1.y;
    float d2 = xv.x * q0.z + xv.y * q1.z;
    float d3 = xv.x * q0.w + xv.y * q1.w;
    #pragma unroll
    for (int off = 32; off; off >>= 1) {
        s0 += __shfl_down(s0, off, 64); s1 += __shfl_down(s1, off, 64);
        s2 += __shfl_down(s2, off, 64); s3 += __shfl_down(s3, off, 64);
        d0 += __shfl_down(d0, off, 64); d1 += __shfl_down(d1, off, 64);
        d2 += __shfl_down(d2, off, 64); d3 += __shfl_down(d3, off, 64);
    }
    if (lane == 0) {
        float4 sv = {s0, s1, s2, s3};
        float4 dv = {d0, d1, d2, d3};
        *(float4*)(as1 + node * 4) = sv;
        *(float4*)(ad1 + node * 4) = dv;
    }
}

// ---------------------------------------------------------------------------
// Parallel CSR scan: blocksum -> scanbsum -> expand
// ---------------------------------------------------------------------------
__global__ __launch_bounds__(256) void blocksum_kernel(
    const int* __restrict__ deg, int* __restrict__ bsum)
{
    __shared__ int ps[256];
    const int t = threadIdx.x;
    int i = blockIdx.x * 256 + t;
    ps[t] = (i < N_NODES) ? deg[i] : 0;
    __syncthreads();
    for (int off = 128; off; off >>= 1) {
        if (t < off) ps[t] += ps[t + off];
        __syncthreads();
    }
    if (t == 0) bsum[blockIdx.x] = ps[0];
}

__global__ __launch_bounds__(256) void scanbsum_kernel(
    const int* __restrict__ bsum, int* __restrict__ boff)
{
    __shared__ int ps[256];
    const int t = threadIdx.x;
    ps[t] = (t < NB_SCAN) ? bsum[t] : 0;
    __syncthreads();
    for (int off = 1; off < 256; off <<= 1) {
        int u = (t >= off) ? ps[t - off] : 0;
        __syncthreads();
        ps[t] += u;
        __syncthreads();
    }
    boff[t] = (t > 0) ? ps[t - 1] : 0;         // exclusive
}

__global__ __launch_bounds__(256) void expand_kernel(
    const int* __restrict__ deg, const int* __restrict__ boff,
    int* __restrict__ rowptr)
{
    __shared__ int ps[256];
    const int t = threadIdx.x;
    int i = blockIdx.x * 256 + t;
    int v = (i < N_NODES) ? deg[i] : 0;
    ps[t] = v;
    __syncthreads();
    for (int off = 1; off < 256; off <<= 1) {
        int u = (t >= off) ? ps[t - off] : 0;
        __syncthreads();
        ps[t] += u;
        __syncthreads();
    }
    if (i <= N_NODES) rowptr[i] = boff[blockIdx.x] + ps[t] - v;   // exclusive
}

// ---------------------------------------------------------------------------
// fillw: CSR fill + per-edge attention weights (computed once per edge).
// ---------------------------------------------------------------------------
__global__ void fillw_kernel(const int* __restrict__ src_a, const int* __restrict__ dst_a,
                             const int* __restrict__ rowptr, int* __restrict__ cursor,
                             const float* __restrict__ as1, const float* __restrict__ ad1,
                             int* __restrict__ srcSorted, float4* __restrict__ wS)
{
    int j = blockIdx.x * blockDim.x + threadIdx.x;
    if (j >= E_TOT) return;
    int s, d;
    if (j < N_EDGES) { s = src_a[j]; d = dst_a[j]; }
    else             { s = j - N_EDGES; d = s; }
    int pos = atomicAdd(&cursor[d], 1);
    int slot = rowptr[d] + pos;
    srcSorted[slot] = s;
    float4 A  = *(const float4*)(as1 + s * 4);
    float4 Dv = *(const float4*)(ad1 + d * 4);
    float a0 = A.x + Dv.x, a1 = A.y + Dv.y, a2 = A.z + Dv.z, a3 = A.w + Dv.w;
    a0 = a0 > 0.f ? a0 : NEG_SLOPE * a0;
    a1 = a1 > 0.f ? a1 : NEG_SLOPE * a1;
    a2 = a2 > 0.f ? a2 : NEG_SLOPE * a2;
    a3 = a3 > 0.f ? a3 : NEG_SLOPE * a3;
    float4 w = {__expf(a0), __expf(a1), __expf(a2), __expf(a3)};
    wS[slot] = w;
}

// ---------------------------------------------------------------------------
// agg1x: xaggb[n][h][k] (bf16) = softmax-weighted sum of xb[src] rows (bf16).
// One wave per dst node, lane = 2 k-channels; weights pre-computed (wS).
// ---------------------------------------------------------------------------
__global__ __launch_bounds__(256) void agg1x_kernel(
    const int* __restrict__ rowptr, const int* __restrict__ srcS,
    const float4* __restrict__ wS, const unsigned int* __restrict__ xb,
    unsigned int* __restrict__ xaggb)
{
    int gid  = blockIdx.x * blockDim.x + threadIdx.x;
    int n    = gid >> 6;
    int lane = threadIdx.x & 63;
    if (n >= N_NODES) return;
    const int e0 = rowptr[n], e1 = rowptr[n + 1];

    float2 acc0 = {0,0}, acc1 = {0,0}, acc2 = {0,0}, acc3 = {0,0};
    float den0 = 0, den1 = 0, den2 = 0, den3 = 0;
    int e = e0;
    for (; e + 2 <= e1; e += 2) {              // 2 gathers in flight
        int s0 = srcS[e], s1 = srcS[e + 1];
        float4 W0 = wS[e];
        float4 W1 = wS[e + 1];
        unsigned int xu0 = xb[(size_t)s0 * 64 + lane];
        unsigned int xu1 = xb[(size_t)s1 * 64 + lane];
        float xa = bf16_lo(xu0), xbv = bf16_hi(xu0);
        float ya = bf16_lo(xu1), ybv = bf16_hi(xu1);
        acc0.x = fmaf(W0.x, xa, acc0.x); acc0.y = fmaf(W0.x, xbv, acc0.y);
        acc1.x = fmaf(W0.y, xa, acc1.x); acc1.y = fmaf(W0.y, xbv, acc1.y);
        acc2.x = fmaf(W0.z, xa, acc2.x); acc2.y = fmaf(W0.z, xbv, acc2.y);
        acc3.x = fmaf(W0.w, xa, acc3.x); acc3.y = fmaf(W0.w, xbv, acc3.y);
        acc0.x = fmaf(W1.x, ya, acc0.x); acc0.y = fmaf(W1.x, ybv, acc0.y);
        acc1.x = fmaf(W1.y, ya, acc1.x); acc1.y = fmaf(W1.y, ybv, acc1.y);
        acc2.x = fmaf(W1.z, ya, acc2.x); acc2.y = fmaf(W1.z, ybv, acc2.y);
        acc3.x = fmaf(W1.w, ya, acc3.x); acc3.y = fmaf(W1.w, ybv, acc3.y);
        den0 += W0.x + W1.x; den1 += W0.y + W1.y;
        den2 += W0.z + W1.z; den3 += W0.w + W1.w;
    }
    for (; e < e1; e++) {
        int s = srcS[e];
        float4 W0 = wS[e];
        unsigned int xu = xb[(size_t)s * 64 + lane];
        float xa = bf16_lo(xu), xbv = bf16_hi(xu);
        acc0.x = fmaf(W0.x, xa, acc0.x); acc0.y = fmaf(W0.x, xbv, acc0.y);
        acc1.x = fmaf(W0.y, xa, acc1.x); acc1.y = fmaf(W0.y, xbv, acc1.y);
        acc2.x = fmaf(W0.z, xa, acc2.x); acc2.y = fmaf(W0.z, xbv, acc2.y);
        acc3.x = fmaf(W0.w, xa, acc3.x); acc3.y = fmaf(W0.w, xbv, acc3.y);
        den0 += W0.x; den1 += W0.y; den2 += W0.z; den3 += W0.w;
    }
    float i0 = 1.f / (den0 + 1e-16f), i1 = 1.f / (den1 + 1e-16f);
    float i2 = 1.f / (den2 + 1e-16f), i3 = 1.f / (den3 + 1e-16f);
    unsigned int* o = xaggb + (size_t)n * 256 + lane;      // row = 256 uints
    o[0 * 64] = bf16_pack2(acc0.x * i0, acc0.y * i0);
    o[1 * 64] = bf16_pack2(acc1.x * i1, acc1.y * i1);
    o[2 * 64] = bf16_pack2(acc2.x * i2, acc2.y * i2);
    o[3 * 64] = bf16_pack2(acc3.x * i3, acc3.y * i3);
}

// ---------------------------------------------------------------------------
// mlp7: MFMA phase B. 16 nodes/block, wave = head.
//  Phase A: stage bf16 xagg tile into LDS as-is (raw uint4 copy, no unpack).
//  Phase B: act = xagg @ W1 via 16x 16x16x32 bf16 MFMA per wave:
//           A-frags (4, one per K-chunk) shared across the 4 N-tiles ->
//           only 4 ds_read_b128/thread; B-frags from pre-packed W1b (64 KB,
//           L2-hot). fp32 accumulation in AGPR/VGPR.
//  Epilogue in registers on the C-layout (col=lane&15, row=quad*4+reg):
//           +b1, ELU, v_s/v_d/v_z dots, width-16 shuffle + LDS reduce.
// ---------------------------------------------------------------------------
__global__ __launch_bounds__(256, 4) void mlp7_kernel(
    const unsigned int* __restrict__ xaggb,
    const unsigned int* __restrict__ W1b, const float* __restrict__ b1,
    const float* __restrict__ v_s, const float* __restrict__ v_d,
    const float* __restrict__ v_z,
    float2* __restrict__ az, float* __restrict__ ad2)
{
    __shared__ unsigned int xsh[16 * 260];     // 16.6 KB bf16 tile (+pad)
    __shared__ float pr[4 * 16 * 3];           // 768 B cross-wave partials
    const int t = threadIdx.x;
    const int nodeBase = blockIdx.x * 16;
    const int h = t >> 6;                      // wave = head
    const int lane = t & 63;

    {   // ---- Phase A: stage 16x512ch bf16 tile (no conversion) ----
        const unsigned int* gsrc = xaggb + (size_t)nodeBase * 256;
        #pragma unroll
        for (int i = 0; i < 4; i++) {
            int iu = i * 1024 + t * 4;         // uint index in 4096-uint tile
            uint4 v = *(const uint4*)(gsrc + iu);
            int n = iu >> 8, c = iu & 255;
            *(uint4*)(xsh + n * 260 + c) = v;
        }
    }
    __syncthreads();

    {   // ---- Phase B: MFMA + register epilogue ----
        const int m = lane & 15, quad = lane >> 4;
        // A[m][k]: k = kk*32 + quad*8 + j  (8 bf16 = 4 uints, 16B aligned)
        const unsigned int* abase = xsh + m * 260 + h * 64 + quad * 4;
        v8s af0 = *(const v8s*)(abase + 0);
        v8s af1 = *(const v8s*)(abase + 16);
        v8s af2 = *(const v8s*)(abase + 32);
        v8s af3 = *(const v8s*)(abase + 48);

        float Sr[4] = {0,0,0,0}, Dr[4] = {0,0,0,0}, Zr[4] = {0,0,0,0};
        #pragma unroll
        for (int nt = 0; nt < 4; nt++) {
            const unsigned int* bbase = W1b + (size_t)(h * 16 + nt * 4) * 256 + lane * 4;
            v4f acc = {0.f, 0.f, 0.f, 0.f};
            acc = __builtin_amdgcn_mfma_f32_16x16x32_bf16(af0, *(const v8s*)(bbase + 0 * 256), acc, 0, 0, 0);
            acc = __builtin_amdgcn_mfma_f32_16x16x32_bf16(af1, *(const v8s*)(bbase + 1 * 256), acc, 0, 0, 0);
            acc = __builtin_amdgcn_mfma_f32_16x16x32_bf16(af2, *(const v8s*)(bbase + 2 * 256), acc, 0, 0, 0);
            acc = __builtin_amdgcn_mfma_f32_16x16x32_bf16(af3, *(const v8s*)(bbase + 3 * 256), acc, 0, 0, 0);
            const int c = h * 64 + nt * 16 + m;
            float bb = b1[c], vsc = v_s[c], vdc = v_d[c], vzc = v_z[c];
            #pragma unroll
            for (int r = 0; r < 4; r++) {
                float o = acc[r] + bb;
                o = o > 0.f ? o : __expf(o) - 1.f;     // ELU
                Sr[r] = fmaf(o, vsc, Sr[r]);
                Dr[r] = fmaf(o, vdc, Dr[r]);
                Zr[r] = fmaf(o, vzc, Zr[r]);
            }
        }
        #pragma unroll
        for (int off = 8; off; off >>= 1) {            // reduce over 16 cols
            #pragma unroll
            for (int r = 0; r < 4; r++) {
                Sr[r] += __shfl_down(Sr[r], off, 16);
                Dr[r] += __shfl_down(Dr[r], off, 16);
                Zr[r] += __shfl_down(Zr[r], off, 16);
            }
        }
        if (m == 0) {
            #pragma unroll
            for (int r = 0; r < 4; r++) {
                const int row = quad * 4 + r;          // local node 0..15
                pr[(h * 16 + row) * 3 + 0] = Sr[r];
                pr[(h * 16 + row) * 3 + 1] = Dr[r];
                pr[(h * 16 + row) * 3 + 2] = Zr[r];
            }
        }
    }
    __syncthreads();

    if (t < 16) {   // ---- cross-head reduce + store ----
        float s = 0.f, d = 0.f, z = 0.f;
        #pragma unroll
        for (int w = 0; w < 4; w++) {
            s += pr[(w * 16 + t) * 3 + 0];
            d += pr[(w * 16 + t) * 3 + 1];
            z += pr[(w * 16 + t) * 3 + 2];
        }
        const int node = nodeBase + t;
        float2 azv = {s, z};
        az[node]  = azv;
        ad2[node] = d;
    }
}

// ---------------------------------------------------------------------------
// agg2z: out[n] = sum_e w_e * z[src] / sum_e w_e + cst.  8 B/edge gather.
// ---------------------------------------------------------------------------
__global__ __launch_bounds__(256) void agg2z_kernel(
    const int* __restrict__ rowptr, const int* __restrict__ srcS,
    const float2* __restrict__ az, const float* __restrict__ ad2,
    const float* __restrict__ cst, float* __restrict__ out)
{
    int gid  = blockIdx.x * blockDim.x + threadIdx.x;
    int n    = gid >> 3;                       // 8 lanes per node
    int sl   = threadIdx.x & 7;
    if (n >= N_NODES) return;
    const float adh = ad2[n];
    const int e0 = rowptr[n], e1 = rowptr[n + 1];

    float acc = 0.f, den = 0.f;
    for (int e = e0 + sl; e < e1; e += 8) {
        int s = srcS[e];
        float2 v = az[s];
        float a = v.x + adh;
        a = a > 0.f ? a : NEG_SLOPE * a;
        float w = __expf(a);
        acc = fmaf(w, v.y, acc);
        den += w;
    }
    #pragma unroll
    for (int off = 4; off; off >>= 1) {
        acc += __shfl_down(acc, off, 8);
        den += __shfl_down(den, off, 8);
    }
    if (sl == 0) out[n] = acc / (den + 1e-16f) + cst[0];
}

extern "C" void kernel_launch(void* const* d_in, const int* in_sizes, int n_in,
                              void* d_out, int out_size, void* d_ws, size_t ws_size,
                              hipStream_t stream)
{
    const float* x      = (const float*)d_in[0];
    const int*   ei     = (const int*)d_in[1];
    const float* W1     = (const float*)d_in[2];
    const float* a_src1 = (const float*)d_in[3];
    const float* a_dst1 = (const float*)d_in[4];
    const float* b1     = (const float*)d_in[5];
    const float* W2     = (const float*)d_in[6];
    const float* a_src2 = (const float*)d_in[7];
    const float* a_dst2 = (const float*)d_in[8];
    const float* b2     = (const float*)d_in[9];
    const float* fc_w   = (const float*)d_in[10];
    const float* fc_b   = (const float*)d_in[11];
    float* out = (float*)d_out;

    const int* srcA = ei;
    const int* dstA = ei + N_EDGES;

    // workspace layout (pads after rowptr/srcSorted as OOB insurance)
    float* ws = (float*)d_ws;
    size_t off = 0;
    unsigned int* xaggb = (unsigned int*)(ws + off); off += (size_t)N_NODES * 256;  // 51.2 MB
    unsigned int* xb    = (unsigned int*)(ws + off); off += (size_t)N_NODES * 64;   // 12.8 MB
    float4* wS     = (float4*)(ws + off); off += (size_t)E_TOT * 4 + 4;             // 13.6 MB
    float* as1     = ws + off; off += (size_t)N_NODES * HEADS;
    float* ad1     = ws + off; off += (size_t)N_NODES * HEADS;
    float2* az     = (float2*)(ws + off); off += (size_t)N_NODES * 2;
    float* ad2     = ws + off; off += N_NODES;
    float* p_src   = ws + off; off += IN_DIM * HEADS;
    float* p_dst   = ws + off; off += IN_DIM * HEADS;
    float* v_s     = ws + off; off += C1;
    float* v_d     = ws + off; off += C1;
    float* v_z     = ws + off; off += C1;
    float* cst     = ws + off; off += 2;
    unsigned int* W1b = (unsigned int*)(ws + off); off += 16384;     // 64 KB packed bf16
    int* rowptr    = (int*)(ws + off); off += N_NODES + 1 + 256;     // +pad
    int* srcSorted = (int*)(ws + off); off += E_TOT + 256;           // +pad
    int* bsum      = (int*)(ws + off); off += 256;
    int* boff      = (int*)(ws + off); off += 256;
    int* zstart    = (int*)(ws + off);
    int* deg       = (int*)(ws + off); off += N_NODES;
    int* cursor    = (int*)(ws + off); off += N_NODES;
    hipMemsetAsync(zstart, 0, 2 * N_NODES * sizeof(int), stream);

    // projection collapses + W1 bf16 B-fragment packing
    prep_kernel<<<1, 512, 0, stream>>>(W1, a_src1, a_dst1, W2, a_src2, a_dst2,
                                       b2, fc_w, fc_b, p_src, p_dst, v_s, v_d, v_z, cst, W1b);

    // fused: per-node proj + x->bf16 convert, plus CSR degree count
    convproj_count_kernel<<<PROJ_BLOCKS + COUNT_BLOCKS, 256, 0, stream>>>(
        x, p_src, p_dst, dstA, as1, ad1, xb, deg);

    // CSR: parallel scan + fill-with-weights
    blocksum_kernel<<<NB_SCAN, 256, 0, stream>>>(deg, bsum);
    scanbsum_kernel<<<1, 256, 0, stream>>>(bsum, boff);
    expand_kernel<<<NB_SCAN, 256, 0, stream>>>(deg, boff, rowptr);
    fillw_kernel<<<COUNT_BLOCKS, 256, 0, stream>>>(srcA, dstA, rowptr, cursor,
                                                   as1, ad1, srcSorted, wS);

    // layer-1 aggregation in bf16 x-space (weights pre-computed)
    agg1x_kernel<<<(N_NODES * 64 + 255) / 256, 256, 0, stream>>>(rowptr, srcSorted, wS, xb, xaggb);

    // MFMA MLP (phase C collapsed; epilogue in registers)
    mlp7_kernel<<<N_NODES / 16, 256, 0, stream>>>(xaggb, W1b, b1, v_s, v_d, v_z, az, ad2);

    // layer 2 + final: scalar gather
    agg2z_kernel<<<(N_NODES * 8 + 255) / 256, 256, 0, stream>>>(rowptr, srcSorted, az, ad2, cst, out);
}

// Round 15
// 276.824 us; speedup vs baseline: 2.2101x; 1.1020x over previous
//
#include <hip/hip_runtime.h>

#define N_NODES 50000
#define N_EDGES 800000
#define E_TOT   850000           // edges + self loops
#define IN_DIM  128
#define HID     64
#define HEADS   4
#define C1      256              // HEADS*HID
#define OUT_DIM 64
#define NEG_SLOPE 0.2f

#define CP_NODES   32                              // nodes per proj block
#define CP_BLOCKS  ((N_NODES + CP_NODES - 1) / CP_NODES)   // 1563
#define COUNT_BLOCKS ((E_TOT + 255) / 256)         // 3321
#define NB_SCAN ((N_NODES + 255) / 256)            // 196

typedef __attribute__((ext_vector_type(8))) short v8s;   // 8 bf16 (4 VGPRs)
typedef __attribute__((ext_vector_type(4))) float v4f;   // MFMA accumulator

// ---- bf16 helpers (manual: bf16 = top 16 bits of fp32, RNE) ----------------
__device__ __forceinline__ unsigned int bf16_rne(float f) {
    unsigned int u = __float_as_uint(f);
    return (u + 0x7FFFu + ((u >> 16) & 1u)) >> 16;
}
__device__ __forceinline__ unsigned int bf16_pack2(float a, float b) {
    return bf16_rne(a) | (bf16_rne(b) << 16);
}
__device__ __forceinline__ float bf16_lo(unsigned int u) { return __uint_as_float(u << 16); }
__device__ __forceinline__ float bf16_hi(unsigned int u) { return __uint_as_float(u & 0xFFFF0000u); }

// ---------------------------------------------------------------------------
// prep: p_src/p_dst collapse the layer-1 logit projection; v_s/v_d/v_z
// collapse ALL consumers of h2; cst = b2.fc_w + fc_b; W1 -> bf16 B-fragments.
// ---------------------------------------------------------------------------
__global__ __launch_bounds__(512) void prep_kernel(
    const float* __restrict__ W1, const float* __restrict__ a_src1,
    const float* __restrict__ a_dst1,
    const float* __restrict__ W2, const float* __restrict__ a_src2,
    const float* __restrict__ a_dst2, const float* __restrict__ b2,
    const float* __restrict__ fc_w, const float* __restrict__ fc_b,
    float* __restrict__ p_src, float* __restrict__ p_dst,
    float* __restrict__ v_s, float* __restrict__ v_d, float* __restrict__ v_z,
    float* __restrict__ cst, unsigned int* __restrict__ W1b)
{
    const int t = threadIdx.x;                 // 512 = 128 k * 4 h
    const int k = t >> 2, h = t & 3;
    const float* wrow = W1 + k * C1 + h * HID;
    const float* as = a_src1 + h * HID;
    const float* ad = a_dst1 + h * HID;
    float s = 0.f, d = 0.f;
    for (int c = 0; c < HID; c++) {
        float w = wrow[c];
        s = fmaf(w, as[c], s);
        d = fmaf(w, ad[c], d);
    }
    p_src[k * HEADS + h] = s;
    p_dst[k * HEADS + h] = d;

    if (t < C1) {                              // layer-2 collapse vectors
        const float* w2row = W2 + t * OUT_DIM;
        float vs = 0.f, vd = 0.f, vz = 0.f;
        for (int c = 0; c < OUT_DIM; c++) {
            float w = w2row[c];
            vs = fmaf(w, a_src2[c], vs);
            vd = fmaf(w, a_dst2[c], vd);
            vz = fmaf(w, fc_w[c], vz);
        }
        v_s[t] = vs; v_d[t] = vd; v_z[t] = vz;
    }
    if (t == 0) {
        float s2 = 0.f;
        for (int c = 0; c < OUT_DIM; c++) s2 = fmaf(b2[c], fc_w[c], s2);
        cst[0] = s2 + fc_b[0];
    }

    // W1 -> bf16 B-fragment packing (16384 uints = 64 KB)
    for (int idx = t; idx < 16384; idx += 512) {
        int i    = idx & 3;
        int lane = (idx >> 2) & 63;
        int kk   = (idx >> 8) & 3;
        int nt   = (idx >> 10) & 3;
        int hh   = idx >> 12;
        int k0 = kk * 32 + (lane >> 4) * 8 + i * 2;
        int c  = hh * 64 + nt * 16 + (lane & 15);
        W1b[idx] = bf16_pack2(W1[(size_t)k0 * C1 + c], W1[(size_t)(k0 + 1) * C1 + c]);
    }
}

// ---------------------------------------------------------------------------
// convproj_count: fused launch.
//  Blocks [0, CP_BLOCKS): 32 nodes/block (staging amortized 8x per wave):
//    per-node logit projections as1/ad1 AND x -> bf16.
//  Blocks [CP_BLOCKS, +COUNT_BLOCKS): per-edge degree count (CSR step 1).
// ---------------------------------------------------------------------------
__global__ __launch_bounds__(256) void convproj_count_kernel(
    const float* __restrict__ x, const float* __restrict__ p_src,
    const float* __restrict__ p_dst, const int* __restrict__ dst_a,
    float* __restrict__ as1, float* __restrict__ ad1,
    unsigned int* __restrict__ xb, int* __restrict__ deg)
{
    if (blockIdx.x >= CP_BLOCKS) {             // ---- count part ----
        int j = (blockIdx.x - CP_BLOCKS) * 256 + threadIdx.x;
        if (j < E_TOT) {
            int d = (j < N_EDGES) ? dst_a[j] : (j - N_EDGES);   // self loop
            atomicAdd(&deg[d], 1);
        }
        return;
    }
    // ---- proj + convert part ----
    __shared__ float ps[IN_DIM * HEADS];       // 2 KB
    __shared__ float pd[IN_DIM * HEADS];       // 2 KB
    const int t = threadIdx.x;
    for (int i = t; i < IN_DIM * HEADS; i += 256) { ps[i] = p_src[i]; pd[i] = p_dst[i]; }
    __syncthreads();
    const int wv   = t >> 6;
    const int lane = t & 63;
    float4 p0 = *(const float4*)(ps + (lane * 2) * HEADS);
    float4 p1 = *(const float4*)(ps + (lane * 2 + 1) * HEADS);
    float4 q0 = *(const float4*)(pd + (lane * 2) * HEADS);
    float4 q1 = *(const float4*)(pd + (lane * 2 + 1) * HEADS);
    const int nodeBase = blockIdx.x * CP_NODES + wv * 8;   // wave: 8 contiguous nodes
    #pragma unroll
    for (int i = 0; i < 8; i++) {
        const int node = nodeBase + i;
        if (node >= N_NODES) break;
        float2 xv = *(const float2*)(x + (size_t)node * IN_DIM + lane * 2);
        xb[(size_t)node * 64 + lane] = bf16_pack2(xv.x, xv.y);
        float s0 = xv.x * p0.x + xv.y * p1.x;
        float s1 = xv.x * p0.y + xv.y * p1.y;
        float s2 = xv.x * p0.z + xv.y * p1.z;
        float s3 = xv.x * p0.w + xv.y * p1.w;
        float d0 = xv.x * q0.x + xv.y * q1.x;
        float d1 = xv.x * q0.y + xv.y * q1.y;
        float d2 = xv.x * q0.z + xv.y * q1.z;
        float d3 = xv.x * q0.w + xv.y * q1.w;
        #pragma unroll
        for (int off = 32; off; off >>= 1) {
            s0 += __shfl_down(s0, off, 64); s1 += __shfl_down(s1, off, 64);
            s2 += __shfl_down(s2, off, 64); s3 += __shfl_down(s3, off, 64);
            d0 += __shfl_down(d0, off, 64); d1 += __shfl_down(d1, off, 64);
            d2 += __shfl_down(d2, off, 64); d3 += __shfl_down(d3, off, 64);
        }
        if (lane == 0) {
            float4 sv = {s0, s1, s2, s3};
            float4 dv = {d0, d1, d2, d3};
            *(float4*)(as1 + node * 4) = sv;
            *(float4*)(ad1 + node * 4) = dv;
        }
    }
}

// ---------------------------------------------------------------------------
// Parallel CSR scan: blocksum -> scanbsum -> expand
// ---------------------------------------------------------------------------
__global__ __launch_bounds__(256) void blocksum_kernel(
    const int* __restrict__ deg, int* __restrict__ bsum)
{
    __shared__ int ps[256];
    const int t = threadIdx.x;
    int i = blockIdx.x * 256 + t;
    ps[t] = (i < N_NODES) ? deg[i] : 0;
    __syncthreads();
    for (int off = 128; off; off >>= 1) {
        if (t < off) ps[t] += ps[t + off];
        __syncthreads();
    }
    if (t == 0) bsum[blockIdx.x] = ps[0];
}

__global__ __launch_bounds__(256) void scanbsum_kernel(
    const int* __restrict__ bsum, int* __restrict__ boff)
{
    __shared__ int ps[256];
    const int t = threadIdx.x;
    ps[t] = (t < NB_SCAN) ? bsum[t] : 0;
    __syncthreads();
    for (int off = 1; off < 256; off <<= 1) {
        int u = (t >= off) ? ps[t - off] : 0;
        __syncthreads();
        ps[t] += u;
        __syncthreads();
    }
    boff[t] = (t > 0) ? ps[t - 1] : 0;         // exclusive
}

__global__ __launch_bounds__(256) void expand_kernel(
    const int* __restrict__ deg, const int* __restrict__ boff,
    int* __restrict__ rowptr)
{
    __shared__ int ps[256];
    const int t = threadIdx.x;
    int i = blockIdx.x * 256 + t;
    int v = (i < N_NODES) ? deg[i] : 0;
    ps[t] = v;
    __syncthreads();
    for (int off = 1; off < 256; off <<= 1) {
        int u = (t >= off) ? ps[t - off] : 0;
        __syncthreads();
        ps[t] += u;
        __syncthreads();
    }
    if (i <= N_NODES) rowptr[i] = boff[blockIdx.x] + ps[t] - v;   // exclusive
}

// ---------------------------------------------------------------------------
// fillw: CSR fill + per-edge attention weights (computed once per edge).
// ---------------------------------------------------------------------------
__global__ void fillw_kernel(const int* __restrict__ src_a, const int* __restrict__ dst_a,
                             const int* __restrict__ rowptr, int* __restrict__ cursor,
                             const float* __restrict__ as1, const float* __restrict__ ad1,
                             int* __restrict__ srcSorted, float4* __restrict__ wS)
{
    int j = blockIdx.x * blockDim.x + threadIdx.x;
    if (j >= E_TOT) return;
    int s, d;
    if (j < N_EDGES) { s = src_a[j]; d = dst_a[j]; }
    else             { s = j - N_EDGES; d = s; }
    int pos = atomicAdd(&cursor[d], 1);
    int slot = rowptr[d] + pos;
    srcSorted[slot] = s;
    float4 A  = *(const float4*)(as1 + s * 4);
    float4 Dv = *(const float4*)(ad1 + d * 4);
    float a0 = A.x + Dv.x, a1 = A.y + Dv.y, a2 = A.z + Dv.z, a3 = A.w + Dv.w;
    a0 = a0 > 0.f ? a0 : NEG_SLOPE * a0;
    a1 = a1 > 0.f ? a1 : NEG_SLOPE * a1;
    a2 = a2 > 0.f ? a2 : NEG_SLOPE * a2;
    a3 = a3 > 0.f ? a3 : NEG_SLOPE * a3;
    float4 w = {__expf(a0), __expf(a1), __expf(a2), __expf(a3)};
    wS[slot] = w;
}

// ---------------------------------------------------------------------------
// agg1x: xaggb[n][h][k] (bf16) = softmax-weighted sum of xb[src] rows (bf16).
// One wave per dst node, lane = 2 k-channels; weights pre-computed (wS);
// unroll x4 -> 4 row-gathers in flight.
// ---------------------------------------------------------------------------
__global__ __launch_bounds__(256) void agg1x_kernel(
    const int* __restrict__ rowptr, const int* __restrict__ srcS,
    const float4* __restrict__ wS, const unsigned int* __restrict__ xb,
    unsigned int* __restrict__ xaggb)
{
    int gid  = blockIdx.x * blockDim.x + threadIdx.x;
    int n    = gid >> 6;
    int lane = threadIdx.x & 63;
    if (n >= N_NODES) return;
    const int e0 = rowptr[n], e1 = rowptr[n + 1];

    float2 acc0 = {0,0}, acc1 = {0,0}, acc2 = {0,0}, acc3 = {0,0};
    float den0 = 0, den1 = 0, den2 = 0, den3 = 0;
    int e = e0;
    for (; e + 4 <= e1; e += 4) {              // 4 gathers in flight
        int s0 = srcS[e], s1 = srcS[e + 1], s2 = srcS[e + 2], s3 = srcS[e + 3];
        float4 W0 = wS[e],     W1 = wS[e + 1];
        float4 W2 = wS[e + 2], W3 = wS[e + 3];
        unsigned int xu0 = xb[(size_t)s0 * 64 + lane];
        unsigned int xu1 = xb[(size_t)s1 * 64 + lane];
        unsigned int xu2 = xb[(size_t)s2 * 64 + lane];
        unsigned int xu3 = xb[(size_t)s3 * 64 + lane];
        float a0 = bf16_lo(xu0), b0 = bf16_hi(xu0);
        float a1 = bf16_lo(xu1), b1 = bf16_hi(xu1);
        float a2 = bf16_lo(xu2), b2 = bf16_hi(xu2);
        float a3 = bf16_lo(xu3), b3 = bf16_hi(xu3);
        acc0.x = fmaf(W0.x, a0, acc0.x); acc0.y = fmaf(W0.x, b0, acc0.y);
        acc1.x = fmaf(W0.y, a0, acc1.x); acc1.y = fmaf(W0.y, b0, acc1.y);
        acc2.x = fmaf(W0.z, a0, acc2.x); acc2.y = fmaf(W0.z, b0, acc2.y);
        acc3.x = fmaf(W0.w, a0, acc3.x); acc3.y = fmaf(W0.w, b0, acc3.y);
        acc0.x = fmaf(W1.x, a1, acc0.x); acc0.y = fmaf(W1.x, b1, acc0.y);
        acc1.x = fmaf(W1.y, a1, acc1.x); acc1.y = fmaf(W1.y, b1, acc1.y);
        acc2.x = fmaf(W1.z, a1, acc2.x); acc2.y = fmaf(W1.z, b1, acc2.y);
        acc3.x = fmaf(W1.w, a1, acc3.x); acc3.y = fmaf(W1.w, b1, acc3.y);
        acc0.x = fmaf(W2.x, a2, acc0.x); acc0.y = fmaf(W2.x, b2, acc0.y);
        acc1.x = fmaf(W2.y, a2, acc1.x); acc1.y = fmaf(W2.y, b2, acc1.y);
        acc2.x = fmaf(W2.z, a2, acc2.x); acc2.y = fmaf(W2.z, b2, acc2.y);
        acc3.x = fmaf(W2.w, a2, acc3.x); acc3.y = fmaf(W2.w, b2, acc3.y);
        acc0.x = fmaf(W3.x, a3, acc0.x); acc0.y = fmaf(W3.x, b3, acc0.y);
        acc1.x = fmaf(W3.y, a3, acc1.x); acc1.y = fmaf(W3.y, b3, acc1.y);
        acc2.x = fmaf(W3.z, a3, acc2.x); acc2.y = fmaf(W3.z, b3, acc2.y);
        acc3.x = fmaf(W3.w, a3, acc3.x); acc3.y = fmaf(W3.w, b3, acc3.y);
        den0 += (W0.x + W1.x) + (W2.x + W3.x);
        den1 += (W0.y + W1.y) + (W2.y + W3.y);
        den2 += (W0.z + W1.z) + (W2.z + W3.z);
        den3 += (W0.w + W1.w) + (W2.w + W3.w);
    }
    for (; e < e1; e++) {
        int s = srcS[e];
        float4 W0 = wS[e];
        unsigned int xu = xb[(size_t)s * 64 + lane];
        float xa = bf16_lo(xu), xbv = bf16_hi(xu);
        acc0.x = fmaf(W0.x, xa, acc0.x); acc0.y = fmaf(W0.x, xbv, acc0.y);
        acc1.x = fmaf(W0.y, xa, acc1.x); acc1.y = fmaf(W0.y, xbv, acc1.y);
        acc2.x = fmaf(W0.z, xa, acc2.x); acc2.y = fmaf(W0.z, xbv, acc2.y);
        acc3.x = fmaf(W0.w, xa, acc3.x); acc3.y = fmaf(W0.w, xbv, acc3.y);
        den0 += W0.x; den1 += W0.y; den2 += W0.z; den3 += W0.w;
    }
    float i0 = 1.f / (den0 + 1e-16f), i1 = 1.f / (den1 + 1e-16f);
    float i2 = 1.f / (den2 + 1e-16f), i3 = 1.f / (den3 + 1e-16f);
    unsigned int* o = xaggb + (size_t)n * 256 + lane;      // row = 256 uints
    o[0 * 64] = bf16_pack2(acc0.x * i0, acc0.y * i0);
    o[1 * 64] = bf16_pack2(acc1.x * i1, acc1.y * i1);
    o[2 * 64] = bf16_pack2(acc2.x * i2, acc2.y * i2);
    o[3 * 64] = bf16_pack2(acc3.x * i3, acc3.y * i3);
}

// ---------------------------------------------------------------------------
// mlp7: MFMA phase B. 16 nodes/block, wave = head. (unchanged from r14)
// ---------------------------------------------------------------------------
__global__ __launch_bounds__(256, 4) void mlp7_kernel(
    const unsigned int* __restrict__ xaggb,
    const unsigned int* __restrict__ W1b, const float* __restrict__ b1,
    const float* __restrict__ v_s, const float* __restrict__ v_d,
    const float* __restrict__ v_z,
    float2* __restrict__ az, float* __restrict__ ad2)
{
    __shared__ unsigned int xsh[16 * 260];     // 16.6 KB bf16 tile (+pad)
    __shared__ float pr[4 * 16 * 3];           // 768 B cross-wave partials
    const int t = threadIdx.x;
    const int nodeBase = blockIdx.x * 16;
    const int h = t >> 6;                      // wave = head
    const int lane = t & 63;

    {   // ---- Phase A: stage 16x512ch bf16 tile (no conversion) ----
        const unsigned int* gsrc = xaggb + (size_t)nodeBase * 256;
        #pragma unroll
        for (int i = 0; i < 4; i++) {
            int iu = i * 1024 + t * 4;         // uint index in 4096-uint tile
            uint4 v = *(const uint4*)(gsrc + iu);
            int n = iu >> 8, c = iu & 255;
            *(uint4*)(xsh + n * 260 + c) = v;
        }
    }
    __syncthreads();

    {   // ---- Phase B: MFMA + register epilogue ----
        const int m = lane & 15, quad = lane >> 4;
        const unsigned int* abase = xsh + m * 260 + h * 64 + quad * 4;
        v8s af0 = *(const v8s*)(abase + 0);
        v8s af1 = *(const v8s*)(abase + 16);
        v8s af2 = *(const v8s*)(abase + 32);
        v8s af3 = *(const v8s*)(abase + 48);

        float Sr[4] = {0,0,0,0}, Dr[4] = {0,0,0,0}, Zr[4] = {0,0,0,0};
        #pragma unroll
        for (int nt = 0; nt < 4; nt++) {
            const unsigned int* bbase = W1b + (size_t)(h * 16 + nt * 4) * 256 + lane * 4;
            v4f acc = {0.f, 0.f, 0.f, 0.f};
            acc = __builtin_amdgcn_mfma_f32_16x16x32_bf16(af0, *(const v8s*)(bbase + 0 * 256), acc, 0, 0, 0);
            acc = __builtin_amdgcn_mfma_f32_16x16x32_bf16(af1, *(const v8s*)(bbase + 1 * 256), acc, 0, 0, 0);
            acc = __builtin_amdgcn_mfma_f32_16x16x32_bf16(af2, *(const v8s*)(bbase + 2 * 256), acc, 0, 0, 0);
            acc = __builtin_amdgcn_mfma_f32_16x16x32_bf16(af3, *(const v8s*)(bbase + 3 * 256), acc, 0, 0, 0);
            const int c = h * 64 + nt * 16 + m;
            float bb = b1[c], vsc = v_s[c], vdc = v_d[c], vzc = v_z[c];
            #pragma unroll
            for (int r = 0; r < 4; r++) {
                float o = acc[r] + bb;
                o = o > 0.f ? o : __expf(o) - 1.f;     // ELU
                Sr[r] = fmaf(o, vsc, Sr[r]);
                Dr[r] = fmaf(o, vdc, Dr[r]);
                Zr[r] = fmaf(o, vzc, Zr[r]);
            }
        }
        #pragma unroll
        for (int off = 8; off; off >>= 1) {            // reduce over 16 cols
            #pragma unroll
            for (int r = 0; r < 4; r++) {
                Sr[r] += __shfl_down(Sr[r], off, 16);
                Dr[r] += __shfl_down(Dr[r], off, 16);
                Zr[r] += __shfl_down(Zr[r], off, 16);
            }
        }
        if (m == 0) {
            #pragma unroll
            for (int r = 0; r < 4; r++) {
                const int row = quad * 4 + r;          // local node 0..15
                pr[(h * 16 + row) * 3 + 0] = Sr[r];
                pr[(h * 16 + row) * 3 + 1] = Dr[r];
                pr[(h * 16 + row) * 3 + 2] = Zr[r];
            }
        }
    }
    __syncthreads();

    if (t < 16) {   // ---- cross-head reduce + store ----
        float s = 0.f, d = 0.f, z = 0.f;
        #pragma unroll
        for (int w = 0; w < 4; w++) {
            s += pr[(w * 16 + t) * 3 + 0];
            d += pr[(w * 16 + t) * 3 + 1];
            z += pr[(w * 16 + t) * 3 + 2];
        }
        const int node = nodeBase + t;
        float2 azv = {s, z};
        az[node]  = azv;
        ad2[node] = d;
    }
}

// ---------------------------------------------------------------------------
// agg2z: out[n] = sum_e w_e * z[src] / sum_e w_e + cst.  8 B/edge gather.
// ---------------------------------------------------------------------------
__global__ __launch_bounds__(256) void agg2z_kernel(
    const int* __restrict__ rowptr, const int* __restrict__ srcS,
    const float2* __restrict__ az, const float* __restrict__ ad2,
    const float* __restrict__ cst, float* __restrict__ out)
{
    int gid  = blockIdx.x * blockDim.x + threadIdx.x;
    int n    = gid >> 3;                       // 8 lanes per node
    int sl   = threadIdx.x & 7;
    if (n >= N_NODES) return;
    const float adh = ad2[n];
    const int e0 = rowptr[n], e1 = rowptr[n + 1];

    float acc = 0.f, den = 0.f;
    for (int e = e0 + sl; e < e1; e += 8) {
        int s = srcS[e];
        float2 v = az[s];
        float a = v.x + adh;
        a = a > 0.f ? a : NEG_SLOPE * a;
        float w = __expf(a);
        acc = fmaf(w, v.y, acc);
        den += w;
    }
    #pragma unroll
    for (int off = 4; off; off >>= 1) {
        acc += __shfl_down(acc, off, 8);
        den += __shfl_down(den, off, 8);
    }
    if (sl == 0) out[n] = acc / (den + 1e-16f) + cst[0];
}

extern "C" void kernel_launch(void* const* d_in, const int* in_sizes, int n_in,
                              void* d_out, int out_size, void* d_ws, size_t ws_size,
                              hipStream_t stream)
{
    const float* x      = (const float*)d_in[0];
    const int*   ei     = (const int*)d_in[1];
    const float* W1     = (const float*)d_in[2];
    const float* a_src1 = (const float*)d_in[3];
    const float* a_dst1 = (const float*)d_in[4];
    const float* b1     = (const float*)d_in[5];
    const float* W2     = (const float*)d_in[6];
    const float* a_src2 = (const float*)d_in[7];
    const float* a_dst2 = (const float*)d_in[8];
    const float* b2     = (const float*)d_in[9];
    const float* fc_w   = (const float*)d_in[10];
    const float* fc_b   = (const float*)d_in[11];
    float* out = (float*)d_out;

    const int* srcA = ei;
    const int* dstA = ei + N_EDGES;

    // workspace layout (pads after rowptr/srcSorted as OOB insurance)
    float* ws = (float*)d_ws;
    size_t off = 0;
    unsigned int* xaggb = (unsigned int*)(ws + off); off += (size_t)N_NODES * 256;  // 51.2 MB
    unsigned int* xb    = (unsigned int*)(ws + off); off += (size_t)N_NODES * 64;   // 12.8 MB
    float4* wS     = (float4*)(ws + off); off += (size_t)E_TOT * 4 + 4;             // 13.6 MB
    float* as1     = ws + off; off += (size_t)N_NODES * HEADS;
    float* ad1     = ws + off; off += (size_t)N_NODES * HEADS;
    float2* az     = (float2*)(ws + off); off += (size_t)N_NODES * 2;
    float* ad2     = ws + off; off += N_NODES;
    float* p_src   = ws + off; off += IN_DIM * HEADS;
    float* p_dst   = ws + off; off += IN_DIM * HEADS;
    float* v_s     = ws + off; off += C1;
    float* v_d     = ws + off; off += C1;
    float* v_z     = ws + off; off += C1;
    float* cst     = ws + off; off += 2;
    unsigned int* W1b = (unsigned int*)(ws + off); off += 16384;     // 64 KB packed bf16
    int* rowptr    = (int*)(ws + off); off += N_NODES + 1 + 256;     // +pad
    int* srcSorted = (int*)(ws + off); off += E_TOT + 256;           // +pad
    int* bsum      = (int*)(ws + off); off += 256;
    int* boff      = (int*)(ws + off); off += 256;
    int* zstart    = (int*)(ws + off);
    int* deg       = (int*)(ws + off); off += N_NODES;
    int* cursor    = (int*)(ws + off); off += N_NODES;
    hipMemsetAsync(zstart, 0, 2 * N_NODES * sizeof(int), stream);

    // projection collapses + W1 bf16 B-fragment packing
    prep_kernel<<<1, 512, 0, stream>>>(W1, a_src1, a_dst1, W2, a_src2, a_dst2,
                                       b2, fc_w, fc_b, p_src, p_dst, v_s, v_d, v_z, cst, W1b);

    // fused: per-node proj + x->bf16 convert (32 nodes/block), CSR degree count
    convproj_count_kernel<<<CP_BLOCKS + COUNT_BLOCKS, 256, 0, stream>>>(
        x, p_src, p_dst, dstA, as1, ad1, xb, deg);

    // CSR: parallel scan + fill-with-weights
    blocksum_kernel<<<NB_SCAN, 256, 0, stream>>>(deg, bsum);
    scanbsum_kernel<<<1, 256, 0, stream>>>(bsum, boff);
    expand_kernel<<<NB_SCAN, 256, 0, stream>>>(deg, boff, rowptr);
    fillw_kernel<<<COUNT_BLOCKS, 256, 0, stream>>>(srcA, dstA, rowptr, cursor,
                                                   as1, ad1, srcSorted, wS);

    // layer-1 aggregation in bf16 x-space (weights pre-computed, x4 unroll)
    agg1x_kernel<<<(N_NODES * 64 + 255) / 256, 256, 0, stream>>>(rowptr, srcSorted, wS, xb, xaggb);

    // MFMA MLP (phase C collapsed; epilogue in registers)
    mlp7_kernel<<<N_NODES / 16, 256, 0, stream>>>(xaggb, W1b, b1, v_s, v_d, v_z, az, ad2);

    // layer 2 + final: scalar gather
    agg2z_kernel<<<(N_NODES * 8 + 255) / 256, 256, 0, stream>>>(rowptr, srcSorted, az, ad2, cst, out);
}

// Round 16
// 262.982 us; speedup vs baseline: 2.3264x; 1.0526x over previous
//
#include <hip/hip_runtime.h>

#define N_NODES 50000
#define N_EDGES 800000
#define E_TOT   850000           // edges + self loops
#define IN_DIM  128
#define HID     64
#define HEADS   4
#define C1      256              // HEADS*HID
#define OUT_DIM 64
#define NEG_SLOPE 0.2f

#define CP_NODES   32                              // nodes per proj block
#define CP_BLOCKS  ((N_NODES + CP_NODES - 1) / CP_NODES)   // 1563
#define COUNT_BLOCKS ((E_TOT + 255) / 256)         // 3321
#define NB_SCAN ((N_NODES + 255) / 256)            // 196

typedef __attribute__((ext_vector_type(8))) short v8s;   // 8 bf16 (4 VGPRs)
typedef __attribute__((ext_vector_type(4))) float v4f;   // MFMA accumulator

// ---- bf16 helpers (manual: bf16 = top 16 bits of fp32, RNE) ----------------
__device__ __forceinline__ unsigned int bf16_rne(float f) {
    unsigned int u = __float_as_uint(f);
    return (u + 0x7FFFu + ((u >> 16) & 1u)) >> 16;
}
__device__ __forceinline__ unsigned int bf16_pack2(float a, float b) {
    return bf16_rne(a) | (bf16_rne(b) << 16);
}
__device__ __forceinline__ float bf16_lo(unsigned int u) { return __uint_as_float(u << 16); }
__device__ __forceinline__ float bf16_hi(unsigned int u) { return __uint_as_float(u & 0xFFFF0000u); }

// ---------------------------------------------------------------------------
// prep: p_src/p_dst collapse the layer-1 logit projection; v_s/v_d/v_z
// collapse ALL consumers of h2; cst = b2.fc_w + fc_b; W1 -> bf16 B-fragments.
// ---------------------------------------------------------------------------
__global__ __launch_bounds__(512) void prep_kernel(
    const float* __restrict__ W1, const float* __restrict__ a_src1,
    const float* __restrict__ a_dst1,
    const float* __restrict__ W2, const float* __restrict__ a_src2,
    const float* __restrict__ a_dst2, const float* __restrict__ b2,
    const float* __restrict__ fc_w, const float* __restrict__ fc_b,
    float* __restrict__ p_src, float* __restrict__ p_dst,
    float* __restrict__ v_s, float* __restrict__ v_d, float* __restrict__ v_z,
    float* __restrict__ cst, unsigned int* __restrict__ W1b)
{
    const int t = threadIdx.x;                 // 512 = 128 k * 4 h
    const int k = t >> 2, h = t & 3;
    const float* wrow = W1 + k * C1 + h * HID;
    const float* as = a_src1 + h * HID;
    const float* ad = a_dst1 + h * HID;
    float s = 0.f, d = 0.f;
    for (int c = 0; c < HID; c++) {
        float w = wrow[c];
        s = fmaf(w, as[c], s);
        d = fmaf(w, ad[c], d);
    }
    p_src[k * HEADS + h] = s;
    p_dst[k * HEADS + h] = d;

    if (t < C1) {                              // layer-2 collapse vectors
        const float* w2row = W2 + t * OUT_DIM;
        float vs = 0.f, vd = 0.f, vz = 0.f;
        for (int c = 0; c < OUT_DIM; c++) {
            float w = w2row[c];
            vs = fmaf(w, a_src2[c], vs);
            vd = fmaf(w, a_dst2[c], vd);
            vz = fmaf(w, fc_w[c], vz);
        }
        v_s[t] = vs; v_d[t] = vd; v_z[t] = vz;
    }
    if (t == 0) {
        float s2 = 0.f;
        for (int c = 0; c < OUT_DIM; c++) s2 = fmaf(b2[c], fc_w[c], s2);
        cst[0] = s2 + fc_b[0];
    }

    // W1 -> bf16 B-fragment packing (16384 uints = 64 KB)
    for (int idx = t; idx < 16384; idx += 512) {
        int i    = idx & 3;
        int lane = (idx >> 2) & 63;
        int kk   = (idx >> 8) & 3;
        int nt   = (idx >> 10) & 3;
        int hh   = idx >> 12;
        int k0 = kk * 32 + (lane >> 4) * 8 + i * 2;
        int c  = hh * 64 + nt * 16 + (lane & 15);
        W1b[idx] = bf16_pack2(W1[(size_t)k0 * C1 + c], W1[(size_t)(k0 + 1) * C1 + c]);
    }
}

// ---------------------------------------------------------------------------
// convproj_count: fused launch.
//  Blocks [0, CP_BLOCKS): 32 nodes/block: projections as1/ad1 AND x -> bf16.
//  Blocks [CP_BLOCKS, +COUNT_BLOCKS): degree count; NEW: stores each edge's
//    claimed position posE[j] (coalesced) so fillw2 needs no atomic.
// ---------------------------------------------------------------------------
__global__ __launch_bounds__(256) void convproj_count_kernel(
    const float* __restrict__ x, const float* __restrict__ p_src,
    const float* __restrict__ p_dst, const int* __restrict__ dst_a,
    float* __restrict__ as1, float* __restrict__ ad1,
    unsigned int* __restrict__ xb, int* __restrict__ deg,
    int* __restrict__ posE)
{
    if (blockIdx.x >= CP_BLOCKS) {             // ---- count part ----
        int j = (blockIdx.x - CP_BLOCKS) * 256 + threadIdx.x;
        if (j < E_TOT) {
            int d = (j < N_EDGES) ? dst_a[j] : (j - N_EDGES);   // self loop
            posE[j] = atomicAdd(&deg[d], 1);
        }
        return;
    }
    // ---- proj + convert part ----
    __shared__ float ps[IN_DIM * HEADS];       // 2 KB
    __shared__ float pd[IN_DIM * HEADS];       // 2 KB
    const int t = threadIdx.x;
    for (int i = t; i < IN_DIM * HEADS; i += 256) { ps[i] = p_src[i]; pd[i] = p_dst[i]; }
    __syncthreads();
    const int wv   = t >> 6;
    const int lane = t & 63;
    float4 p0 = *(const float4*)(ps + (lane * 2) * HEADS);
    float4 p1 = *(const float4*)(ps + (lane * 2 + 1) * HEADS);
    float4 q0 = *(const float4*)(pd + (lane * 2) * HEADS);
    float4 q1 = *(const float4*)(pd + (lane * 2 + 1) * HEADS);
    const int nodeBase = blockIdx.x * CP_NODES + wv * 8;   // wave: 8 contiguous nodes
    #pragma unroll
    for (int i = 0; i < 8; i++) {
        const int node = nodeBase + i;
        if (node >= N_NODES) break;
        float2 xv = *(const float2*)(x + (size_t)node * IN_DIM + lane * 2);
        xb[(size_t)node * 64 + lane] = bf16_pack2(xv.x, xv.y);
        float s0 = xv.x * p0.x + xv.y * p1.x;
        float s1 = xv.x * p0.y + xv.y * p1.y;
        float s2 = xv.x * p0.z + xv.y * p1.z;
        float s3 = xv.x * p0.w + xv.y * p1.w;
        float d0 = xv.x * q0.x + xv.y * q1.x;
        float d1 = xv.x * q0.y + xv.y * q1.y;
        float d2 = xv.x * q0.z + xv.y * q1.z;
        float d3 = xv.x * q0.w + xv.y * q1.w;
        #pragma unroll
        for (int off = 32; off; off >>= 1) {
            s0 += __shfl_down(s0, off, 64); s1 += __shfl_down(s1, off, 64);
            s2 += __shfl_down(s2, off, 64); s3 += __shfl_down(s3, off, 64);
            d0 += __shfl_down(d0, off, 64); d1 += __shfl_down(d1, off, 64);
            d2 += __shfl_down(d2, off, 64); d3 += __shfl_down(d3, off, 64);
        }
        if (lane == 0) {
            float4 sv = {s0, s1, s2, s3};
            float4 dv = {d0, d1, d2, d3};
            *(float4*)(as1 + node * 4) = sv;
            *(float4*)(ad1 + node * 4) = dv;
        }
    }
}

// ---------------------------------------------------------------------------
// Parallel CSR scan: blocksum -> scanbsum -> expand
// ---------------------------------------------------------------------------
__global__ __launch_bounds__(256) void blocksum_kernel(
    const int* __restrict__ deg, int* __restrict__ bsum)
{
    __shared__ int ps[256];
    const int t = threadIdx.x;
    int i = blockIdx.x * 256 + t;
    ps[t] = (i < N_NODES) ? deg[i] : 0;
    __syncthreads();
    for (int off = 128; off; off >>= 1) {
        if (t < off) ps[t] += ps[t + off];
        __syncthreads();
    }
    if (t == 0) bsum[blockIdx.x] = ps[0];
}

__global__ __launch_bounds__(256) void scanbsum_kernel(
    const int* __restrict__ bsum, int* __restrict__ boff)
{
    __shared__ int ps[256];
    const int t = threadIdx.x;
    ps[t] = (t < NB_SCAN) ? bsum[t] : 0;
    __syncthreads();
    for (int off = 1; off < 256; off <<= 1) {
        int u = (t >= off) ? ps[t - off] : 0;
        __syncthreads();
        ps[t] += u;
        __syncthreads();
    }
    boff[t] = (t > 0) ? ps[t - 1] : 0;         // exclusive
}

__global__ __launch_bounds__(256) void expand_kernel(
    const int* __restrict__ deg, const int* __restrict__ boff,
    int* __restrict__ rowptr)
{
    __shared__ int ps[256];
    const int t = threadIdx.x;
    int i = blockIdx.x * 256 + t;
    int v = (i < N_NODES) ? deg[i] : 0;
    ps[t] = v;
    __syncthreads();
    for (int off = 1; off < 256; off <<= 1) {
        int u = (t >= off) ? ps[t - off] : 0;
        __syncthreads();
        ps[t] += u;
        __syncthreads();
    }
    if (i <= N_NODES) rowptr[i] = boff[blockIdx.x] + ps[t] - v;   // exclusive
}

// ---------------------------------------------------------------------------
// fillw2: atomic-free CSR fill. slot = rowptr[d] + posE[j] (claimed in count).
// Scatters only int2{src, j} (8 B); weights written COALESCED in edge order.
// ---------------------------------------------------------------------------
__global__ void fillw2_kernel(const int* __restrict__ src_a, const int* __restrict__ dst_a,
                              const int* __restrict__ rowptr, const int* __restrict__ posE,
                              const float* __restrict__ as1, const float* __restrict__ ad1,
                              int2* __restrict__ srcj, float4* __restrict__ wE)
{
    int j = blockIdx.x * blockDim.x + threadIdx.x;
    if (j >= E_TOT) return;
    int s, d;
    if (j < N_EDGES) { s = src_a[j]; d = dst_a[j]; }
    else             { s = j - N_EDGES; d = s; }
    int slot = rowptr[d] + posE[j];
    int2 sj = {s, j};
    srcj[slot] = sj;                           // 8 B scatter (only scatter left)
    float4 A  = *(const float4*)(as1 + s * 4);
    float4 Dv = *(const float4*)(ad1 + d * 4);
    float a0 = A.x + Dv.x, a1 = A.y + Dv.y, a2 = A.z + Dv.z, a3 = A.w + Dv.w;
    a0 = a0 > 0.f ? a0 : NEG_SLOPE * a0;
    a1 = a1 > 0.f ? a1 : NEG_SLOPE * a1;
    a2 = a2 > 0.f ? a2 : NEG_SLOPE * a2;
    a3 = a3 > 0.f ? a3 : NEG_SLOPE * a3;
    float4 w = {__expf(a0), __expf(a1), __expf(a2), __expf(a3)};
    wE[j] = w;                                 // coalesced
}

// ---------------------------------------------------------------------------
// agg1x: xaggb[n][h][k] (bf16) = softmax-weighted sum of xb[src] rows (bf16).
// One wave per dst node; srcj gives (src, edge-id); weights via wE[j]
// (wave-uniform L2-hot indirection); unroll x4.
// ---------------------------------------------------------------------------
__global__ __launch_bounds__(256) void agg1x_kernel(
    const int* __restrict__ rowptr, const int2* __restrict__ srcj,
    const float4* __restrict__ wE, const unsigned int* __restrict__ xb,
    unsigned int* __restrict__ xaggb)
{
    int gid  = blockIdx.x * blockDim.x + threadIdx.x;
    int n    = gid >> 6;
    int lane = threadIdx.x & 63;
    if (n >= N_NODES) return;
    const int e0 = rowptr[n], e1 = rowptr[n + 1];

    float2 acc0 = {0,0}, acc1 = {0,0}, acc2 = {0,0}, acc3 = {0,0};
    float den0 = 0, den1 = 0, den2 = 0, den3 = 0;
    int e = e0;
    for (; e + 4 <= e1; e += 4) {              // 4 gathers in flight
        int2 sj0 = srcj[e],     sj1 = srcj[e + 1];
        int2 sj2 = srcj[e + 2], sj3 = srcj[e + 3];
        float4 W0 = wE[sj0.y], W1 = wE[sj1.y];
        float4 W2 = wE[sj2.y], W3 = wE[sj3.y];
        unsigned int xu0 = xb[(size_t)sj0.x * 64 + lane];
        unsigned int xu1 = xb[(size_t)sj1.x * 64 + lane];
        unsigned int xu2 = xb[(size_t)sj2.x * 64 + lane];
        unsigned int xu3 = xb[(size_t)sj3.x * 64 + lane];
        float a0 = bf16_lo(xu0), b0 = bf16_hi(xu0);
        float a1 = bf16_lo(xu1), b1 = bf16_hi(xu1);
        float a2 = bf16_lo(xu2), b2 = bf16_hi(xu2);
        float a3 = bf16_lo(xu3), b3 = bf16_hi(xu3);
        acc0.x = fmaf(W0.x, a0, acc0.x); acc0.y = fmaf(W0.x, b0, acc0.y);
        acc1.x = fmaf(W0.y, a0, acc1.x); acc1.y = fmaf(W0.y, b0, acc1.y);
        acc2.x = fmaf(W0.z, a0, acc2.x); acc2.y = fmaf(W0.z, b0, acc2.y);
        acc3.x = fmaf(W0.w, a0, acc3.x); acc3.y = fmaf(W0.w, b0, acc3.y);
        acc0.x = fmaf(W1.x, a1, acc0.x); acc0.y = fmaf(W1.x, b1, acc0.y);
        acc1.x = fmaf(W1.y, a1, acc1.x); acc1.y = fmaf(W1.y, b1, acc1.y);
        acc2.x = fmaf(W1.z, a1, acc2.x); acc2.y = fmaf(W1.z, b1, acc2.y);
        acc3.x = fmaf(W1.w, a1, acc3.x); acc3.y = fmaf(W1.w, b1, acc3.y);
        acc0.x = fmaf(W2.x, a2, acc0.x); acc0.y = fmaf(W2.x, b2, acc0.y);
        acc1.x = fmaf(W2.y, a2, acc1.x); acc1.y = fmaf(W2.y, b2, acc1.y);
        acc2.x = fmaf(W2.z, a2, acc2.x); acc2.y = fmaf(W2.z, b2, acc2.y);
        acc3.x = fmaf(W2.w, a2, acc3.x); acc3.y = fmaf(W2.w, b2, acc3.y);
        acc0.x = fmaf(W3.x, a3, acc0.x); acc0.y = fmaf(W3.x, b3, acc0.y);
        acc1.x = fmaf(W3.y, a3, acc1.x); acc1.y = fmaf(W3.y, b3, acc1.y);
        acc2.x = fmaf(W3.z, a3, acc2.x); acc2.y = fmaf(W3.z, b3, acc2.y);
        acc3.x = fmaf(W3.w, a3, acc3.x); acc3.y = fmaf(W3.w, b3, acc3.y);
        den0 += (W0.x + W1.x) + (W2.x + W3.x);
        den1 += (W0.y + W1.y) + (W2.y + W3.y);
        den2 += (W0.z + W1.z) + (W2.z + W3.z);
        den3 += (W0.w + W1.w) + (W2.w + W3.w);
    }
    for (; e < e1; e++) {
        int2 sj = srcj[e];
        float4 W0 = wE[sj.y];
        unsigned int xu = xb[(size_t)sj.x * 64 + lane];
        float xa = bf16_lo(xu), xbv = bf16_hi(xu);
        acc0.x = fmaf(W0.x, xa, acc0.x); acc0.y = fmaf(W0.x, xbv, acc0.y);
        acc1.x = fmaf(W0.y, xa, acc1.x); acc1.y = fmaf(W0.y, xbv, acc1.y);
        acc2.x = fmaf(W0.z, xa, acc2.x); acc2.y = fmaf(W0.z, xbv, acc2.y);
        acc3.x = fmaf(W0.w, xa, acc3.x); acc3.y = fmaf(W0.w, xbv, acc3.y);
        den0 += W0.x; den1 += W0.y; den2 += W0.z; den3 += W0.w;
    }
    float i0 = 1.f / (den0 + 1e-16f), i1 = 1.f / (den1 + 1e-16f);
    float i2 = 1.f / (den2 + 1e-16f), i3 = 1.f / (den3 + 1e-16f);
    unsigned int* o = xaggb + (size_t)n * 256 + lane;      // row = 256 uints
    o[0 * 64] = bf16_pack2(acc0.x * i0, acc0.y * i0);
    o[1 * 64] = bf16_pack2(acc1.x * i1, acc1.y * i1);
    o[2 * 64] = bf16_pack2(acc2.x * i2, acc2.y * i2);
    o[3 * 64] = bf16_pack2(acc3.x * i3, acc3.y * i3);
}

// ---------------------------------------------------------------------------
// mlp7: MFMA phase B. 16 nodes/block, wave = head. (unchanged)
// ---------------------------------------------------------------------------
__global__ __launch_bounds__(256, 4) void mlp7_kernel(
    const unsigned int* __restrict__ xaggb,
    const unsigned int* __restrict__ W1b, const float* __restrict__ b1,
    const float* __restrict__ v_s, const float* __restrict__ v_d,
    const float* __restrict__ v_z,
    float2* __restrict__ az, float* __restrict__ ad2)
{
    __shared__ unsigned int xsh[16 * 260];     // 16.6 KB bf16 tile (+pad)
    __shared__ float pr[4 * 16 * 3];           // 768 B cross-wave partials
    const int t = threadIdx.x;
    const int nodeBase = blockIdx.x * 16;
    const int h = t >> 6;                      // wave = head
    const int lane = t & 63;

    {   // ---- Phase A: stage 16x512ch bf16 tile (no conversion) ----
        const unsigned int* gsrc = xaggb + (size_t)nodeBase * 256;
        #pragma unroll
        for (int i = 0; i < 4; i++) {
            int iu = i * 1024 + t * 4;         // uint index in 4096-uint tile
            uint4 v = *(const uint4*)(gsrc + iu);
            int n = iu >> 8, c = iu & 255;
            *(uint4*)(xsh + n * 260 + c) = v;
        }
    }
    __syncthreads();

    {   // ---- Phase B: MFMA + register epilogue ----
        const int m = lane & 15, quad = lane >> 4;
        const unsigned int* abase = xsh + m * 260 + h * 64 + quad * 4;
        v8s af0 = *(const v8s*)(abase + 0);
        v8s af1 = *(const v8s*)(abase + 16);
        v8s af2 = *(const v8s*)(abase + 32);
        v8s af3 = *(const v8s*)(abase + 48);

        float Sr[4] = {0,0,0,0}, Dr[4] = {0,0,0,0}, Zr[4] = {0,0,0,0};
        #pragma unroll
        for (int nt = 0; nt < 4; nt++) {
            const unsigned int* bbase = W1b + (size_t)(h * 16 + nt * 4) * 256 + lane * 4;
            v4f acc = {0.f, 0.f, 0.f, 0.f};
            acc = __builtin_amdgcn_mfma_f32_16x16x32_bf16(af0, *(const v8s*)(bbase + 0 * 256), acc, 0, 0, 0);
            acc = __builtin_amdgcn_mfma_f32_16x16x32_bf16(af1, *(const v8s*)(bbase + 1 * 256), acc, 0, 0, 0);
            acc = __builtin_amdgcn_mfma_f32_16x16x32_bf16(af2, *(const v8s*)(bbase + 2 * 256), acc, 0, 0, 0);
            acc = __builtin_amdgcn_mfma_f32_16x16x32_bf16(af3, *(const v8s*)(bbase + 3 * 256), acc, 0, 0, 0);
            const int c = h * 64 + nt * 16 + m;
            float bb = b1[c], vsc = v_s[c], vdc = v_d[c], vzc = v_z[c];
            #pragma unroll
            for (int r = 0; r < 4; r++) {
                float o = acc[r] + bb;
                o = o > 0.f ? o : __expf(o) - 1.f;     // ELU
                Sr[r] = fmaf(o, vsc, Sr[r]);
                Dr[r] = fmaf(o, vdc, Dr[r]);
                Zr[r] = fmaf(o, vzc, Zr[r]);
            }
        }
        #pragma unroll
        for (int off = 8; off; off >>= 1) {            // reduce over 16 cols
            #pragma unroll
            for (int r = 0; r < 4; r++) {
                Sr[r] += __shfl_down(Sr[r], off, 16);
                Dr[r] += __shfl_down(Dr[r], off, 16);
                Zr[r] += __shfl_down(Zr[r], off, 16);
            }
        }
        if (m == 0) {
            #pragma unroll
            for (int r = 0; r < 4; r++) {
                const int row = quad * 4 + r;          // local node 0..15
                pr[(h * 16 + row) * 3 + 0] = Sr[r];
                pr[(h * 16 + row) * 3 + 1] = Dr[r];
                pr[(h * 16 + row) * 3 + 2] = Zr[r];
            }
        }
    }
    __syncthreads();

    if (t < 16) {   // ---- cross-head reduce + store ----
        float s = 0.f, d = 0.f, z = 0.f;
        #pragma unroll
        for (int w = 0; w < 4; w++) {
            s += pr[(w * 16 + t) * 3 + 0];
            d += pr[(w * 16 + t) * 3 + 1];
            z += pr[(w * 16 + t) * 3 + 2];
        }
        const int node = nodeBase + t;
        float2 azv = {s, z};
        az[node]  = azv;
        ad2[node] = d;
    }
}

// ---------------------------------------------------------------------------
// agg2z: out[n] = sum_e w_e * z[src] / sum_e w_e + cst.  8 B/edge gather.
// ---------------------------------------------------------------------------
__global__ __launch_bounds__(256) void agg2z_kernel(
    const int* __restrict__ rowptr, const int2* __restrict__ srcj,
    const float2* __restrict__ az, const float* __restrict__ ad2,
    const float* __restrict__ cst, float* __restrict__ out)
{
    int gid  = blockIdx.x * blockDim.x + threadIdx.x;
    int n    = gid >> 3;                       // 8 lanes per node
    int sl   = threadIdx.x & 7;
    if (n >= N_NODES) return;
    const float adh = ad2[n];
    const int e0 = rowptr[n], e1 = rowptr[n + 1];

    float acc = 0.f, den = 0.f;
    for (int e = e0 + sl; e < e1; e += 8) {
        int s = srcj[e].x;
        float2 v = az[s];
        float a = v.x + adh;
        a = a > 0.f ? a : NEG_SLOPE * a;
        float w = __expf(a);
        acc = fmaf(w, v.y, acc);
        den += w;
    }
    #pragma unroll
    for (int off = 4; off; off >>= 1) {
        acc += __shfl_down(acc, off, 8);
        den += __shfl_down(den, off, 8);
    }
    if (sl == 0) out[n] = acc / (den + 1e-16f) + cst[0];
}

extern "C" void kernel_launch(void* const* d_in, const int* in_sizes, int n_in,
                              void* d_out, int out_size, void* d_ws, size_t ws_size,
                              hipStream_t stream)
{
    const float* x      = (const float*)d_in[0];
    const int*   ei     = (const int*)d_in[1];
    const float* W1     = (const float*)d_in[2];
    const float* a_src1 = (const float*)d_in[3];
    const float* a_dst1 = (const float*)d_in[4];
    const float* b1     = (const float*)d_in[5];
    const float* W2     = (const float*)d_in[6];
    const float* a_src2 = (const float*)d_in[7];
    const float* a_dst2 = (const float*)d_in[8];
    const float* b2     = (const float*)d_in[9];
    const float* fc_w   = (const float*)d_in[10];
    const float* fc_b   = (const float*)d_in[11];
    float* out = (float*)d_out;

    const int* srcA = ei;
    const int* dstA = ei + N_EDGES;

    // workspace layout (pads after index buffers as OOB insurance)
    float* ws = (float*)d_ws;
    size_t off = 0;
    unsigned int* xaggb = (unsigned int*)(ws + off); off += (size_t)N_NODES * 256;  // 51.2 MB
    unsigned int* xb    = (unsigned int*)(ws + off); off += (size_t)N_NODES * 64;   // 12.8 MB
    float4* wE     = (float4*)(ws + off); off += (size_t)E_TOT * 4 + 4;             // 13.6 MB
    int2* srcj     = (int2*)(ws + off); off += (size_t)E_TOT * 2 + 256;             //  6.8 MB
    int* posE      = (int*)(ws + off); off += E_TOT + 256;                          //  3.4 MB
    float* as1     = ws + off; off += (size_t)N_NODES * HEADS;
    float* ad1     = ws + off; off += (size_t)N_NODES * HEADS;
    float2* az     = (float2*)(ws + off); off += (size_t)N_NODES * 2;
    float* ad2     = ws + off; off += N_NODES;
    float* p_src   = ws + off; off += IN_DIM * HEADS;
    float* p_dst   = ws + off; off += IN_DIM * HEADS;
    float* v_s     = ws + off; off += C1;
    float* v_d     = ws + off; off += C1;
    float* v_z     = ws + off; off += C1;
    float* cst     = ws + off; off += 2;
    unsigned int* W1b = (unsigned int*)(ws + off); off += 16384;     // 64 KB packed bf16
    int* rowptr    = (int*)(ws + off); off += N_NODES + 1 + 256;     // +pad
    int* bsum      = (int*)(ws + off); off += 256;
    int* boff      = (int*)(ws + off); off += 256;
    int* deg       = (int*)(ws + off); off += N_NODES;
    hipMemsetAsync(deg, 0, N_NODES * sizeof(int), stream);

    // projection collapses + W1 bf16 B-fragment packing
    prep_kernel<<<1, 512, 0, stream>>>(W1, a_src1, a_dst1, W2, a_src2, a_dst2,
                                       b2, fc_w, fc_b, p_src, p_dst, v_s, v_d, v_z, cst, W1b);

    // fused: per-node proj + x->bf16 convert; count claims positions (posE)
    convproj_count_kernel<<<CP_BLOCKS + COUNT_BLOCKS, 256, 0, stream>>>(
        x, p_src, p_dst, dstA, as1, ad1, xb, deg, posE);

    // CSR: parallel scan + atomic-free fill (weights coalesced in edge order)
    blocksum_kernel<<<NB_SCAN, 256, 0, stream>>>(deg, bsum);
    scanbsum_kernel<<<1, 256, 0, stream>>>(bsum, boff);
    expand_kernel<<<NB_SCAN, 256, 0, stream>>>(deg, boff, rowptr);
    fillw2_kernel<<<COUNT_BLOCKS, 256, 0, stream>>>(srcA, dstA, rowptr, posE,
                                                    as1, ad1, srcj, wE);

    // layer-1 aggregation in bf16 x-space
    agg1x_kernel<<<(N_NODES * 64 + 255) / 256, 256, 0, stream>>>(rowptr, srcj, wE, xb, xaggb);

    // MFMA MLP (phase C collapsed; epilogue in registers)
    mlp7_kernel<<<N_NODES / 16, 256, 0, stream>>>(xaggb, W1b, b1, v_s, v_d, v_z, az, ad2);

    // layer 2 + final: scalar gather
    agg2z_kernel<<<(N_NODES * 8 + 255) / 256, 256, 0, stream>>>(rowptr, srcj, az, ad2, cst, out);
}

// Round 17
// 251.690 us; speedup vs baseline: 2.4308x; 1.0449x over previous
//
#include <hip/hip_runtime.h>
#include <hip/hip_fp16.h>

#define N_NODES 50000
#define N_EDGES 800000
#define E_TOT   850000           // edges + self loops
#define IN_DIM  128
#define HID     64
#define HEADS   4
#define C1      256              // HEADS*HID
#define OUT_DIM 64
#define NEG_SLOPE 0.2f

#define CP_NODES   32                              // nodes per proj block
#define CP_BLOCKS  ((N_NODES + CP_NODES - 1) / CP_NODES)   // 1563
#define COUNT_BLOCKS ((E_TOT + 255) / 256)         // 3321
#define NB_SCAN ((N_NODES + 255) / 256)            // 196

typedef __attribute__((ext_vector_type(8))) short v8s;   // 8 bf16 (4 VGPRs)
typedef __attribute__((ext_vector_type(4))) float v4f;   // MFMA accumulator

// ---- bf16 helpers (manual: bf16 = top 16 bits of fp32, RNE) ----------------
__device__ __forceinline__ unsigned int bf16_rne(float f) {
    unsigned int u = __float_as_uint(f);
    return (u + 0x7FFFu + ((u >> 16) & 1u)) >> 16;
}
__device__ __forceinline__ unsigned int bf16_pack2(float a, float b) {
    return bf16_rne(a) | (bf16_rne(b) << 16);
}
__device__ __forceinline__ float bf16_lo(unsigned int u) { return __uint_as_float(u << 16); }
__device__ __forceinline__ float bf16_hi(unsigned int u) { return __uint_as_float(u & 0xFFFF0000u); }

// ---- fp16 pack helpers for edge weights ------------------------------------
__device__ __forceinline__ unsigned int f16_pack2(float a, float b) {
    __half2 h = __floats2half2_rn(a, b);
    return *(unsigned int*)&h;
}
__device__ __forceinline__ float2 f16_unp2(unsigned int u) {
    __half2 h = *(__half2*)&u;
    return __half22float2(h);
}

// ---------------------------------------------------------------------------
// prep: p_src/p_dst collapse the layer-1 logit projection; v_s/v_d/v_z
// collapse ALL consumers of h2; cst = b2.fc_w + fc_b; W1 -> bf16 B-fragments.
// ---------------------------------------------------------------------------
__global__ __launch_bounds__(512) void prep_kernel(
    const float* __restrict__ W1, const float* __restrict__ a_src1,
    const float* __restrict__ a_dst1,
    const float* __restrict__ W2, const float* __restrict__ a_src2,
    const float* __restrict__ a_dst2, const float* __restrict__ b2,
    const float* __restrict__ fc_w, const float* __restrict__ fc_b,
    float* __restrict__ p_src, float* __restrict__ p_dst,
    float* __restrict__ v_s, float* __restrict__ v_d, float* __restrict__ v_z,
    float* __restrict__ cst, unsigned int* __restrict__ W1b)
{
    const int t = threadIdx.x;                 // 512 = 128 k * 4 h
    const int k = t >> 2, h = t & 3;
    const float* wrow = W1 + k * C1 + h * HID;
    const float* as = a_src1 + h * HID;
    const float* ad = a_dst1 + h * HID;
    float s = 0.f, d = 0.f;
    for (int c = 0; c < HID; c++) {
        float w = wrow[c];
        s = fmaf(w, as[c], s);
        d = fmaf(w, ad[c], d);
    }
    p_src[k * HEADS + h] = s;
    p_dst[k * HEADS + h] = d;

    if (t < C1) {                              // layer-2 collapse vectors
        const float* w2row = W2 + t * OUT_DIM;
        float vs = 0.f, vd = 0.f, vz = 0.f;
        for (int c = 0; c < OUT_DIM; c++) {
            float w = w2row[c];
            vs = fmaf(w, a_src2[c], vs);
            vd = fmaf(w, a_dst2[c], vd);
            vz = fmaf(w, fc_w[c], vz);
        }
        v_s[t] = vs; v_d[t] = vd; v_z[t] = vz;
    }
    if (t == 0) {
        float s2 = 0.f;
        for (int c = 0; c < OUT_DIM; c++) s2 = fmaf(b2[c], fc_w[c], s2);
        cst[0] = s2 + fc_b[0];
    }

    // W1 -> bf16 B-fragment packing (16384 uints = 64 KB)
    for (int idx = t; idx < 16384; idx += 512) {
        int i    = idx & 3;
        int lane = (idx >> 2) & 63;
        int kk   = (idx >> 8) & 3;
        int nt   = (idx >> 10) & 3;
        int hh   = idx >> 12;
        int k0 = kk * 32 + (lane >> 4) * 8 + i * 2;
        int c  = hh * 64 + nt * 16 + (lane & 15);
        W1b[idx] = bf16_pack2(W1[(size_t)k0 * C1 + c], W1[(size_t)(k0 + 1) * C1 + c]);
    }
}

// ---------------------------------------------------------------------------
// convproj_count: fused launch.
//  Blocks [0, CP_BLOCKS): 32 nodes/block: projections as1/ad1 AND x -> bf16.
//  Blocks [CP_BLOCKS, +COUNT_BLOCKS): degree count; stores each edge's
//    claimed position posE[j] so fillw3 needs no atomic.
// ---------------------------------------------------------------------------
__global__ __launch_bounds__(256) void convproj_count_kernel(
    const float* __restrict__ x, const float* __restrict__ p_src,
    const float* __restrict__ p_dst, const int* __restrict__ dst_a,
    float* __restrict__ as1, float* __restrict__ ad1,
    unsigned int* __restrict__ xb, int* __restrict__ deg,
    int* __restrict__ posE)
{
    if (blockIdx.x >= CP_BLOCKS) {             // ---- count part ----
        int j = (blockIdx.x - CP_BLOCKS) * 256 + threadIdx.x;
        if (j < E_TOT) {
            int d = (j < N_EDGES) ? dst_a[j] : (j - N_EDGES);   // self loop
            posE[j] = atomicAdd(&deg[d], 1);
        }
        return;
    }
    // ---- proj + convert part ----
    __shared__ float ps[IN_DIM * HEADS];       // 2 KB
    __shared__ float pd[IN_DIM * HEADS];       // 2 KB
    const int t = threadIdx.x;
    for (int i = t; i < IN_DIM * HEADS; i += 256) { ps[i] = p_src[i]; pd[i] = p_dst[i]; }
    __syncthreads();
    const int wv   = t >> 6;
    const int lane = t & 63;
    float4 p0 = *(const float4*)(ps + (lane * 2) * HEADS);
    float4 p1 = *(const float4*)(ps + (lane * 2 + 1) * HEADS);
    float4 q0 = *(const float4*)(pd + (lane * 2) * HEADS);
    float4 q1 = *(const float4*)(pd + (lane * 2 + 1) * HEADS);
    const int nodeBase = blockIdx.x * CP_NODES + wv * 8;   // wave: 8 contiguous nodes
    #pragma unroll
    for (int i = 0; i < 8; i++) {
        const int node = nodeBase + i;
        if (node >= N_NODES) break;
        float2 xv = *(const float2*)(x + (size_t)node * IN_DIM + lane * 2);
        xb[(size_t)node * 64 + lane] = bf16_pack2(xv.x, xv.y);
        float s0 = xv.x * p0.x + xv.y * p1.x;
        float s1 = xv.x * p0.y + xv.y * p1.y;
        float s2 = xv.x * p0.z + xv.y * p1.z;
        float s3 = xv.x * p0.w + xv.y * p1.w;
        float d0 = xv.x * q0.x + xv.y * q1.x;
        float d1 = xv.x * q0.y + xv.y * q1.y;
        float d2 = xv.x * q0.z + xv.y * q1.z;
        float d3 = xv.x * q0.w + xv.y * q1.w;
        #pragma unroll
        for (int off = 32; off; off >>= 1) {
            s0 += __shfl_down(s0, off, 64); s1 += __shfl_down(s1, off, 64);
            s2 += __shfl_down(s2, off, 64); s3 += __shfl_down(s3, off, 64);
            d0 += __shfl_down(d0, off, 64); d1 += __shfl_down(d1, off, 64);
            d2 += __shfl_down(d2, off, 64); d3 += __shfl_down(d3, off, 64);
        }
        if (lane == 0) {
            float4 sv = {s0, s1, s2, s3};
            float4 dv = {d0, d1, d2, d3};
            *(float4*)(as1 + node * 4) = sv;
            *(float4*)(ad1 + node * 4) = dv;
        }
    }
}

// ---------------------------------------------------------------------------
// Parallel CSR scan: blocksum -> scanbsum -> expand
// ---------------------------------------------------------------------------
__global__ __launch_bounds__(256) void blocksum_kernel(
    const int* __restrict__ deg, int* __restrict__ bsum)
{
    __shared__ int ps[256];
    const int t = threadIdx.x;
    int i = blockIdx.x * 256 + t;
    ps[t] = (i < N_NODES) ? deg[i] : 0;
    __syncthreads();
    for (int off = 128; off; off >>= 1) {
        if (t < off) ps[t] += ps[t + off];
        __syncthreads();
    }
    if (t == 0) bsum[blockIdx.x] = ps[0];
}

__global__ __launch_bounds__(256) void scanbsum_kernel(
    const int* __restrict__ bsum, int* __restrict__ boff)
{
    __shared__ int ps[256];
    const int t = threadIdx.x;
    ps[t] = (t < NB_SCAN) ? bsum[t] : 0;
    __syncthreads();
    for (int off = 1; off < 256; off <<= 1) {
        int u = (t >= off) ? ps[t - off] : 0;
        __syncthreads();
        ps[t] += u;
        __syncthreads();
    }
    boff[t] = (t > 0) ? ps[t - 1] : 0;         // exclusive
}

__global__ __launch_bounds__(256) void expand_kernel(
    const int* __restrict__ deg, const int* __restrict__ boff,
    int* __restrict__ rowptr)
{
    __shared__ int ps[256];
    const int t = threadIdx.x;
    int i = blockIdx.x * 256 + t;
    int v = (i < N_NODES) ? deg[i] : 0;
    ps[t] = v;
    __syncthreads();
    for (int off = 1; off < 256; off <<= 1) {
        int u = (t >= off) ? ps[t - off] : 0;
        __syncthreads();
        ps[t] += u;
        __syncthreads();
    }
    if (i <= N_NODES) rowptr[i] = boff[blockIdx.x] + ps[t] - v;   // exclusive
}

// ---------------------------------------------------------------------------
// fillw3: atomic-free CSR fill with ONE 16 B sorted record per edge:
// rec[slot] = {src, w01(2xf16), w23(2xf16), 0}. Weights live in the sorted
// stream, so agg1x reads 4 consecutive records = one 64 B line.
// ---------------------------------------------------------------------------
__global__ void fillw3_kernel(const int* __restrict__ src_a, const int* __restrict__ dst_a,
                              const int* __restrict__ rowptr, const int* __restrict__ posE,
                              const float* __restrict__ as1, const float* __restrict__ ad1,
                              int4* __restrict__ rec)
{
    int j = blockIdx.x * blockDim.x + threadIdx.x;
    if (j >= E_TOT) return;
    int s, d;
    if (j < N_EDGES) { s = src_a[j]; d = dst_a[j]; }
    else             { s = j - N_EDGES; d = s; }
    int slot = rowptr[d] + posE[j];
    float4 A  = *(const float4*)(as1 + s * 4);
    float4 Dv = *(const float4*)(ad1 + d * 4);
    float a0 = A.x + Dv.x, a1 = A.y + Dv.y, a2 = A.z + Dv.z, a3 = A.w + Dv.w;
    a0 = a0 > 0.f ? a0 : NEG_SLOPE * a0;
    a1 = a1 > 0.f ? a1 : NEG_SLOPE * a1;
    a2 = a2 > 0.f ? a2 : NEG_SLOPE * a2;
    a3 = a3 > 0.f ? a3 : NEG_SLOPE * a3;
    int4 r;
    r.x = s;
    r.y = (int)f16_pack2(__expf(a0), __expf(a1));
    r.z = (int)f16_pack2(__expf(a2), __expf(a3));
    r.w = 0;
    rec[slot] = r;                             // single 16 B scatter
}

// ---------------------------------------------------------------------------
// agg1x: xaggb[n][h][k] (bf16) = softmax-weighted sum of xb[src] rows (bf16).
// One wave per dst node; per-edge {src, weights} in one sorted record;
// unroll x4 -> 4 xb-row gathers in flight, 4 records = one 64 B line.
// ---------------------------------------------------------------------------
__global__ __launch_bounds__(256) void agg1x_kernel(
    const int* __restrict__ rowptr, const int4* __restrict__ rec,
    const unsigned int* __restrict__ xb, unsigned int* __restrict__ xaggb)
{
    int gid  = blockIdx.x * blockDim.x + threadIdx.x;
    int n    = gid >> 6;
    int lane = threadIdx.x & 63;
    if (n >= N_NODES) return;
    const int e0 = rowptr[n], e1 = rowptr[n + 1];

    float2 acc0 = {0,0}, acc1 = {0,0}, acc2 = {0,0}, acc3 = {0,0};
    float den0 = 0, den1 = 0, den2 = 0, den3 = 0;
    int e = e0;
    for (; e + 4 <= e1; e += 4) {              // 4 gathers in flight
        int4 r0 = rec[e],     r1 = rec[e + 1];
        int4 r2 = rec[e + 2], r3 = rec[e + 3];
        unsigned int xu0 = xb[(size_t)r0.x * 64 + lane];
        unsigned int xu1 = xb[(size_t)r1.x * 64 + lane];
        unsigned int xu2 = xb[(size_t)r2.x * 64 + lane];
        unsigned int xu3 = xb[(size_t)r3.x * 64 + lane];
        float2 W0a = f16_unp2(r0.y), W0b = f16_unp2(r0.z);
        float2 W1a = f16_unp2(r1.y), W1b_ = f16_unp2(r1.z);
        float2 W2a = f16_unp2(r2.y), W2b = f16_unp2(r2.z);
        float2 W3a = f16_unp2(r3.y), W3b = f16_unp2(r3.z);
        float a0 = bf16_lo(xu0), b0 = bf16_hi(xu0);
        float a1 = bf16_lo(xu1), b1 = bf16_hi(xu1);
        float a2 = bf16_lo(xu2), b2 = bf16_hi(xu2);
        float a3 = bf16_lo(xu3), b3 = bf16_hi(xu3);
        acc0.x = fmaf(W0a.x, a0, acc0.x); acc0.y = fmaf(W0a.x, b0, acc0.y);
        acc1.x = fmaf(W0a.y, a0, acc1.x); acc1.y = fmaf(W0a.y, b0, acc1.y);
        acc2.x = fmaf(W0b.x, a0, acc2.x); acc2.y = fmaf(W0b.x, b0, acc2.y);
        acc3.x = fmaf(W0b.y, a0, acc3.x); acc3.y = fmaf(W0b.y, b0, acc3.y);
        acc0.x = fmaf(W1a.x, a1, acc0.x); acc0.y = fmaf(W1a.x, b1, acc0.y);
        acc1.x = fmaf(W1a.y, a1, acc1.x); acc1.y = fmaf(W1a.y, b1, acc1.y);
        acc2.x = fmaf(W1b_.x, a1, acc2.x); acc2.y = fmaf(W1b_.x, b1, acc2.y);
        acc3.x = fmaf(W1b_.y, a1, acc3.x); acc3.y = fmaf(W1b_.y, b1, acc3.y);
        acc0.x = fmaf(W2a.x, a2, acc0.x); acc0.y = fmaf(W2a.x, b2, acc0.y);
        acc1.x = fmaf(W2a.y, a2, acc1.x); acc1.y = fmaf(W2a.y, b2, acc1.y);
        acc2.x = fmaf(W2b.x, a2, acc2.x); acc2.y = fmaf(W2b.x, b2, acc2.y);
        acc3.x = fmaf(W2b.y, a2, acc3.x); acc3.y = fmaf(W2b.y, b2, acc3.y);
        acc0.x = fmaf(W3a.x, a3, acc0.x); acc0.y = fmaf(W3a.x, b3, acc0.y);
        acc1.x = fmaf(W3a.y, a3, acc1.x); acc1.y = fmaf(W3a.y, b3, acc1.y);
        acc2.x = fmaf(W3b.x, a3, acc2.x); acc2.y = fmaf(W3b.x, b3, acc2.y);
        acc3.x = fmaf(W3b.y, a3, acc3.x); acc3.y = fmaf(W3b.y, b3, acc3.y);
        den0 += (W0a.x + W1a.x) + (W2a.x + W3a.x);
        den1 += (W0a.y + W1a.y) + (W2a.y + W3a.y);
        den2 += (W0b.x + W1b_.x) + (W2b.x + W3b.x);
        den3 += (W0b.y + W1b_.y) + (W2b.y + W3b.y);
    }
    for (; e < e1; e++) {
        int4 r0 = rec[e];
        unsigned int xu = xb[(size_t)r0.x * 64 + lane];
        float2 Wa = f16_unp2(r0.y), Wb = f16_unp2(r0.z);
        float xa = bf16_lo(xu), xbv = bf16_hi(xu);
        acc0.x = fmaf(Wa.x, xa, acc0.x); acc0.y = fmaf(Wa.x, xbv, acc0.y);
        acc1.x = fmaf(Wa.y, xa, acc1.x); acc1.y = fmaf(Wa.y, xbv, acc1.y);
        acc2.x = fmaf(Wb.x, xa, acc2.x); acc2.y = fmaf(Wb.x, xbv, acc2.y);
        acc3.x = fmaf(Wb.y, xa, acc3.x); acc3.y = fmaf(Wb.y, xbv, acc3.y);
        den0 += Wa.x; den1 += Wa.y; den2 += Wb.x; den3 += Wb.y;
    }
    float i0 = 1.f / (den0 + 1e-16f), i1 = 1.f / (den1 + 1e-16f);
    float i2 = 1.f / (den2 + 1e-16f), i3 = 1.f / (den3 + 1e-16f);
    unsigned int* o = xaggb + (size_t)n * 256 + lane;      // row = 256 uints
    o[0 * 64] = bf16_pack2(acc0.x * i0, acc0.y * i0);
    o[1 * 64] = bf16_pack2(acc1.x * i1, acc1.y * i1);
    o[2 * 64] = bf16_pack2(acc2.x * i2, acc2.y * i2);
    o[3 * 64] = bf16_pack2(acc3.x * i3, acc3.y * i3);
}

// ---------------------------------------------------------------------------
// mlp7: MFMA phase B. 16 nodes/block, wave = head. (unchanged)
// ---------------------------------------------------------------------------
__global__ __launch_bounds__(256, 4) void mlp7_kernel(
    const unsigned int* __restrict__ xaggb,
    const unsigned int* __restrict__ W1b, const float* __restrict__ b1,
    const float* __restrict__ v_s, const float* __restrict__ v_d,
    const float* __restrict__ v_z,
    float2* __restrict__ az, float* __restrict__ ad2)
{
    __shared__ unsigned int xsh[16 * 260];     // 16.6 KB bf16 tile (+pad)
    __shared__ float pr[4 * 16 * 3];           // 768 B cross-wave partials
    const int t = threadIdx.x;
    const int nodeBase = blockIdx.x * 16;
    const int h = t >> 6;                      // wave = head
    const int lane = t & 63;

    {   // ---- Phase A: stage 16x512ch bf16 tile (no conversion) ----
        const unsigned int* gsrc = xaggb + (size_t)nodeBase * 256;
        #pragma unroll
        for (int i = 0; i < 4; i++) {
            int iu = i * 1024 + t * 4;         // uint index in 4096-uint tile
            uint4 v = *(const uint4*)(gsrc + iu);
            int n = iu >> 8, c = iu & 255;
            *(uint4*)(xsh + n * 260 + c) = v;
        }
    }
    __syncthreads();

    {   // ---- Phase B: MFMA + register epilogue ----
        const int m = lane & 15, quad = lane >> 4;
        const unsigned int* abase = xsh + m * 260 + h * 64 + quad * 4;
        v8s af0 = *(const v8s*)(abase + 0);
        v8s af1 = *(const v8s*)(abase + 16);
        v8s af2 = *(const v8s*)(abase + 32);
        v8s af3 = *(const v8s*)(abase + 48);

        float Sr[4] = {0,0,0,0}, Dr[4] = {0,0,0,0}, Zr[4] = {0,0,0,0};
        #pragma unroll
        for (int nt = 0; nt < 4; nt++) {
            const unsigned int* bbase = W1b + (size_t)(h * 16 + nt * 4) * 256 + lane * 4;
            v4f acc = {0.f, 0.f, 0.f, 0.f};
            acc = __builtin_amdgcn_mfma_f32_16x16x32_bf16(af0, *(const v8s*)(bbase + 0 * 256), acc, 0, 0, 0);
            acc = __builtin_amdgcn_mfma_f32_16x16x32_bf16(af1, *(const v8s*)(bbase + 1 * 256), acc, 0, 0, 0);
            acc = __builtin_amdgcn_mfma_f32_16x16x32_bf16(af2, *(const v8s*)(bbase + 2 * 256), acc, 0, 0, 0);
            acc = __builtin_amdgcn_mfma_f32_16x16x32_bf16(af3, *(const v8s*)(bbase + 3 * 256), acc, 0, 0, 0);
            const int c = h * 64 + nt * 16 + m;
            float bb = b1[c], vsc = v_s[c], vdc = v_d[c], vzc = v_z[c];
            #pragma unroll
            for (int r = 0; r < 4; r++) {
                float o = acc[r] + bb;
                o = o > 0.f ? o : __expf(o) - 1.f;     // ELU
                Sr[r] = fmaf(o, vsc, Sr[r]);
                Dr[r] = fmaf(o, vdc, Dr[r]);
                Zr[r] = fmaf(o, vzc, Zr[r]);
            }
        }
        #pragma unroll
        for (int off = 8; off; off >>= 1) {            // reduce over 16 cols
            #pragma unroll
            for (int r = 0; r < 4; r++) {
                Sr[r] += __shfl_down(Sr[r], off, 16);
                Dr[r] += __shfl_down(Dr[r], off, 16);
                Zr[r] += __shfl_down(Zr[r], off, 16);
            }
        }
        if (m == 0) {
            #pragma unroll
            for (int r = 0; r < 4; r++) {
                const int row = quad * 4 + r;          // local node 0..15
                pr[(h * 16 + row) * 3 + 0] = Sr[r];
                pr[(h * 16 + row) * 3 + 1] = Dr[r];
                pr[(h * 16 + row) * 3 + 2] = Zr[r];
            }
        }
    }
    __syncthreads();

    if (t < 16) {   // ---- cross-head reduce + store ----
        float s = 0.f, d = 0.f, z = 0.f;
        #pragma unroll
        for (int w = 0; w < 4; w++) {
            s += pr[(w * 16 + t) * 3 + 0];
            d += pr[(w * 16 + t) * 3 + 1];
            z += pr[(w * 16 + t) * 3 + 2];
        }
        const int node = nodeBase + t;
        float2 azv = {s, z};
        az[node]  = azv;
        ad2[node] = d;
    }
}

// ---------------------------------------------------------------------------
// agg2z: out[n] = sum_e w_e * z[src] / sum_e w_e + cst.  Reads rec[e].x.
// ---------------------------------------------------------------------------
__global__ __launch_bounds__(256) void agg2z_kernel(
    const int* __restrict__ rowptr, const int4* __restrict__ rec,
    const float2* __restrict__ az, const float* __restrict__ ad2,
    const float* __restrict__ cst, float* __restrict__ out)
{
    int gid  = blockIdx.x * blockDim.x + threadIdx.x;
    int n    = gid >> 3;                       // 8 lanes per node
    int sl   = threadIdx.x & 7;
    if (n >= N_NODES) return;
    const float adh = ad2[n];
    const int e0 = rowptr[n], e1 = rowptr[n + 1];

    float acc = 0.f, den = 0.f;
    for (int e = e0 + sl; e < e1; e += 8) {
        int s = rec[e].x;
        float2 v = az[s];
        float a = v.x + adh;
        a = a > 0.f ? a : NEG_SLOPE * a;
        float w = __expf(a);
        acc = fmaf(w, v.y, acc);
        den += w;
    }
    #pragma unroll
    for (int off = 4; off; off >>= 1) {
        acc += __shfl_down(acc, off, 8);
        den += __shfl_down(den, off, 8);
    }
    if (sl == 0) out[n] = acc / (den + 1e-16f) + cst[0];
}

extern "C" void kernel_launch(void* const* d_in, const int* in_sizes, int n_in,
                              void* d_out, int out_size, void* d_ws, size_t ws_size,
                              hipStream_t stream)
{
    const float* x      = (const float*)d_in[0];
    const int*   ei     = (const int*)d_in[1];
    const float* W1     = (const float*)d_in[2];
    const float* a_src1 = (const float*)d_in[3];
    const float* a_dst1 = (const float*)d_in[4];
    const float* b1     = (const float*)d_in[5];
    const float* W2     = (const float*)d_in[6];
    const float* a_src2 = (const float*)d_in[7];
    const float* a_dst2 = (const float*)d_in[8];
    const float* b2     = (const float*)d_in[9];
    const float* fc_w   = (const float*)d_in[10];
    const float* fc_b   = (const float*)d_in[11];
    float* out = (float*)d_out;

    const int* srcA = ei;
    const int* dstA = ei + N_EDGES;

    // workspace layout (pads after index buffers as OOB insurance)
    float* ws = (float*)d_ws;
    size_t off = 0;
    unsigned int* xaggb = (unsigned int*)(ws + off); off += (size_t)N_NODES * 256;  // 51.2 MB
    unsigned int* xb    = (unsigned int*)(ws + off); off += (size_t)N_NODES * 64;   // 12.8 MB
    int4* rec      = (int4*)(ws + off); off += (size_t)E_TOT * 4 + 256;             // 13.6 MB
    int* posE      = (int*)(ws + off); off += E_TOT + 256;                          //  3.4 MB
    float* as1     = ws + off; off += (size_t)N_NODES * HEADS;
    float* ad1     = ws + off; off += (size_t)N_NODES * HEADS;
    float2* az     = (float2*)(ws + off); off += (size_t)N_NODES * 2;
    float* ad2     = ws + off; off += N_NODES;
    float* p_src   = ws + off; off += IN_DIM * HEADS;
    float* p_dst   = ws + off; off += IN_DIM * HEADS;
    float* v_s     = ws + off; off += C1;
    float* v_d     = ws + off; off += C1;
    float* v_z     = ws + off; off += C1;
    float* cst     = ws + off; off += 2;
    unsigned int* W1b = (unsigned int*)(ws + off); off += 16384;     // 64 KB packed bf16
    int* rowptr    = (int*)(ws + off); off += N_NODES + 1 + 256;     // +pad
    int* bsum      = (int*)(ws + off); off += 256;
    int* boff      = (int*)(ws + off); off += 256;
    int* deg       = (int*)(ws + off); off += N_NODES;
    hipMemsetAsync(deg, 0, N_NODES * sizeof(int), stream);

    // projection collapses + W1 bf16 B-fragment packing
    prep_kernel<<<1, 512, 0, stream>>>(W1, a_src1, a_dst1, W2, a_src2, a_dst2,
                                       b2, fc_w, fc_b, p_src, p_dst, v_s, v_d, v_z, cst, W1b);

    // fused: per-node proj + x->bf16 convert; count claims positions (posE)
    convproj_count_kernel<<<CP_BLOCKS + COUNT_BLOCKS, 256, 0, stream>>>(
        x, p_src, p_dst, dstA, as1, ad1, xb, deg, posE);

    // CSR: parallel scan + atomic-free fill (one 16 B sorted record per edge)
    blocksum_kernel<<<NB_SCAN, 256, 0, stream>>>(deg, bsum);
    scanbsum_kernel<<<1, 256, 0, stream>>>(bsum, boff);
    expand_kernel<<<NB_SCAN, 256, 0, stream>>>(deg, boff, rowptr);
    fillw3_kernel<<<COUNT_BLOCKS, 256, 0, stream>>>(srcA, dstA, rowptr, posE,
                                                    as1, ad1, rec);

    // layer-1 aggregation in bf16 x-space
    agg1x_kernel<<<(N_NODES * 64 + 255) / 256, 256, 0, stream>>>(rowptr, rec, xb, xaggb);

    // MFMA MLP (phase C collapsed; epilogue in registers)
    mlp7_kernel<<<N_NODES / 16, 256, 0, stream>>>(xaggb, W1b, b1, v_s, v_d, v_z, az, ad2);

    // layer 2 + final: scalar gather
    agg2z_kernel<<<(N_NODES * 8 + 255) / 256, 256, 0, stream>>>(rowptr, rec, az, ad2, cst, out);
}